// Round 4
// baseline (315.438 us; speedup 1.0000x reference)
//
#include <hip/hip_runtime.h>

// ---- problem constants ----
#define CC   192                 // C
#define C3   576                 // 3C
#define HH   64
#define WW   64
#define HWP  4096                // H*W
#define BB   8
#define DH   48                  // C/HEADS
#define QKV_B (C3*HWP)           // elements per batch of conv-out tensor
#define X_B   (CC*HWP)
#define OUT_HALF ((size_t)BB*X_B)

typedef short bf16x8 __attribute__((ext_vector_type(8)));
typedef float f32x4  __attribute__((ext_vector_type(4)));

#define AS1(p) ((__attribute__((address_space(1))) void*)(p))
#define AS3(p) ((__attribute__((address_space(3))) void*)(p))

__device__ __forceinline__ ushort f2bf(float v) {
    union { float f; unsigned u; } a; a.f = v;
    unsigned r = a.u + 0x7FFF + ((a.u >> 16) & 1);   // RNE
    return (ushort)(r >> 16);
}
__device__ __forceinline__ float bf2f(ushort h) {
    union { float f; unsigned u; } a; a.u = ((unsigned)h) << 16; return a.f;
}

// ============================================================
// in (b,192,4096) fp32 -> out (b,4096,384) bf16: cols 0..191 hi, 192..383 lo
// (used for x, y, and for transposing vx, vy)
// ============================================================
__global__ __launch_bounds__(256) void convert_kernel(const float* __restrict__ in,
    ushort* __restrict__ xt)
{
    __shared__ float L[64][65];
    const int n0 = blockIdx.x * 64, c0 = blockIdx.y * 64, b = blockIdx.z;
    const int t = threadIdx.x;
    const float* ip = in + (size_t)b * X_B;
    #pragma unroll
    for (int i = 0; i < 16; i++) {
        int e = t + 256 * i;
        int r = e >> 6, col = e & 63;
        L[r][col] = ip[(size_t)(c0 + r) * HWP + n0 + col];
    }
    __syncthreads();
    #pragma unroll
    for (int i = 0; i < 4; i++) {
        int e = t + 256 * i;
        int n = e >> 4, c4 = e & 15;
        ushort hi[4], lo[4];
        #pragma unroll
        for (int j = 0; j < 4; j++) {
            float v = L[c4 * 4 + j][n];
            hi[j] = f2bf(v);
            lo[j] = f2bf(v - bf2f(hi[j]));
        }
        size_t base = ((size_t)(b * HWP + n0 + n)) * 384 + c0 + c4 * 4;
        *(ushort4*)&xt[base]       = make_ushort4(hi[0], hi[1], hi[2], hi[3]);
        *(ushort4*)&xt[base + 192] = make_ushort4(lo[0], lo[1], lo[2], lo[3]);
    }
}

// ============================================================
// w_qkv -> Wc(640,384) bf16 hi|lo, zero-padded rows
// ============================================================
__global__ __launch_bounds__(256) void wconvert_kernel(const float* __restrict__ wq,
    ushort* __restrict__ wc)
{
    int e = (blockIdx.x * 256 + threadIdx.x) * 4;
    int oc = e / 384, k = e % 384;
    ushort o[4] = {0, 0, 0, 0};
    if (oc < C3) {
        int kk = (k < 192) ? k : (k - 192);
        #pragma unroll
        for (int j = 0; j < 4; j++) {
            float v = wq[oc * CC + kk + j];
            ushort h = f2bf(v);
            o[j] = (k < 192) ? h : f2bf(v - bf2f(h));
        }
    }
    *(ushort4*)&wc[e] = make_ushort4(o[0], o[1], o[2], o[3]);
}

// ============================================================
// conv1x1 via MFMA; epilogue now writes bf16 hi/lo pairs (t1hh/t1hl)
// ============================================================
__global__ __launch_bounds__(256) void conv1x1_mfma(const ushort* __restrict__ XT,
    const ushort* __restrict__ Wc, ushort* __restrict__ oh, ushort* __restrict__ ol,
    int b0)
{
    __shared__ __align__(16) ushort Asb[128 * 64];
    __shared__ __align__(16) ushort Bsb[128 * 64];
    const int t = threadIdx.x;
    const int lane = t & 63, w = t >> 6;
    const int wm = w >> 1, wn = w & 1;
    const int fr = lane & 15, kg = lane >> 4;
    const int nt = blockIdx.x;
    const int bl = nt >> 5;
    const int n0 = (nt & 31) * 128;
    const int m0 = blockIdx.y * 128;
    const int bg = b0 + bl;

    f32x4 acc[4][4] = {};
    const int ur = w * 64 + lane;

    for (int kc = 0; kc < 9; kc++) {
        int kmod = (kc < 3) ? kc : ((kc < 6) ? kc - 3 : kc - 6);
        int cA = ((kc < 6) ? 0 : 192) + kmod * 64;
        int cB = ((kc >= 3 && kc < 6) ? 192 : 0) + kmod * 64;
        #pragma unroll
        for (int i = 0; i < 4; i++) {
            int u = i * 256 + ur;
            int r = u >> 3, c = u & 7;
            int cs = c ^ (r & 7);
            const ushort* ga = Wc + (size_t)(m0 + r) * 384 + cA + cs * 8;
            __builtin_amdgcn_global_load_lds(AS1(ga), AS3(&Asb[(size_t)(i * 4 + w) * 512]), 16, 0, 0);
            const ushort* gb = XT + ((size_t)(bg * HWP + n0 + r)) * 384 + cB + cs * 8;
            __builtin_amdgcn_global_load_lds(AS1(gb), AS3(&Bsb[(size_t)(i * 4 + w) * 512]), 16, 0, 0);
        }
        __syncthreads();
        #pragma unroll
        for (int kq = 0; kq < 8; kq += 4) {
            bf16x8 af[4], bfr[4];
            #pragma unroll
            for (int m = 0; m < 4; m++) {
                int R = wm * 64 + m * 16 + fr;
                int unit = R * 8 + ((kq + kg) ^ (R & 7));
                af[m] = *(const bf16x8*)&Asb[unit * 8];
            }
            #pragma unroll
            for (int n = 0; n < 4; n++) {
                int R = wn * 64 + n * 16 + fr;
                int unit = R * 8 + ((kq + kg) ^ (R & 7));
                bfr[n] = *(const bf16x8*)&Bsb[unit * 8];
            }
            #pragma unroll
            for (int m = 0; m < 4; m++)
                #pragma unroll
                for (int n = 0; n < 4; n++)
                    acc[m][n] = __builtin_amdgcn_mfma_f32_16x16x32_bf16(af[m], bfr[n], acc[m][n], 0, 0, 0);
        }
        __syncthreads();
    }

    ushort* ohb = oh + (size_t)bl * QKV_B;
    ushort* olb = ol + (size_t)bl * QKV_B;
    #pragma unroll
    for (int m = 0; m < 4; m++) {
        int oc = m0 + wm * 64 + m * 16 + kg * 4;
        #pragma unroll
        for (int n = 0; n < 4; n++) {
            int col = n0 + wn * 64 + n * 16 + fr;
            #pragma unroll
            for (int r = 0; r < 4; r++) {
                if (oc + r < C3) {
                    float v = acc[m][n][r];
                    ushort hi = f2bf(v);
                    ohb[(size_t)(oc + r) * HWP + col] = hi;
                    olb[(size_t)(oc + r) * HWP + col] = f2bf(v - bf2f(hi));
                }
            }
        }
    }
}

// ============================================================
// depthwise 3x3 reading bf16 hi/lo t1; fused q/k hi-lo emission + L2 norm;
// v emitted fp32
// ============================================================
__global__ __launch_bounds__(256) void dw3x3_kernel(const ushort* __restrict__ inh,
    const ushort* __restrict__ inl, const float* __restrict__ wd,
    ushort* __restrict__ qh, ushort* __restrict__ ql,
    float* __restrict__ vv, float* __restrict__ inv, int b0)
{
    __shared__ float P[66][72];
    const int bc = blockIdx.x;          // bl*576 + ch
    const int bl = bc / C3, ch = bc % C3;
    const int b = b0 + bl;
    const int t = threadIdx.x;
    const ushort* iph = inh + (size_t)bc * HWP;
    const ushort* ipl = inl + (size_t)bc * HWP;
    float wr[9];
    #pragma unroll
    for (int k = 0; k < 9; k++) wr[k] = wd[ch * 9 + k];
    for (int i = t; i < 66 * 72; i += 256) ((float*)P)[i] = 0.f;
    __syncthreads();
    #pragma unroll
    for (int i = 0; i < 4; i++) {
        int u = t + 256 * i;
        int y = u >> 4, cg = u & 15;
        ushort4 h4 = *(const ushort4*)&iph[u * 4];
        ushort4 l4 = *(const ushort4*)&ipl[u * 4];
        P[1 + y][4 + cg * 4 + 0] = bf2f(h4.x) + bf2f(l4.x);
        P[1 + y][4 + cg * 4 + 1] = bf2f(h4.y) + bf2f(l4.y);
        P[1 + y][4 + cg * 4 + 2] = bf2f(h4.z) + bf2f(l4.z);
        P[1 + y][4 + cg * 4 + 3] = bf2f(h4.w) + bf2f(l4.w);
    }
    __syncthreads();

    float ssum = 0.f;
    #pragma unroll
    for (int i = 0; i < 4; i++) {
        int u = t + 256 * i;
        int y0 = u >> 4;
        int x0 = (u & 15) * 4;
        float res[4] = {0.f, 0.f, 0.f, 0.f};
        #pragma unroll
        for (int dy = 0; dy < 3; dy++) {
            float4 A = *(float4*)&P[y0 + dy][x0];
            float4 Bv = *(float4*)&P[y0 + dy][x0 + 4];
            float4 Cv = *(float4*)&P[y0 + dy][x0 + 8];
            float c0 = A.w, c1 = Bv.x, c2 = Bv.y, c3 = Bv.z, c4 = Bv.w, c5 = Cv.x;
            float w0 = wr[dy*3], w1 = wr[dy*3+1], w2 = wr[dy*3+2];
            res[0] += w0*c0 + w1*c1 + w2*c2;
            res[1] += w0*c1 + w1*c2 + w2*c3;
            res[2] += w0*c2 + w1*c3 + w2*c4;
            res[3] += w0*c3 + w1*c4 + w2*c5;
        }
        #pragma unroll
        for (int k = 0; k < 4; k++) ssum += res[k] * res[k];
        if (ch < 384) {
            ushort hi[4], lo[4];
            #pragma unroll
            for (int k = 0; k < 4; k++) {
                hi[k] = f2bf(res[k]);
                lo[k] = f2bf(res[k] - bf2f(hi[k]));
            }
            size_t base = ((size_t)b * 384 + ch) * HWP + u * 4;
            *(ushort4*)&qh[base] = make_ushort4(hi[0], hi[1], hi[2], hi[3]);
            *(ushort4*)&ql[base] = make_ushort4(lo[0], lo[1], lo[2], lo[3]);
        } else {
            *(float4*)&vv[((size_t)b * CC + (ch - 384)) * HWP + u * 4] =
                make_float4(res[0], res[1], res[2], res[3]);
        }
    }
    if (ch < 384) {
        #pragma unroll
        for (int off = 32; off > 0; off >>= 1) ssum += __shfl_down(ssum, off);
        __shared__ float red[4];
        if ((t & 63) == 0) red[t >> 6] = ssum;
        __syncthreads();
        if (t == 0) {
            float tot = red[0] + red[1] + red[2] + red[3];
            inv[b * 384 + ch] = 1.f / fmaxf(sqrtf(tot), 1e-12f);
        }
    }
}

// ============================================================
// stacked Gram via MFMA (proven round-3 kernel, unchanged)
// ============================================================
__global__ __launch_bounds__(256) void gram_mfma(const ushort* __restrict__ qhx,
    const ushort* __restrict__ qlx, const ushort* __restrict__ qhy,
    const ushort* __restrict__ qly, float* __restrict__ spart)
{
    __shared__ __align__(16) ushort As[96 * 64];
    __shared__ __align__(16) ushort Bs[96 * 64];
    const int chunk = blockIdx.x, bh = blockIdx.y;
    const int b = bh >> 2, h = bh & 3;
    const int t = threadIdx.x;
    const int lane = t & 63, w = t >> 6;
    const int wm = w >> 1, wn = w & 1;
    const int fr = lane & 15, kg = lane >> 4;

    const size_t qbase = ((size_t)b * 384 + h * DH) * HWP;
    const size_t kbase = ((size_t)b * 384 + 192 + h * DH) * HWP;

    f32x4 acc[3][3] = {};

    for (int term = 0; term < 3; term++) {
        const ushort* Aqx = (term == 2) ? qlx : qhx;
        const ushort* Aqy = (term == 2) ? qly : qhy;
        const ushort* Bkx = (term == 1) ? qlx : qhx;
        const ushort* Bky = (term == 1) ? qly : qhy;
        for (int ks = 0; ks < 8; ks++) {
            const int n0 = chunk * 512 + ks * 64;
            #pragma unroll
            for (int i = 0; i < 3; i++) {
                int u = i * 256 + w * 64 + lane;
                int r = u >> 3, c = u & 7;
                int cs = c ^ (r & 7);
                const ushort* ga = ((r < DH) ? (Aqx + qbase + (size_t)r * HWP)
                                             : (Aqy + qbase + (size_t)(r - DH) * HWP))
                                   + n0 + cs * 8;
                __builtin_amdgcn_global_load_lds(AS1(ga), AS3(&As[(size_t)(i * 4 + w) * 512]), 16, 0, 0);
                const ushort* gb = ((r < DH) ? (Bkx + kbase + (size_t)r * HWP)
                                             : (Bky + kbase + (size_t)(r - DH) * HWP))
                                   + n0 + cs * 8;
                __builtin_amdgcn_global_load_lds(AS1(gb), AS3(&Bs[(size_t)(i * 4 + w) * 512]), 16, 0, 0);
            }
            __syncthreads();
            #pragma unroll
            for (int kq = 0; kq < 8; kq += 4) {
                bf16x8 af[3], bfr[3];
                #pragma unroll
                for (int m = 0; m < 3; m++) {
                    int R = wm * DH + m * 16 + fr;
                    int unit = R * 8 + ((kq + kg) ^ (R & 7));
                    af[m] = *(const bf16x8*)&As[unit * 8];
                }
                #pragma unroll
                for (int n = 0; n < 3; n++) {
                    int R = wn * DH + n * 16 + fr;
                    int unit = R * 8 + ((kq + kg) ^ (R & 7));
                    bfr[n] = *(const bf16x8*)&Bs[unit * 8];
                }
                #pragma unroll
                for (int m = 0; m < 3; m++)
                    #pragma unroll
                    for (int n = 0; n < 3; n++)
                        acc[m][n] = __builtin_amdgcn_mfma_f32_16x16x32_bf16(af[m], bfr[n], acc[m][n], 0, 0, 0);
            }
            __syncthreads();
        }
    }

    float* sp = spart + ((size_t)chunk * 32 + bh) * 9216;
    #pragma unroll
    for (int m = 0; m < 3; m++) {
        int row = wm * DH + m * 16 + kg * 4;
        #pragma unroll
        for (int n = 0; n < 3; n++) {
            int col = wn * DH + n * 16 + fr;
            #pragma unroll
            for (int r = 0; r < 4; r++)
                sp[(row + r) * 96 + col] = acc[m][n][r];
        }
    }
}

// ============================================================
// combine split-K partials, scale, softmax; emit bf16 coefficient matrix
// M''(96 x 384) per bh: six BK=64 chunks [Mhx|Mhy|Mlx|Mly|Mhx|Mhy],
// cols 48..63 of each chunk zero-padded. Rows 0..47 cross, 48..95 self.
// ============================================================
__global__ __launch_bounds__(256) void softmax_kernel(const float* __restrict__ spart,
    const float* __restrict__ invx, const float* __restrict__ invy,
    const float* __restrict__ temp, ushort* __restrict__ mpp)
{
    __shared__ float G[96][97];
    const int bh = blockIdx.x, b = bh >> 2, h = bh & 3;
    const int t = threadIdx.x;
    const float ts = temp[h];
    for (int i = 0; i < 36; i++) {
        int f = t + 256 * i;
        float s = 0.f;
        #pragma unroll
        for (int cch = 0; cch < 8; cch++)
            s += spart[((size_t)cch * 32 + bh) * 9216 + f];
        int r = f / 96, c = f % 96;
        float iq = (r < DH) ? invx[b*384 + h*DH + r] : invy[b*384 + h*DH + (r-DH)];
        float ik = (c < DH) ? invx[b*384 + CC + h*DH + c] : invy[b*384 + CC + h*DH + (c-DH)];
        G[r][c] = s * iq * ik * ts;
    }
    __syncthreads();
    if (t < 192) {
        int r = t >> 1, hf = t & 1;
        float* rowp = &G[r][hf * DH];
        float m = rowp[0];
        for (int i = 1; i < DH; i++) m = fmaxf(m, rowp[i]);
        float s = 0.f;
        for (int i = 0; i < DH; i++) { float e = __expf(rowp[i] - m); rowp[i] = e; s += e; }
        float inv = 1.f / s;
        for (int i = 0; i < DH; i++) rowp[i] *= inv;
    }
    __syncthreads();
    ushort* mo = mpp + (size_t)bh * 96 * 384;
    // zero the pad columns (disjoint from value writes -> no sync needed)
    for (int i = 0; i < 36; i++) {
        int f = t + 256 * i;                 // 96 rows x 96 pad cols
        int r = f / 96, p = f % 96;
        int ch = p >> 4, j = p & 15;
        mo[(size_t)r * 384 + ch * 64 + 48 + j] = 0;
    }
    for (int i = 0; i < 36; i++) {
        int f = t + 256 * i;
        int r = f / 96, c = f % 96;
        float v;
        if (c < DH) v = (r < DH) ? G[DH + r][c] : G[r - DH][c];
        else        v = G[r][c];
        ushort hi = f2bf(v);
        ushort lo = f2bf(v - bf2f(hi));
        size_t rb = (size_t)r * 384;
        if (c < DH) {                        // x-half: chunks 0 (hi), 2 (lo), 4 (hi)
            mo[rb + c] = hi;
            mo[rb + 128 + c] = lo;
            mo[rb + 256 + c] = hi;
        } else {                             // y-half: chunks 1 (hi), 3 (lo), 5 (hi)
            int cp = c - DH;
            mo[rb + 64 + cp] = hi;
            mo[rb + 192 + cp] = lo;
            mo[rb + 320 + cp] = hi;
        }
    }
}

// ============================================================
// output GEMM via MFMA: Out(96 x 4096) = M''(96x384) * B'(384x4096) per bh
// B' chunks: [VTx-hi | VTy-hi | VTx-hi | VTy-hi | VTx-lo | VTy-lo] (head slice)
// tile 96(M) x 128(N), 4 waves 2x2 of 48x64; structure cloned from conv1x1_mfma
// ============================================================
__global__ __launch_bounds__(256) void outmm_mfma(const ushort* __restrict__ VTx,
    const ushort* __restrict__ VTy, const ushort* __restrict__ mpp,
    float* __restrict__ out)
{
    __shared__ __align__(16) ushort As[96 * 64];    // 12 KB
    __shared__ __align__(16) ushort Bs[128 * 64];   // 16 KB
    const int t = threadIdx.x;
    const int lane = t & 63, w = t >> 6;
    const int wm = w >> 1, wn = w & 1;
    const int fr = lane & 15, kg = lane >> 4;
    const int nc = blockIdx.x, bh = blockIdx.y;
    const int b = bh >> 2, h = bh & 3;
    const int n0 = nc * 128;
    const ushort* mp = mpp + (size_t)bh * 96 * 384;

    f32x4 acc[3][4] = {};

    for (int kc = 0; kc < 6; kc++) {
        const ushort* Vsrc = (kc & 1) ? VTy : VTx;
        const int coff = ((kc < 4) ? 0 : 192) + h * DH;
        #pragma unroll
        for (int i = 0; i < 3; i++) {                // A: 96 rows x 8 units
            int u = i * 256 + w * 64 + lane;
            int r = u >> 3, c = u & 7;
            int cs = c ^ (r & 7);
            const ushort* ga = mp + (size_t)r * 384 + kc * 64 + cs * 8;
            __builtin_amdgcn_global_load_lds(AS1(ga), AS3(&As[(size_t)(i * 4 + w) * 512]), 16, 0, 0);
        }
        #pragma unroll
        for (int i = 0; i < 4; i++) {                // B: 128 rows x 8 units
            int u = i * 256 + w * 64 + lane;
            int r = u >> 3, c = u & 7;
            int cs = c ^ (r & 7);
            const ushort* gb = Vsrc + ((size_t)(b * HWP + n0 + r)) * 384 + coff + cs * 8;
            __builtin_amdgcn_global_load_lds(AS1(gb), AS3(&Bs[(size_t)(i * 4 + w) * 512]), 16, 0, 0);
        }
        __syncthreads();
        #pragma unroll
        for (int kq = 0; kq < 8; kq += 4) {
            bf16x8 af[3], bfr[4];
            #pragma unroll
            for (int m = 0; m < 3; m++) {
                int R = wm * DH + m * 16 + fr;
                int unit = R * 8 + ((kq + kg) ^ (R & 7));
                af[m] = *(const bf16x8*)&As[unit * 8];
            }
            #pragma unroll
            for (int n = 0; n < 4; n++) {
                int R = wn * 64 + n * 16 + fr;
                int unit = R * 8 + ((kq + kg) ^ (R & 7));
                bfr[n] = *(const bf16x8*)&Bs[unit * 8];
            }
            #pragma unroll
            for (int m = 0; m < 3; m++)
                #pragma unroll
                for (int n = 0; n < 4; n++)
                    acc[m][n] = __builtin_amdgcn_mfma_f32_16x16x32_bf16(af[m], bfr[n], acc[m][n], 0, 0, 0);
        }
        __syncthreads();
    }

    #pragma unroll
    for (int m = 0; m < 3; m++) {
        int row = wm * DH + m * 16 + kg * 4;
        #pragma unroll
        for (int n = 0; n < 4; n++) {
            int col = n0 + wn * 64 + n * 16 + fr;
            #pragma unroll
            for (int r = 0; r < 4; r++) {
                int rr = row + r;
                float* dst = (rr < DH)
                    ? (out + (size_t)b * X_B + (h * DH + rr) * HWP + col)
                    : (out + OUT_HALF + (size_t)b * X_B + (h * DH + rr - DH) * HWP + col);
                *dst = acc[m][n][r];
            }
        }
    }
}

// ============================================================
extern "C" void kernel_launch(void* const* d_in, const int* in_sizes, int n_in,
                              void* d_out, int out_size, void* d_ws, size_t ws_size,
                              hipStream_t stream)
{
    const float* x  = (const float*)d_in[0];
    const float* y  = (const float*)d_in[1];
    const float* wq = (const float*)d_in[2];
    const float* wd = (const float*)d_in[3];
    const float* tp = (const float*)d_in[4];
    float* out = (float*)d_out;
    float* ws = (float*)d_ws;

    const size_t QKF = 6291456;   // floats per q/k hi-or-lo ushort array (25.2 MB)
    const size_t VF  = 6291456;   // floats per v fp32 array
    const size_t T1F = 9437184;   // t1 region floats (37.7 MB)
    const size_t XTF = 6291456;   // XT ushort array in floats
    const size_t WCF = 122880;

    ushort* qhx = (ushort*)ws;
    ushort* qlx = (ushort*)(ws + QKF);
    ushort* qhy = (ushort*)(ws + 2 * QKF);
    ushort* qly = (ushort*)(ws + 3 * QKF);
    float*  vx  = ws + 4 * QKF;
    float*  vy  = vx + VF;
    float*  t1r = vy + VF;                        // 9.44M floats
    ushort* t1hh = (ushort*)t1r;                  // [4]*576*4096 ushorts
    ushort* t1hl = t1hh + (size_t)4 * QKV_B;
    ushort* XT  = (ushort*)(t1r + T1F);
    ushort* Wc  = (ushort*)(t1r + T1F + XTF);
    float*  invx = t1r + T1F + XTF + WCF;
    float*  invy = invx + 3072;
    // aliases into t1 region (dead after last dw):
    ushort* VTy  = (ushort*)t1r;                                  // 6.29M floats
    float*  spart = t1r + 6291456;                                // 2.36M floats
    ushort* Mpp  = (ushort*)(t1r + 6291456 + 2359296);            // 0.59M floats
    // alias over dead XT:
    ushort* VTx  = XT;

    wconvert_kernel<<<240, 256, 0, stream>>>(wq, Wc);

    // tensor x
    convert_kernel<<<dim3(64, 3, BB), 256, 0, stream>>>(x, XT);
    conv1x1_mfma<<<dim3(128, 5), 256, 0, stream>>>(XT, Wc, t1hh, t1hl, 0);
    dw3x3_kernel<<<4 * C3, 256, 0, stream>>>(t1hh, t1hl, wd, qhx, qlx, vx, invx, 0);
    conv1x1_mfma<<<dim3(128, 5), 256, 0, stream>>>(XT, Wc, t1hh, t1hl, 4);
    dw3x3_kernel<<<4 * C3, 256, 0, stream>>>(t1hh, t1hl, wd, qhx, qlx, vx, invx, 4);

    // tensor y
    convert_kernel<<<dim3(64, 3, BB), 256, 0, stream>>>(y, XT);
    conv1x1_mfma<<<dim3(128, 5), 256, 0, stream>>>(XT, Wc, t1hh, t1hl, 0);
    dw3x3_kernel<<<4 * C3, 256, 0, stream>>>(t1hh, t1hl, wd, qhy, qly, vy, invy, 0);
    conv1x1_mfma<<<dim3(128, 5), 256, 0, stream>>>(XT, Wc, t1hh, t1hl, 4);
    dw3x3_kernel<<<4 * C3, 256, 0, stream>>>(t1hh, t1hl, wd, qhy, qly, vy, invy, 4);

    // transpose v to XT-format (reuses proven convert kernel); VTx over dead XT,
    // VTy over dead t1
    convert_kernel<<<dim3(64, 3, BB), 256, 0, stream>>>(vx, VTx);
    convert_kernel<<<dim3(64, 3, BB), 256, 0, stream>>>(vy, VTy);

    gram_mfma<<<dim3(8, 32), 256, 0, stream>>>(qhx, qlx, qhy, qly, spart);
    softmax_kernel<<<32, 256, 0, stream>>>(spart, invx, invy, tp, Mpp);
    outmm_mfma<<<dim3(HWP / 128, 32), 256, 0, stream>>>(VTx, VTy, Mpp, out);
}

// Round 5
// 310.916 us; speedup vs baseline: 1.0145x; 1.0145x over previous
//
#include <hip/hip_runtime.h>

// ---- problem constants ----
#define CC   192                 // C
#define C3   576                 // 3C
#define HH   64
#define WW   64
#define HWP  4096                // H*W
#define BB   8
#define DH   48                  // C/HEADS
#define QKV_B (C3*HWP)           // elements per batch of conv-out tensor
#define X_B   (CC*HWP)
#define OUT_HALF ((size_t)BB*X_B)

typedef short bf16x8 __attribute__((ext_vector_type(8)));
typedef float f32x4  __attribute__((ext_vector_type(4)));

#define AS1(p) ((__attribute__((address_space(1))) void*)(p))
#define AS3(p) ((__attribute__((address_space(3))) void*)(p))

__device__ __forceinline__ ushort f2bf(float v) {
    union { float f; unsigned u; } a; a.f = v;
    unsigned r = a.u + 0x7FFF + ((a.u >> 16) & 1);   // RNE
    return (ushort)(r >> 16);
}
__device__ __forceinline__ float bf2f(ushort h) {
    union { float f; unsigned u; } a; a.u = ((unsigned)h) << 16; return a.f;
}

// ============================================================
// in (b,192,4096) fp32 -> out (b,4096,384) bf16: cols 0..191 hi, 192..383 lo
// (used for x, y, and for transposing vx, vy)
// ============================================================
__global__ __launch_bounds__(256) void convert_kernel(const float* __restrict__ in,
    ushort* __restrict__ xt)
{
    __shared__ float L[64][65];
    const int n0 = blockIdx.x * 64, c0 = blockIdx.y * 64, b = blockIdx.z;
    const int t = threadIdx.x;
    const float* ip = in + (size_t)b * X_B;
    #pragma unroll
    for (int i = 0; i < 16; i++) {
        int e = t + 256 * i;
        int r = e >> 6, col = e & 63;
        L[r][col] = ip[(size_t)(c0 + r) * HWP + n0 + col];
    }
    __syncthreads();
    #pragma unroll
    for (int i = 0; i < 4; i++) {
        int e = t + 256 * i;
        int n = e >> 4, c4 = e & 15;
        ushort hi[4], lo[4];
        #pragma unroll
        for (int j = 0; j < 4; j++) {
            float v = L[c4 * 4 + j][n];
            hi[j] = f2bf(v);
            lo[j] = f2bf(v - bf2f(hi[j]));
        }
        size_t base = ((size_t)(b * HWP + n0 + n)) * 384 + c0 + c4 * 4;
        *(ushort4*)&xt[base]       = make_ushort4(hi[0], hi[1], hi[2], hi[3]);
        *(ushort4*)&xt[base + 192] = make_ushort4(lo[0], lo[1], lo[2], lo[3]);
    }
}

// ============================================================
// w_qkv -> Wc(640,384) bf16 hi|lo, zero-padded rows
// ============================================================
__global__ __launch_bounds__(256) void wconvert_kernel(const float* __restrict__ wq,
    ushort* __restrict__ wc)
{
    int e = (blockIdx.x * 256 + threadIdx.x) * 4;
    int oc = e / 384, k = e % 384;
    ushort o[4] = {0, 0, 0, 0};
    if (oc < C3) {
        int kk = (k < 192) ? k : (k - 192);
        #pragma unroll
        for (int j = 0; j < 4; j++) {
            float v = wq[oc * CC + kk + j];
            ushort h = f2bf(v);
            o[j] = (k < 192) ? h : f2bf(v - bf2f(h));
        }
    }
    *(ushort4*)&wc[e] = make_ushort4(o[0], o[1], o[2], o[3]);
}

// ============================================================
// conv1x1 via MFMA; epilogue writes PACKED (lo<<16|hi) uint per element
// -> single 4B store, same segment pattern as the proven fp32 epilogue
// ============================================================
__global__ __launch_bounds__(256) void conv1x1_mfma(const ushort* __restrict__ XT,
    const ushort* __restrict__ Wc, unsigned* __restrict__ op, int b0)
{
    __shared__ __align__(16) ushort Asb[128 * 64];
    __shared__ __align__(16) ushort Bsb[128 * 64];
    const int t = threadIdx.x;
    const int lane = t & 63, w = t >> 6;
    const int wm = w >> 1, wn = w & 1;
    const int fr = lane & 15, kg = lane >> 4;
    const int nt = blockIdx.x;
    const int bl = nt >> 5;
    const int n0 = (nt & 31) * 128;
    const int m0 = blockIdx.y * 128;
    const int bg = b0 + bl;

    f32x4 acc[4][4] = {};
    const int ur = w * 64 + lane;

    for (int kc = 0; kc < 9; kc++) {
        int kmod = (kc < 3) ? kc : ((kc < 6) ? kc - 3 : kc - 6);
        int cA = ((kc < 6) ? 0 : 192) + kmod * 64;
        int cB = ((kc >= 3 && kc < 6) ? 192 : 0) + kmod * 64;
        #pragma unroll
        for (int i = 0; i < 4; i++) {
            int u = i * 256 + ur;
            int r = u >> 3, c = u & 7;
            int cs = c ^ (r & 7);
            const ushort* ga = Wc + (size_t)(m0 + r) * 384 + cA + cs * 8;
            __builtin_amdgcn_global_load_lds(AS1(ga), AS3(&Asb[(size_t)(i * 4 + w) * 512]), 16, 0, 0);
            const ushort* gb = XT + ((size_t)(bg * HWP + n0 + r)) * 384 + cB + cs * 8;
            __builtin_amdgcn_global_load_lds(AS1(gb), AS3(&Bsb[(size_t)(i * 4 + w) * 512]), 16, 0, 0);
        }
        __syncthreads();
        #pragma unroll
        for (int kq = 0; kq < 8; kq += 4) {
            bf16x8 af[4], bfr[4];
            #pragma unroll
            for (int m = 0; m < 4; m++) {
                int R = wm * 64 + m * 16 + fr;
                int unit = R * 8 + ((kq + kg) ^ (R & 7));
                af[m] = *(const bf16x8*)&Asb[unit * 8];
            }
            #pragma unroll
            for (int n = 0; n < 4; n++) {
                int R = wn * 64 + n * 16 + fr;
                int unit = R * 8 + ((kq + kg) ^ (R & 7));
                bfr[n] = *(const bf16x8*)&Bsb[unit * 8];
            }
            #pragma unroll
            for (int m = 0; m < 4; m++)
                #pragma unroll
                for (int n = 0; n < 4; n++)
                    acc[m][n] = __builtin_amdgcn_mfma_f32_16x16x32_bf16(af[m], bfr[n], acc[m][n], 0, 0, 0);
        }
        __syncthreads();
    }

    unsigned* ob = op + (size_t)bl * QKV_B;
    #pragma unroll
    for (int m = 0; m < 4; m++) {
        int oc = m0 + wm * 64 + m * 16 + kg * 4;
        #pragma unroll
        for (int n = 0; n < 4; n++) {
            int col = n0 + wn * 64 + n * 16 + fr;
            #pragma unroll
            for (int r = 0; r < 4; r++) {
                if (oc + r < C3) {
                    float v = acc[m][n][r];
                    ushort hi = f2bf(v);
                    ushort lo = f2bf(v - bf2f(hi));
                    ob[(size_t)(oc + r) * HWP + col] = ((unsigned)lo << 16) | hi;
                }
            }
        }
    }
}

// ============================================================
// depthwise 3x3 reading packed-uint t1; fused q/k hi-lo emission + L2 norm;
// v emitted fp32
// ============================================================
__global__ __launch_bounds__(256) void dw3x3_kernel(const unsigned* __restrict__ inp,
    const float* __restrict__ wd,
    ushort* __restrict__ qh, ushort* __restrict__ ql,
    float* __restrict__ vv, float* __restrict__ inv, int b0)
{
    __shared__ float P[66][72];
    const int bc = blockIdx.x;          // bl*576 + ch
    const int bl = bc / C3, ch = bc % C3;
    const int b = b0 + bl;
    const int t = threadIdx.x;
    const unsigned* ip = inp + (size_t)bc * HWP;
    float wr[9];
    #pragma unroll
    for (int k = 0; k < 9; k++) wr[k] = wd[ch * 9 + k];
    for (int i = t; i < 66 * 72; i += 256) ((float*)P)[i] = 0.f;
    __syncthreads();
    #pragma unroll
    for (int i = 0; i < 4; i++) {
        int u = t + 256 * i;
        int y = u >> 4, cg = u & 15;
        uint4 p4 = *(const uint4*)&ip[u * 4];
        P[1 + y][4 + cg * 4 + 0] = bf2f((ushort)(p4.x & 0xFFFF)) + bf2f((ushort)(p4.x >> 16));
        P[1 + y][4 + cg * 4 + 1] = bf2f((ushort)(p4.y & 0xFFFF)) + bf2f((ushort)(p4.y >> 16));
        P[1 + y][4 + cg * 4 + 2] = bf2f((ushort)(p4.z & 0xFFFF)) + bf2f((ushort)(p4.z >> 16));
        P[1 + y][4 + cg * 4 + 3] = bf2f((ushort)(p4.w & 0xFFFF)) + bf2f((ushort)(p4.w >> 16));
    }
    __syncthreads();

    float ssum = 0.f;
    #pragma unroll
    for (int i = 0; i < 4; i++) {
        int u = t + 256 * i;
        int y0 = u >> 4;
        int x0 = (u & 15) * 4;
        float res[4] = {0.f, 0.f, 0.f, 0.f};
        #pragma unroll
        for (int dy = 0; dy < 3; dy++) {
            float4 A = *(float4*)&P[y0 + dy][x0];
            float4 Bv = *(float4*)&P[y0 + dy][x0 + 4];
            float4 Cv = *(float4*)&P[y0 + dy][x0 + 8];
            float c0 = A.w, c1 = Bv.x, c2 = Bv.y, c3 = Bv.z, c4 = Bv.w, c5 = Cv.x;
            float w0 = wr[dy*3], w1 = wr[dy*3+1], w2 = wr[dy*3+2];
            res[0] += w0*c0 + w1*c1 + w2*c2;
            res[1] += w0*c1 + w1*c2 + w2*c3;
            res[2] += w0*c2 + w1*c3 + w2*c4;
            res[3] += w0*c3 + w1*c4 + w2*c5;
        }
        #pragma unroll
        for (int k = 0; k < 4; k++) ssum += res[k] * res[k];
        if (ch < 384) {
            ushort hi[4], lo[4];
            #pragma unroll
            for (int k = 0; k < 4; k++) {
                hi[k] = f2bf(res[k]);
                lo[k] = f2bf(res[k] - bf2f(hi[k]));
            }
            size_t base = ((size_t)b * 384 + ch) * HWP + u * 4;
            *(ushort4*)&qh[base] = make_ushort4(hi[0], hi[1], hi[2], hi[3]);
            *(ushort4*)&ql[base] = make_ushort4(lo[0], lo[1], lo[2], lo[3]);
        } else {
            *(float4*)&vv[((size_t)b * CC + (ch - 384)) * HWP + u * 4] =
                make_float4(res[0], res[1], res[2], res[3]);
        }
    }
    if (ch < 384) {
        #pragma unroll
        for (int off = 32; off > 0; off >>= 1) ssum += __shfl_down(ssum, off);
        __shared__ float red[4];
        if ((t & 63) == 0) red[t >> 6] = ssum;
        __syncthreads();
        if (t == 0) {
            float tot = red[0] + red[1] + red[2] + red[3];
            inv[b * 384 + ch] = 1.f / fmaxf(sqrtf(tot), 1e-12f);
        }
    }
}

// ============================================================
// stacked Gram via MFMA (proven, unchanged)
// ============================================================
__global__ __launch_bounds__(256) void gram_mfma(const ushort* __restrict__ qhx,
    const ushort* __restrict__ qlx, const ushort* __restrict__ qhy,
    const ushort* __restrict__ qly, float* __restrict__ spart)
{
    __shared__ __align__(16) ushort As[96 * 64];
    __shared__ __align__(16) ushort Bs[96 * 64];
    const int chunk = blockIdx.x, bh = blockIdx.y;
    const int b = bh >> 2, h = bh & 3;
    const int t = threadIdx.x;
    const int lane = t & 63, w = t >> 6;
    const int wm = w >> 1, wn = w & 1;
    const int fr = lane & 15, kg = lane >> 4;

    const size_t qbase = ((size_t)b * 384 + h * DH) * HWP;
    const size_t kbase = ((size_t)b * 384 + 192 + h * DH) * HWP;

    f32x4 acc[3][3] = {};

    for (int term = 0; term < 3; term++) {
        const ushort* Aqx = (term == 2) ? qlx : qhx;
        const ushort* Aqy = (term == 2) ? qly : qhy;
        const ushort* Bkx = (term == 1) ? qlx : qhx;
        const ushort* Bky = (term == 1) ? qly : qhy;
        for (int ks = 0; ks < 8; ks++) {
            const int n0 = chunk * 512 + ks * 64;
            #pragma unroll
            for (int i = 0; i < 3; i++) {
                int u = i * 256 + w * 64 + lane;
                int r = u >> 3, c = u & 7;
                int cs = c ^ (r & 7);
                const ushort* ga = ((r < DH) ? (Aqx + qbase + (size_t)r * HWP)
                                             : (Aqy + qbase + (size_t)(r - DH) * HWP))
                                   + n0 + cs * 8;
                __builtin_amdgcn_global_load_lds(AS1(ga), AS3(&As[(size_t)(i * 4 + w) * 512]), 16, 0, 0);
                const ushort* gb = ((r < DH) ? (Bkx + kbase + (size_t)r * HWP)
                                             : (Bky + kbase + (size_t)(r - DH) * HWP))
                                   + n0 + cs * 8;
                __builtin_amdgcn_global_load_lds(AS1(gb), AS3(&Bs[(size_t)(i * 4 + w) * 512]), 16, 0, 0);
            }
            __syncthreads();
            #pragma unroll
            for (int kq = 0; kq < 8; kq += 4) {
                bf16x8 af[3], bfr[3];
                #pragma unroll
                for (int m = 0; m < 3; m++) {
                    int R = wm * DH + m * 16 + fr;
                    int unit = R * 8 + ((kq + kg) ^ (R & 7));
                    af[m] = *(const bf16x8*)&As[unit * 8];
                }
                #pragma unroll
                for (int n = 0; n < 3; n++) {
                    int R = wn * DH + n * 16 + fr;
                    int unit = R * 8 + ((kq + kg) ^ (R & 7));
                    bfr[n] = *(const bf16x8*)&Bs[unit * 8];
                }
                #pragma unroll
                for (int m = 0; m < 3; m++)
                    #pragma unroll
                    for (int n = 0; n < 3; n++)
                        acc[m][n] = __builtin_amdgcn_mfma_f32_16x16x32_bf16(af[m], bfr[n], acc[m][n], 0, 0, 0);
            }
            __syncthreads();
        }
    }

    float* sp = spart + ((size_t)chunk * 32 + bh) * 9216;
    #pragma unroll
    for (int m = 0; m < 3; m++) {
        int row = wm * DH + m * 16 + kg * 4;
        #pragma unroll
        for (int n = 0; n < 3; n++) {
            int col = wn * DH + n * 16 + fr;
            #pragma unroll
            for (int r = 0; r < 4; r++)
                sp[(row + r) * 96 + col] = acc[m][n][r];
        }
    }
}

// ============================================================
// combine split-K partials, scale, softmax; emit bf16 coefficient matrix
// M''(96 x 384): six BK=64 chunks [Mhx|Mhy|Mlx|Mly|Mhx|Mhy], pad cols zeroed
// ============================================================
__global__ __launch_bounds__(256) void softmax_kernel(const float* __restrict__ spart,
    const float* __restrict__ invx, const float* __restrict__ invy,
    const float* __restrict__ temp, ushort* __restrict__ mpp)
{
    __shared__ float G[96][97];
    const int bh = blockIdx.x, b = bh >> 2, h = bh & 3;
    const int t = threadIdx.x;
    const float ts = temp[h];
    for (int i = 0; i < 36; i++) {
        int f = t + 256 * i;
        float s = 0.f;
        #pragma unroll
        for (int cch = 0; cch < 8; cch++)
            s += spart[((size_t)cch * 32 + bh) * 9216 + f];
        int r = f / 96, c = f % 96;
        float iq = (r < DH) ? invx[b*384 + h*DH + r] : invy[b*384 + h*DH + (r-DH)];
        float ik = (c < DH) ? invx[b*384 + CC + h*DH + c] : invy[b*384 + CC + h*DH + (c-DH)];
        G[r][c] = s * iq * ik * ts;
    }
    __syncthreads();
    if (t < 192) {
        int r = t >> 1, hf = t & 1;
        float* rowp = &G[r][hf * DH];
        float m = rowp[0];
        for (int i = 1; i < DH; i++) m = fmaxf(m, rowp[i]);
        float s = 0.f;
        for (int i = 0; i < DH; i++) { float e = __expf(rowp[i] - m); rowp[i] = e; s += e; }
        float inv = 1.f / s;
        for (int i = 0; i < DH; i++) rowp[i] *= inv;
    }
    __syncthreads();
    ushort* mo = mpp + (size_t)bh * 96 * 384;
    for (int i = 0; i < 36; i++) {
        int f = t + 256 * i;                 // 96 rows x 96 pad cols
        int r = f / 96, p = f % 96;
        int ch = p >> 4, j = p & 15;
        mo[(size_t)r * 384 + ch * 64 + 48 + j] = 0;
    }
    for (int i = 0; i < 36; i++) {
        int f = t + 256 * i;
        int r = f / 96, c = f % 96;
        float v;
        if (c < DH) v = (r < DH) ? G[DH + r][c] : G[r - DH][c];
        else        v = G[r][c];
        ushort hi = f2bf(v);
        ushort lo = f2bf(v - bf2f(hi));
        size_t rb = (size_t)r * 384;
        if (c < DH) {
            mo[rb + c] = hi;
            mo[rb + 128 + c] = lo;
            mo[rb + 256 + c] = hi;
        } else {
            int cp = c - DH;
            mo[rb + 64 + cp] = hi;
            mo[rb + 192 + cp] = lo;
            mo[rb + 320 + cp] = hi;
        }
    }
}

// ============================================================
// output GEMM via MFMA (proven, unchanged)
// ============================================================
__global__ __launch_bounds__(256) void outmm_mfma(const ushort* __restrict__ VTx,
    const ushort* __restrict__ VTy, const ushort* __restrict__ mpp,
    float* __restrict__ out)
{
    __shared__ __align__(16) ushort As[96 * 64];
    __shared__ __align__(16) ushort Bs[128 * 64];
    const int t = threadIdx.x;
    const int lane = t & 63, w = t >> 6;
    const int wm = w >> 1, wn = w & 1;
    const int fr = lane & 15, kg = lane >> 4;
    const int nc = blockIdx.x, bh = blockIdx.y;
    const int b = bh >> 2, h = bh & 3;
    const int n0 = nc * 128;
    const ushort* mp = mpp + (size_t)bh * 96 * 384;

    f32x4 acc[3][4] = {};

    for (int kc = 0; kc < 6; kc++) {
        const ushort* Vsrc = (kc & 1) ? VTy : VTx;
        const int coff = ((kc < 4) ? 0 : 192) + h * DH;
        #pragma unroll
        for (int i = 0; i < 3; i++) {
            int u = i * 256 + w * 64 + lane;
            int r = u >> 3, c = u & 7;
            int cs = c ^ (r & 7);
            const ushort* ga = mp + (size_t)r * 384 + kc * 64 + cs * 8;
            __builtin_amdgcn_global_load_lds(AS1(ga), AS3(&As[(size_t)(i * 4 + w) * 512]), 16, 0, 0);
        }
        #pragma unroll
        for (int i = 0; i < 4; i++) {
            int u = i * 256 + w * 64 + lane;
            int r = u >> 3, c = u & 7;
            int cs = c ^ (r & 7);
            const ushort* gb = Vsrc + ((size_t)(b * HWP + n0 + r)) * 384 + coff + cs * 8;
            __builtin_amdgcn_global_load_lds(AS1(gb), AS3(&Bs[(size_t)(i * 4 + w) * 512]), 16, 0, 0);
        }
        __syncthreads();
        #pragma unroll
        for (int kq = 0; kq < 8; kq += 4) {
            bf16x8 af[3], bfr[4];
            #pragma unroll
            for (int m = 0; m < 3; m++) {
                int R = wm * DH + m * 16 + fr;
                int unit = R * 8 + ((kq + kg) ^ (R & 7));
                af[m] = *(const bf16x8*)&As[unit * 8];
            }
            #pragma unroll
            for (int n = 0; n < 4; n++) {
                int R = wn * 64 + n * 16 + fr;
                int unit = R * 8 + ((kq + kg) ^ (R & 7));
                bfr[n] = *(const bf16x8*)&Bs[unit * 8];
            }
            #pragma unroll
            for (int m = 0; m < 3; m++)
                #pragma unroll
                for (int n = 0; n < 4; n++)
                    acc[m][n] = __builtin_amdgcn_mfma_f32_16x16x32_bf16(af[m], bfr[n], acc[m][n], 0, 0, 0);
        }
        __syncthreads();
    }

    #pragma unroll
    for (int m = 0; m < 3; m++) {
        int row = wm * DH + m * 16 + kg * 4;
        #pragma unroll
        for (int n = 0; n < 4; n++) {
            int col = n0 + wn * 64 + n * 16 + fr;
            #pragma unroll
            for (int r = 0; r < 4; r++) {
                int rr = row + r;
                float* dst = (rr < DH)
                    ? (out + (size_t)b * X_B + (h * DH + rr) * HWP + col)
                    : (out + OUT_HALF + (size_t)b * X_B + (h * DH + rr - DH) * HWP + col);
                *dst = acc[m][n][r];
            }
        }
    }
}

// ============================================================
extern "C" void kernel_launch(void* const* d_in, const int* in_sizes, int n_in,
                              void* d_out, int out_size, void* d_ws, size_t ws_size,
                              hipStream_t stream)
{
    const float* x  = (const float*)d_in[0];
    const float* y  = (const float*)d_in[1];
    const float* wq = (const float*)d_in[2];
    const float* wd = (const float*)d_in[3];
    const float* tp = (const float*)d_in[4];
    float* out = (float*)d_out;
    float* ws = (float*)d_ws;

    const size_t QKF = 6291456;   // floats per q/k hi-or-lo ushort array (25.2 MB)
    const size_t VF  = 6291456;   // floats per v fp32 array
    const size_t T1F = 9437184;   // t1 region floats (37.7 MB)
    const size_t XTF = 6291456;   // XT ushort array in floats
    const size_t WCF = 122880;

    ushort* qhx = (ushort*)ws;
    ushort* qlx = (ushort*)(ws + QKF);
    ushort* qhy = (ushort*)(ws + 2 * QKF);
    ushort* qly = (ushort*)(ws + 3 * QKF);
    float*  vx  = ws + 4 * QKF;
    float*  vy  = vx + VF;
    float*  t1r = vy + VF;                        // 9.44M floats
    unsigned* t1p = (unsigned*)t1r;               // [4]*576*4096 packed uints
    ushort* XT  = (ushort*)(t1r + T1F);
    ushort* Wc  = (ushort*)(t1r + T1F + XTF);
    float*  invx = t1r + T1F + XTF + WCF;
    float*  invy = invx + 3072;
    // aliases into t1 region (dead after last dw):
    ushort* VTy  = (ushort*)t1r;                                  // 6.29M floats
    float*  spart = t1r + 6291456;                                // 2.36M floats
    ushort* Mpp  = (ushort*)(t1r + 6291456 + 2359296);            // 0.59M floats
    // alias over dead XT:
    ushort* VTx  = XT;

    wconvert_kernel<<<240, 256, 0, stream>>>(wq, Wc);

    // tensor x
    convert_kernel<<<dim3(64, 3, BB), 256, 0, stream>>>(x, XT);
    conv1x1_mfma<<<dim3(128, 5), 256, 0, stream>>>(XT, Wc, t1p, 0);
    dw3x3_kernel<<<4 * C3, 256, 0, stream>>>(t1p, wd, qhx, qlx, vx, invx, 0);
    conv1x1_mfma<<<dim3(128, 5), 256, 0, stream>>>(XT, Wc, t1p, 4);
    dw3x3_kernel<<<4 * C3, 256, 0, stream>>>(t1p, wd, qhx, qlx, vx, invx, 4);

    // tensor y
    convert_kernel<<<dim3(64, 3, BB), 256, 0, stream>>>(y, XT);
    conv1x1_mfma<<<dim3(128, 5), 256, 0, stream>>>(XT, Wc, t1p, 0);
    dw3x3_kernel<<<4 * C3, 256, 0, stream>>>(t1p, wd, qhy, qly, vy, invy, 0);
    conv1x1_mfma<<<dim3(128, 5), 256, 0, stream>>>(XT, Wc, t1p, 4);
    dw3x3_kernel<<<4 * C3, 256, 0, stream>>>(t1p, wd, qhy, qly, vy, invy, 4);

    // transpose v to XT-format; VTx over dead XT, VTy over dead t1
    convert_kernel<<<dim3(64, 3, BB), 256, 0, stream>>>(vx, VTx);
    convert_kernel<<<dim3(64, 3, BB), 256, 0, stream>>>(vy, VTy);

    gram_mfma<<<dim3(8, 32), 256, 0, stream>>>(qhx, qlx, qhy, qly, spart);
    softmax_kernel<<<32, 256, 0, stream>>>(spart, invx, invy, tp, Mpp);
    outmm_mfma<<<dim3(HWP / 128, 32), 256, 0, stream>>>(VTx, VTy, Mpp, out);
}

// Round 7
// 300.540 us; speedup vs baseline: 1.0496x; 1.0345x over previous
//
#include <hip/hip_runtime.h>

// ---- problem constants ----
#define CC   192                 // C
#define C3   576                 // 3C
#define HH   64
#define WW   64
#define HWP  4096                // H*W
#define BB   8
#define DH   48                  // C/HEADS
#define QKV_B (C3*HWP)           // elements per batch of conv-out tensor
#define X_B   (CC*HWP)
#define OUT_HALF ((size_t)BB*X_B)

typedef short bf16x8 __attribute__((ext_vector_type(8)));
typedef float f32x4  __attribute__((ext_vector_type(4)));

#define AS1(p) ((__attribute__((address_space(1))) void*)(p))
#define AS3(p) ((__attribute__((address_space(3))) void*)(p))

__device__ __forceinline__ ushort f2bf(float v) {
    union { float f; unsigned u; } a; a.f = v;
    unsigned r = a.u + 0x7FFF + ((a.u >> 16) & 1);   // RNE
    return (ushort)(r >> 16);
}
__device__ __forceinline__ float bf2f(ushort h) {
    union { float f; unsigned u; } a; a.u = ((unsigned)h) << 16; return a.f;
}

// ============================================================
// in (b,192,4096) fp32 -> out (b,4096,384) bf16: cols 0..191 hi, 192..383 lo
// (used for x, y, and for transposing vx, vy)
// ============================================================
__global__ __launch_bounds__(256) void convert_kernel(const float* __restrict__ in,
    ushort* __restrict__ xt)
{
    __shared__ float L[64][65];
    const int n0 = blockIdx.x * 64, c0 = blockIdx.y * 64, b = blockIdx.z;
    const int t = threadIdx.x;
    const float* ip = in + (size_t)b * X_B;
    #pragma unroll
    for (int i = 0; i < 16; i++) {
        int e = t + 256 * i;
        int r = e >> 6, col = e & 63;
        L[r][col] = ip[(size_t)(c0 + r) * HWP + n0 + col];
    }
    __syncthreads();
    #pragma unroll
    for (int i = 0; i < 4; i++) {
        int e = t + 256 * i;
        int n = e >> 4, c4 = e & 15;
        ushort hi[4], lo[4];
        #pragma unroll
        for (int j = 0; j < 4; j++) {
            float v = L[c4 * 4 + j][n];
            hi[j] = f2bf(v);
            lo[j] = f2bf(v - bf2f(hi[j]));
        }
        size_t base = ((size_t)(b * HWP + n0 + n)) * 384 + c0 + c4 * 4;
        *(ushort4*)&xt[base]       = make_ushort4(hi[0], hi[1], hi[2], hi[3]);
        *(ushort4*)&xt[base + 192] = make_ushort4(lo[0], lo[1], lo[2], lo[3]);
    }
}

// ============================================================
// w_qkv -> Wc(640,384) bf16 hi|lo, zero-padded rows
// ============================================================
__global__ __launch_bounds__(256) void wconvert_kernel(const float* __restrict__ wq,
    ushort* __restrict__ wc)
{
    int e = (blockIdx.x * 256 + threadIdx.x) * 4;
    int oc = e / 384, k = e % 384;
    ushort o[4] = {0, 0, 0, 0};
    if (oc < C3) {
        int kk = (k < 192) ? k : (k - 192);
        #pragma unroll
        for (int j = 0; j < 4; j++) {
            float v = wq[oc * CC + kk + j];
            ushort h = f2bf(v);
            o[j] = (k < 192) ? h : f2bf(v - bf2f(h));
        }
    }
    *(ushort4*)&wc[e] = make_ushort4(o[0], o[1], o[2], o[3]);
}

// ============================================================
// conv1x1 via MFMA, 2-phase double-buffered (T3 minimum recipe):
// issue STAGE(buf^1, kc+1) BEFORE computing tile kc; one barrier per iter
// (the compiler's vmcnt(0)+barrier at loop end completes the prefetch,
//  which by then has been covered by 128 MFMAs of compute).
// 4 batches per launch (b0 = 0 or 4), grid (128, 5). Packed (lo<<16|hi) out.
// ============================================================
__global__ __launch_bounds__(256) void conv1x1_mfma(const ushort* __restrict__ XT,
    const ushort* __restrict__ Wc, unsigned* __restrict__ op, int b0)
{
    __shared__ __align__(16) ushort Asb[2][128 * 64];   // 2 x 16 KB
    __shared__ __align__(16) ushort Bsb[2][128 * 64];   // 2 x 16 KB
    const int t = threadIdx.x;
    const int lane = t & 63, w = t >> 6;
    const int wm = w >> 1, wn = w & 1;
    const int fr = lane & 15, kg = lane >> 4;
    const int nt = blockIdx.x;
    const int bl = nt >> 5;                    // local batch 0..3
    const int n0 = (nt & 31) * 128;
    const int m0 = blockIdx.y * 128;
    const int bg = b0 + bl;
    const int ur = w * 64 + lane;

    f32x4 acc[4][4] = {};

    auto STAGE = [&](int buf, int kc) {
        int kmod = (kc < 3) ? kc : ((kc < 6) ? kc - 3 : kc - 6);
        int cA = ((kc < 6) ? 0 : 192) + kmod * 64;            // A': hi,hi,lo
        int cB = ((kc >= 3 && kc < 6) ? 192 : 0) + kmod * 64; // B': hi,lo,hi
        #pragma unroll
        for (int i = 0; i < 4; i++) {
            int u = i * 256 + ur;
            int r = u >> 3, c = u & 7;
            int cs = c ^ (r & 7);
            const ushort* ga = Wc + (size_t)(m0 + r) * 384 + cA + cs * 8;
            __builtin_amdgcn_global_load_lds(AS1(ga), AS3(&Asb[buf][(i * 4 + w) * 512]), 16, 0, 0);
            const ushort* gb = XT + ((size_t)(bg * HWP + n0 + r)) * 384 + cB + cs * 8;
            __builtin_amdgcn_global_load_lds(AS1(gb), AS3(&Bsb[buf][(i * 4 + w) * 512]), 16, 0, 0);
        }
    };

    STAGE(0, 0);
    __syncthreads();                 // drain -> tile 0 resident
    int cur = 0;
    for (int kc = 0; kc < 9; kc++) {
        if (kc < 8) STAGE(cur ^ 1, kc + 1);     // prefetch next tile under compute
        #pragma unroll
        for (int kq = 0; kq < 8; kq += 4) {
            bf16x8 af[4], bfr[4];
            #pragma unroll
            for (int m = 0; m < 4; m++) {
                int R = wm * 64 + m * 16 + fr;
                int unit = R * 8 + ((kq + kg) ^ (R & 7));
                af[m] = *(const bf16x8*)&Asb[cur][unit * 8];
            }
            #pragma unroll
            for (int n = 0; n < 4; n++) {
                int R = wn * 64 + n * 16 + fr;
                int unit = R * 8 + ((kq + kg) ^ (R & 7));
                bfr[n] = *(const bf16x8*)&Bsb[cur][unit * 8];
            }
            #pragma unroll
            for (int m = 0; m < 4; m++)
                #pragma unroll
                for (int n = 0; n < 4; n++)
                    acc[m][n] = __builtin_amdgcn_mfma_f32_16x16x32_bf16(af[m], bfr[n], acc[m][n], 0, 0, 0);
        }
        __syncthreads();             // vmcnt(0)+lgkmcnt(0)+barrier: prefetch done, WAR safe
        cur ^= 1;
    }

    unsigned* ob = op + (size_t)bl * QKV_B;
    #pragma unroll
    for (int m = 0; m < 4; m++) {
        int oc = m0 + wm * 64 + m * 16 + kg * 4;
        #pragma unroll
        for (int n = 0; n < 4; n++) {
            int col = n0 + wn * 64 + n * 16 + fr;
            #pragma unroll
            for (int r = 0; r < 4; r++) {
                if (oc + r < C3) {
                    float v = acc[m][n][r];
                    ushort hi = f2bf(v);
                    ushort lo = f2bf(v - bf2f(hi));
                    ob[(size_t)(oc + r) * HWP + col] = ((unsigned)lo << 16) | hi;
                }
            }
        }
    }
}

// ============================================================
// depthwise 3x3 reading packed-uint t1; fused q/k hi-lo emission + L2 norm;
// v emitted fp32
// ============================================================
__global__ __launch_bounds__(256) void dw3x3_kernel(const unsigned* __restrict__ inp,
    const float* __restrict__ wd,
    ushort* __restrict__ qh, ushort* __restrict__ ql,
    float* __restrict__ vv, float* __restrict__ inv, int b0)
{
    __shared__ float P[66][72];
    const int bc = blockIdx.x;          // bl*576 + ch
    const int bl = bc / C3, ch = bc % C3;
    const int b = b0 + bl;
    const int t = threadIdx.x;
    const unsigned* ip = inp + (size_t)bc * HWP;
    float wr[9];
    #pragma unroll
    for (int k = 0; k < 9; k++) wr[k] = wd[ch * 9 + k];
    for (int i = t; i < 66 * 72; i += 256) ((float*)P)[i] = 0.f;
    __syncthreads();
    #pragma unroll
    for (int i = 0; i < 4; i++) {
        int u = t + 256 * i;
        int y = u >> 4, cg = u & 15;
        uint4 p4 = *(const uint4*)&ip[u * 4];
        P[1 + y][4 + cg * 4 + 0] = bf2f((ushort)(p4.x & 0xFFFF)) + bf2f((ushort)(p4.x >> 16));
        P[1 + y][4 + cg * 4 + 1] = bf2f((ushort)(p4.y & 0xFFFF)) + bf2f((ushort)(p4.y >> 16));
        P[1 + y][4 + cg * 4 + 2] = bf2f((ushort)(p4.z & 0xFFFF)) + bf2f((ushort)(p4.z >> 16));
        P[1 + y][4 + cg * 4 + 3] = bf2f((ushort)(p4.w & 0xFFFF)) + bf2f((ushort)(p4.w >> 16));
    }
    __syncthreads();

    float ssum = 0.f;
    #pragma unroll
    for (int i = 0; i < 4; i++) {
        int u = t + 256 * i;
        int y0 = u >> 4;
        int x0 = (u & 15) * 4;
        float res[4] = {0.f, 0.f, 0.f, 0.f};
        #pragma unroll
        for (int dy = 0; dy < 3; dy++) {
            float4 A = *(float4*)&P[y0 + dy][x0];
            float4 Bv = *(float4*)&P[y0 + dy][x0 + 4];
            float4 Cv = *(float4*)&P[y0 + dy][x0 + 8];
            float c0 = A.w, c1 = Bv.x, c2 = Bv.y, c3 = Bv.z, c4 = Bv.w, c5 = Cv.x;
            float w0 = wr[dy*3], w1 = wr[dy*3+1], w2 = wr[dy*3+2];
            res[0] += w0*c0 + w1*c1 + w2*c2;
            res[1] += w0*c1 + w1*c2 + w2*c3;
            res[2] += w0*c2 + w1*c3 + w2*c4;
            res[3] += w0*c3 + w1*c4 + w2*c5;
        }
        #pragma unroll
        for (int k = 0; k < 4; k++) ssum += res[k] * res[k];
        if (ch < 384) {
            ushort hi[4], lo[4];
            #pragma unroll
            for (int k = 0; k < 4; k++) {
                hi[k] = f2bf(res[k]);
                lo[k] = f2bf(res[k] - bf2f(hi[k]));
            }
            size_t base = ((size_t)b * 384 + ch) * HWP + u * 4;
            *(ushort4*)&qh[base] = make_ushort4(hi[0], hi[1], hi[2], hi[3]);
            *(ushort4*)&ql[base] = make_ushort4(lo[0], lo[1], lo[2], lo[3]);
        } else {
            *(float4*)&vv[((size_t)b * CC + (ch - 384)) * HWP + u * 4] =
                make_float4(res[0], res[1], res[2], res[3]);
        }
    }
    if (ch < 384) {
        #pragma unroll
        for (int off = 32; off > 0; off >>= 1) ssum += __shfl_down(ssum, off);
        __shared__ float red[4];
        if ((t & 63) == 0) red[t >> 6] = ssum;
        __syncthreads();
        if (t == 0) {
            float tot = red[0] + red[1] + red[2] + red[3];
            inv[b * 384 + ch] = 1.f / fmaxf(sqrtf(tot), 1e-12f);
        }
    }
}

// ============================================================
// stacked Gram via MFMA (proven, unchanged)
// ============================================================
__global__ __launch_bounds__(256) void gram_mfma(const ushort* __restrict__ qhx,
    const ushort* __restrict__ qlx, const ushort* __restrict__ qhy,
    const ushort* __restrict__ qly, float* __restrict__ spart)
{
    __shared__ __align__(16) ushort As[96 * 64];
    __shared__ __align__(16) ushort Bs[96 * 64];
    const int chunk = blockIdx.x, bh = blockIdx.y;
    const int b = bh >> 2, h = bh & 3;
    const int t = threadIdx.x;
    const int lane = t & 63, w = t >> 6;
    const int wm = w >> 1, wn = w & 1;
    const int fr = lane & 15, kg = lane >> 4;

    const size_t qbase = ((size_t)b * 384 + h * DH) * HWP;
    const size_t kbase = ((size_t)b * 384 + 192 + h * DH) * HWP;

    f32x4 acc[3][3] = {};

    for (int term = 0; term < 3; term++) {
        const ushort* Aqx = (term == 2) ? qlx : qhx;
        const ushort* Aqy = (term == 2) ? qly : qhy;
        const ushort* Bkx = (term == 1) ? qlx : qhx;
        const ushort* Bky = (term == 1) ? qly : qhy;
        for (int ks = 0; ks < 8; ks++) {
            const int n0 = chunk * 512 + ks * 64;
            #pragma unroll
            for (int i = 0; i < 3; i++) {
                int u = i * 256 + w * 64 + lane;
                int r = u >> 3, c = u & 7;
                int cs = c ^ (r & 7);
                const ushort* ga = ((r < DH) ? (Aqx + qbase + (size_t)r * HWP)
                                             : (Aqy + qbase + (size_t)(r - DH) * HWP))
                                   + n0 + cs * 8;
                __builtin_amdgcn_global_load_lds(AS1(ga), AS3(&As[(size_t)(i * 4 + w) * 512]), 16, 0, 0);
                const ushort* gb = ((r < DH) ? (Bkx + kbase + (size_t)r * HWP)
                                             : (Bky + kbase + (size_t)(r - DH) * HWP))
                                   + n0 + cs * 8;
                __builtin_amdgcn_global_load_lds(AS1(gb), AS3(&Bs[(size_t)(i * 4 + w) * 512]), 16, 0, 0);
            }
            __syncthreads();
            #pragma unroll
            for (int kq = 0; kq < 8; kq += 4) {
                bf16x8 af[3], bfr[3];
                #pragma unroll
                for (int m = 0; m < 3; m++) {
                    int R = wm * DH + m * 16 + fr;
                    int unit = R * 8 + ((kq + kg) ^ (R & 7));
                    af[m] = *(const bf16x8*)&As[unit * 8];
                }
                #pragma unroll
                for (int n = 0; n < 3; n++) {
                    int R = wn * DH + n * 16 + fr;
                    int unit = R * 8 + ((kq + kg) ^ (R & 7));
                    bfr[n] = *(const bf16x8*)&Bs[unit * 8];
                }
                #pragma unroll
                for (int m = 0; m < 3; m++)
                    #pragma unroll
                    for (int n = 0; n < 3; n++)
                        acc[m][n] = __builtin_amdgcn_mfma_f32_16x16x32_bf16(af[m], bfr[n], acc[m][n], 0, 0, 0);
            }
            __syncthreads();
        }
    }

    float* sp = spart + ((size_t)chunk * 32 + bh) * 9216;
    #pragma unroll
    for (int m = 0; m < 3; m++) {
        int row = wm * DH + m * 16 + kg * 4;
        #pragma unroll
        for (int n = 0; n < 3; n++) {
            int col = wn * DH + n * 16 + fr;
            #pragma unroll
            for (int r = 0; r < 4; r++)
                sp[(row + r) * 96 + col] = acc[m][n][r];
        }
    }
}

// ============================================================
// combine split-K partials, scale, softmax; emit bf16 coefficient matrix
// M''(96 x 384): six BK=64 chunks [Mhx|Mhy|Mlx|Mly|Mhx|Mhy], pad cols zeroed
// ============================================================
__global__ __launch_bounds__(256) void softmax_kernel(const float* __restrict__ spart,
    const float* __restrict__ invx, const float* __restrict__ invy,
    const float* __restrict__ temp, ushort* __restrict__ mpp)
{
    __shared__ float G[96][97];
    const int bh = blockIdx.x, b = bh >> 2, h = bh & 3;
    const int t = threadIdx.x;
    const float ts = temp[h];
    for (int i = 0; i < 36; i++) {
        int f = t + 256 * i;
        float s = 0.f;
        #pragma unroll
        for (int cch = 0; cch < 8; cch++)
            s += spart[((size_t)cch * 32 + bh) * 9216 + f];
        int r = f / 96, c = f % 96;
        float iq = (r < DH) ? invx[b*384 + h*DH + r] : invy[b*384 + h*DH + (r-DH)];
        float ik = (c < DH) ? invx[b*384 + CC + h*DH + c] : invy[b*384 + CC + h*DH + (c-DH)];
        G[r][c] = s * iq * ik * ts;
    }
    __syncthreads();
    if (t < 192) {
        int r = t >> 1, hf = t & 1;
        float* rowp = &G[r][hf * DH];
        float m = rowp[0];
        for (int i = 1; i < DH; i++) m = fmaxf(m, rowp[i]);
        float s = 0.f;
        for (int i = 0; i < DH; i++) { float e = __expf(rowp[i] - m); rowp[i] = e; s += e; }
        float inv = 1.f / s;
        for (int i = 0; i < DH; i++) rowp[i] *= inv;
    }
    __syncthreads();
    ushort* mo = mpp + (size_t)bh * 96 * 384;
    for (int i = 0; i < 36; i++) {
        int f = t + 256 * i;                 // 96 rows x 96 pad cols
        int r = f / 96, p = f % 96;
        int ch = p >> 4, j = p & 15;
        mo[(size_t)r * 384 + ch * 64 + 48 + j] = 0;
    }
    for (int i = 0; i < 36; i++) {
        int f = t + 256 * i;
        int r = f / 96, c = f % 96;
        float v;
        if (c < DH) v = (r < DH) ? G[DH + r][c] : G[r - DH][c];
        else        v = G[r][c];
        ushort hi = f2bf(v);
        ushort lo = f2bf(v - bf2f(hi));
        size_t rb = (size_t)r * 384;
        if (c < DH) {
            mo[rb + c] = hi;
            mo[rb + 128 + c] = lo;
            mo[rb + 256 + c] = hi;
        } else {
            int cp = c - DH;
            mo[rb + 64 + cp] = hi;
            mo[rb + 192 + cp] = lo;
            mo[rb + 320 + cp] = hi;
        }
    }
}

// ============================================================
// output GEMM via MFMA (proven, unchanged)
// ============================================================
__global__ __launch_bounds__(256) void outmm_mfma(const ushort* __restrict__ VTx,
    const ushort* __restrict__ VTy, const ushort* __restrict__ mpp,
    float* __restrict__ out)
{
    __shared__ __align__(16) ushort As[96 * 64];
    __shared__ __align__(16) ushort Bs[128 * 64];
    const int t = threadIdx.x;
    const int lane = t & 63, w = t >> 6;
    const int wm = w >> 1, wn = w & 1;
    const int fr = lane & 15, kg = lane >> 4;
    const int nc = blockIdx.x, bh = blockIdx.y;
    const int b = bh >> 2, h = bh & 3;
    const int n0 = nc * 128;
    const ushort* mp = mpp + (size_t)bh * 96 * 384;

    f32x4 acc[3][4] = {};

    for (int kc = 0; kc < 6; kc++) {
        const ushort* Vsrc = (kc & 1) ? VTy : VTx;
        const int coff = ((kc < 4) ? 0 : 192) + h * DH;
        #pragma unroll
        for (int i = 0; i < 3; i++) {
            int u = i * 256 + w * 64 + lane;
            int r = u >> 3, c = u & 7;
            int cs = c ^ (r & 7);
            const ushort* ga = mp + (size_t)r * 384 + kc * 64 + cs * 8;
            __builtin_amdgcn_global_load_lds(AS1(ga), AS3(&As[(size_t)(i * 4 + w) * 512]), 16, 0, 0);
        }
        #pragma unroll
        for (int i = 0; i < 4; i++) {
            int u = i * 256 + w * 64 + lane;
            int r = u >> 3, c = u & 7;
            int cs = c ^ (r & 7);
            const ushort* gb = Vsrc + ((size_t)(b * HWP + n0 + r)) * 384 + coff + cs * 8;
            __builtin_amdgcn_global_load_lds(AS1(gb), AS3(&Bs[(size_t)(i * 4 + w) * 512]), 16, 0, 0);
        }
        __syncthreads();
        #pragma unroll
        for (int kq = 0; kq < 8; kq += 4) {
            bf16x8 af[3], bfr[4];
            #pragma unroll
            for (int m = 0; m < 3; m++) {
                int R = wm * DH + m * 16 + fr;
                int unit = R * 8 + ((kq + kg) ^ (R & 7));
                af[m] = *(const bf16x8*)&As[unit * 8];
            }
            #pragma unroll
            for (int n = 0; n < 4; n++) {
                int R = wn * 64 + n * 16 + fr;
                int unit = R * 8 + ((kq + kg) ^ (R & 7));
                bfr[n] = *(const bf16x8*)&Bs[unit * 8];
            }
            #pragma unroll
            for (int m = 0; m < 3; m++)
                #pragma unroll
                for (int n = 0; n < 4; n++)
                    acc[m][n] = __builtin_amdgcn_mfma_f32_16x16x32_bf16(af[m], bfr[n], acc[m][n], 0, 0, 0);
        }
        __syncthreads();
    }

    #pragma unroll
    for (int m = 0; m < 3; m++) {
        int row = wm * DH + m * 16 + kg * 4;
        #pragma unroll
        for (int n = 0; n < 4; n++) {
            int col = n0 + wn * 64 + n * 16 + fr;
            #pragma unroll
            for (int r = 0; r < 4; r++) {
                int rr = row + r;
                float* dst = (rr < DH)
                    ? (out + (size_t)b * X_B + (h * DH + rr) * HWP + col)
                    : (out + OUT_HALF + (size_t)b * X_B + (h * DH + rr - DH) * HWP + col);
                *dst = acc[m][n][r];
            }
        }
    }
}

// ============================================================
extern "C" void kernel_launch(void* const* d_in, const int* in_sizes, int n_in,
                              void* d_out, int out_size, void* d_ws, size_t ws_size,
                              hipStream_t stream)
{
    const float* x  = (const float*)d_in[0];
    const float* y  = (const float*)d_in[1];
    const float* wq = (const float*)d_in[2];
    const float* wd = (const float*)d_in[3];
    const float* tp = (const float*)d_in[4];
    float* out = (float*)d_out;
    float* ws = (float*)d_ws;

    // ---- workspace layout (float units), identical to the round-4 PASSING build
    const size_t QKF = 6291456;   // floats per q/k hi-or-lo ushort array (25.2 MB)
    const size_t VF  = 6291456;   // floats per v fp32 array
    const size_t T1F = 9437184;   // t1 region floats (37.7 MB, 4 batches packed)
    const size_t XTF = 6291456;   // XT ushort array in floats
    const size_t WCF = 122880;

    ushort* qhx = (ushort*)ws;
    ushort* qlx = (ushort*)(ws + QKF);
    ushort* qhy = (ushort*)(ws + 2 * QKF);
    ushort* qly = (ushort*)(ws + 3 * QKF);
    float*  vx  = ws + 4 * QKF;
    float*  vy  = vx + VF;
    float*  t1r = vy + VF;                        // 9.44M floats
    unsigned* t1p = (unsigned*)t1r;               // [4]*576*4096 packed uints
    ushort* XT  = (ushort*)(t1r + T1F);
    ushort* Wc  = (ushort*)(t1r + T1F + XTF);
    float*  invx = t1r + T1F + XTF + WCF;
    float*  invy = invx + 3072;
    // aliases into t1 region (dead after last dw):
    ushort* VTy  = (ushort*)t1r;                                  // 6.29M floats
    float*  spart = t1r + 6291456;                                // 2.36M floats
    ushort* Mpp  = (ushort*)(t1r + 6291456 + 2359296);            // 0.59M floats
    // alias over dead XT:
    ushort* VTx  = XT;

    wconvert_kernel<<<240, 256, 0, stream>>>(wq, Wc);

    // tensor x
    convert_kernel<<<dim3(64, 3, BB), 256, 0, stream>>>(x, XT);
    conv1x1_mfma<<<dim3(128, 5), 256, 0, stream>>>(XT, Wc, t1p, 0);
    dw3x3_kernel<<<4 * C3, 256, 0, stream>>>(t1p, wd, qhx, qlx, vx, invx, 0);
    conv1x1_mfma<<<dim3(128, 5), 256, 0, stream>>>(XT, Wc, t1p, 4);
    dw3x3_kernel<<<4 * C3, 256, 0, stream>>>(t1p, wd, qhx, qlx, vx, invx, 4);

    // tensor y
    convert_kernel<<<dim3(64, 3, BB), 256, 0, stream>>>(y, XT);
    conv1x1_mfma<<<dim3(128, 5), 256, 0, stream>>>(XT, Wc, t1p, 0);
    dw3x3_kernel<<<4 * C3, 256, 0, stream>>>(t1p, wd, qhy, qly, vy, invy, 0);
    conv1x1_mfma<<<dim3(128, 5), 256, 0, stream>>>(XT, Wc, t1p, 4);
    dw3x3_kernel<<<4 * C3, 256, 0, stream>>>(t1p, wd, qhy, qly, vy, invy, 4);

    // transpose v to XT-format; VTx over dead XT, VTy over dead t1
    convert_kernel<<<dim3(64, 3, BB), 256, 0, stream>>>(vx, VTx);
    convert_kernel<<<dim3(64, 3, BB), 256, 0, stream>>>(vy, VTy);

    gram_mfma<<<dim3(8, 32), 256, 0, stream>>>(qhx, qlx, qhy, qly, spart);
    softmax_kernel<<<32, 256, 0, stream>>>(spart, invx, invy, tp, Mpp);
    outmm_mfma<<<dim3(HWP / 128, 32), 256, 0, stream>>>(VTx, VTy, Mpp, out);
}

// Round 8
// 287.008 us; speedup vs baseline: 1.0991x; 1.0471x over previous
//
#include <hip/hip_runtime.h>

// ---- problem constants ----
#define CC   192                 // C
#define C3   576                 // 3C
#define HH   64
#define WW   64
#define HWP  4096                // H*W
#define BB   8
#define DH   48                  // C/HEADS
#define QKV_B (C3*HWP)           // elements per batch of conv-out tensor
#define X_B   (CC*HWP)
#define OUT_HALF ((size_t)BB*X_B)

typedef short bf16x8 __attribute__((ext_vector_type(8)));
typedef float f32x4  __attribute__((ext_vector_type(4)));

#define AS1(p) ((__attribute__((address_space(1))) void*)(p))
#define AS3(p) ((__attribute__((address_space(3))) void*)(p))

__device__ __forceinline__ ushort f2bf(float v) {
    union { float f; unsigned u; } a; a.f = v;
    unsigned r = a.u + 0x7FFF + ((a.u >> 16) & 1);   // RNE
    return (ushort)(r >> 16);
}
__device__ __forceinline__ float bf2f(ushort h) {
    union { float f; unsigned u; } a; a.u = ((unsigned)h) << 16; return a.f;
}

// ============================================================
// in (b,192,4096) fp32 -> out (b,4096,384) bf16: cols 0..191 hi, 192..383 lo
// (used for x, y, and for transposing vx, vy)
// ============================================================
__global__ __launch_bounds__(256) void convert_kernel(const float* __restrict__ in,
    ushort* __restrict__ xt)
{
    __shared__ float L[64][65];
    const int n0 = blockIdx.x * 64, c0 = blockIdx.y * 64, b = blockIdx.z;
    const int t = threadIdx.x;
    const float* ip = in + (size_t)b * X_B;
    #pragma unroll
    for (int i = 0; i < 16; i++) {
        int e = t + 256 * i;
        int r = e >> 6, col = e & 63;
        L[r][col] = ip[(size_t)(c0 + r) * HWP + n0 + col];
    }
    __syncthreads();
    #pragma unroll
    for (int i = 0; i < 4; i++) {
        int e = t + 256 * i;
        int n = e >> 4, c4 = e & 15;
        ushort hi[4], lo[4];
        #pragma unroll
        for (int j = 0; j < 4; j++) {
            float v = L[c4 * 4 + j][n];
            hi[j] = f2bf(v);
            lo[j] = f2bf(v - bf2f(hi[j]));
        }
        size_t base = ((size_t)(b * HWP + n0 + n)) * 384 + c0 + c4 * 4;
        *(ushort4*)&xt[base]       = make_ushort4(hi[0], hi[1], hi[2], hi[3]);
        *(ushort4*)&xt[base + 192] = make_ushort4(lo[0], lo[1], lo[2], lo[3]);
    }
}

// ============================================================
// w_qkv -> Wc(640,384) bf16 hi|lo, zero-padded rows
// ============================================================
__global__ __launch_bounds__(256) void wconvert_kernel(const float* __restrict__ wq,
    ushort* __restrict__ wc)
{
    int e = (blockIdx.x * 256 + threadIdx.x) * 4;
    int oc = e / 384, k = e % 384;
    ushort o[4] = {0, 0, 0, 0};
    if (oc < C3) {
        int kk = (k < 192) ? k : (k - 192);
        #pragma unroll
        for (int j = 0; j < 4; j++) {
            float v = wq[oc * CC + kk + j];
            ushort h = f2bf(v);
            o[j] = (k < 192) ? h : f2bf(v - bf2f(h));
        }
    }
    *(ushort4*)&wc[e] = make_ushort4(o[0], o[1], o[2], o[3]);
}

// ============================================================
// conv1x1 via MFMA, BK=32 double-buffered: LDS 32KB -> 5 blocks/CU, so all
// 640 blocks of a dispatch are co-resident (no tail round). 18 K-chunks
// (3 hi/lo terms x 6). XCD-aware 1D grid: 5 blocks sharing one B-slice run
// consecutively on one XCD (L2 reuse). Packed (lo<<16|hi) epilogue.
// ============================================================
__global__ __launch_bounds__(256) void conv1x1_mfma(const ushort* __restrict__ XT,
    const ushort* __restrict__ Wc, unsigned* __restrict__ op, int b0)
{
    __shared__ __align__(16) ushort Asb[2][128 * 32];   // 2 x 8 KB
    __shared__ __align__(16) ushort Bsb[2][128 * 32];   // 2 x 8 KB
    const int t = threadIdx.x;
    const int lane = t & 63, w = t >> 6;
    const int wm = w >> 1, wn = w & 1;
    const int fr = lane & 15, kg = lane >> 4;
    // XCD-aware decode: 640 = 8 xcd x 16 nt x 5 mi; same-nt blocks adjacent per XCD
    const int g = blockIdx.x;
    const int xcd = g & 7, s = g >> 3;          // s in [0,80)
    const int nt = xcd * 16 + s / 5;            // [0,128): 4 batches x 32 n-tiles
    const int mi = s % 5;
    const int bl = nt >> 5;                     // local batch 0..3
    const int n0 = (nt & 31) * 128;
    const int m0 = mi * 128;
    const int bg = b0 + bl;

    f32x4 acc[4][4] = {};

    auto STAGE = [&](int buf, int kc) {
        // term 0: Whi*Xhi (kc 0-5), term 1: Whi*Xlo (6-11), term 2: Wlo*Xhi (12-17)
        int km = (kc < 6) ? kc : ((kc < 12) ? kc - 6 : kc - 12);
        int cA = ((kc < 12) ? 0 : 192) + km * 32;
        int cB = ((kc >= 6 && kc < 12) ? 192 : 0) + km * 32;
        #pragma unroll
        for (int i = 0; i < 2; i++) {
            int u = i * 256 + w * 64 + lane;    // unit id 0..511 (16B units)
            int r = u >> 2, c = u & 3;
            int cs = c ^ (r & 3);               // pre-swizzled source column
            const ushort* ga = Wc + (size_t)(m0 + r) * 384 + cA + cs * 8;
            __builtin_amdgcn_global_load_lds(AS1(ga), AS3(&Asb[buf][(i * 256 + w * 64) * 8]), 16, 0, 0);
            const ushort* gb = XT + ((size_t)(bg * HWP + n0 + r)) * 384 + cB + cs * 8;
            __builtin_amdgcn_global_load_lds(AS1(gb), AS3(&Bsb[buf][(i * 256 + w * 64) * 8]), 16, 0, 0);
        }
    };

    STAGE(0, 0);
    __syncthreads();                 // tile 0 resident
    int cur = 0;
    for (int kc = 0; kc < 18; kc++) {
        if (kc < 17) STAGE(cur ^ 1, kc + 1);    // prefetch next tile under compute
        bf16x8 af[4], bfr[4];
        #pragma unroll
        for (int m = 0; m < 4; m++) {
            int R = wm * 64 + m * 16 + fr;
            int unit = R * 4 + (kg ^ (R & 3));
            af[m] = *(const bf16x8*)&Asb[cur][unit * 8];
        }
        #pragma unroll
        for (int n = 0; n < 4; n++) {
            int R = wn * 64 + n * 16 + fr;
            int unit = R * 4 + (kg ^ (R & 3));
            bfr[n] = *(const bf16x8*)&Bsb[cur][unit * 8];
        }
        #pragma unroll
        for (int m = 0; m < 4; m++)
            #pragma unroll
            for (int n = 0; n < 4; n++)
                acc[m][n] = __builtin_amdgcn_mfma_f32_16x16x32_bf16(af[m], bfr[n], acc[m][n], 0, 0, 0);
        __syncthreads();             // prefetch done + WAR safe
        cur ^= 1;
    }

    unsigned* ob = op + (size_t)bl * QKV_B;
    #pragma unroll
    for (int m = 0; m < 4; m++) {
        int oc = m0 + wm * 64 + m * 16 + kg * 4;
        #pragma unroll
        for (int n = 0; n < 4; n++) {
            int col = n0 + wn * 64 + n * 16 + fr;
            #pragma unroll
            for (int r = 0; r < 4; r++) {
                if (oc + r < C3) {
                    float v = acc[m][n][r];
                    ushort hi = f2bf(v);
                    ushort lo = f2bf(v - bf2f(hi));
                    ob[(size_t)(oc + r) * HWP + col] = ((unsigned)lo << 16) | hi;
                }
            }
        }
    }
}

// ============================================================
// depthwise 3x3 reading packed-uint t1; fused q/k hi-lo emission + L2 norm;
// v emitted fp32
// ============================================================
__global__ __launch_bounds__(256) void dw3x3_kernel(const unsigned* __restrict__ inp,
    const float* __restrict__ wd,
    ushort* __restrict__ qh, ushort* __restrict__ ql,
    float* __restrict__ vv, float* __restrict__ inv, int b0)
{
    __shared__ float P[66][72];
    const int bc = blockIdx.x;          // bl*576 + ch
    const int bl = bc / C3, ch = bc % C3;
    const int b = b0 + bl;
    const int t = threadIdx.x;
    const unsigned* ip = inp + (size_t)bc * HWP;
    float wr[9];
    #pragma unroll
    for (int k = 0; k < 9; k++) wr[k] = wd[ch * 9 + k];
    for (int i = t; i < 66 * 72; i += 256) ((float*)P)[i] = 0.f;
    __syncthreads();
    #pragma unroll
    for (int i = 0; i < 4; i++) {
        int u = t + 256 * i;
        int y = u >> 4, cg = u & 15;
        uint4 p4 = *(const uint4*)&ip[u * 4];
        P[1 + y][4 + cg * 4 + 0] = bf2f((ushort)(p4.x & 0xFFFF)) + bf2f((ushort)(p4.x >> 16));
        P[1 + y][4 + cg * 4 + 1] = bf2f((ushort)(p4.y & 0xFFFF)) + bf2f((ushort)(p4.y >> 16));
        P[1 + y][4 + cg * 4 + 2] = bf2f((ushort)(p4.z & 0xFFFF)) + bf2f((ushort)(p4.z >> 16));
        P[1 + y][4 + cg * 4 + 3] = bf2f((ushort)(p4.w & 0xFFFF)) + bf2f((ushort)(p4.w >> 16));
    }
    __syncthreads();

    float ssum = 0.f;
    #pragma unroll
    for (int i = 0; i < 4; i++) {
        int u = t + 256 * i;
        int y0 = u >> 4;
        int x0 = (u & 15) * 4;
        float res[4] = {0.f, 0.f, 0.f, 0.f};
        #pragma unroll
        for (int dy = 0; dy < 3; dy++) {
            float4 A = *(float4*)&P[y0 + dy][x0];
            float4 Bv = *(float4*)&P[y0 + dy][x0 + 4];
            float4 Cv = *(float4*)&P[y0 + dy][x0 + 8];
            float c0 = A.w, c1 = Bv.x, c2 = Bv.y, c3 = Bv.z, c4 = Bv.w, c5 = Cv.x;
            float w0 = wr[dy*3], w1 = wr[dy*3+1], w2 = wr[dy*3+2];
            res[0] += w0*c0 + w1*c1 + w2*c2;
            res[1] += w0*c1 + w1*c2 + w2*c3;
            res[2] += w0*c2 + w1*c3 + w2*c4;
            res[3] += w0*c3 + w1*c4 + w2*c5;
        }
        #pragma unroll
        for (int k = 0; k < 4; k++) ssum += res[k] * res[k];
        if (ch < 384) {
            ushort hi[4], lo[4];
            #pragma unroll
            for (int k = 0; k < 4; k++) {
                hi[k] = f2bf(res[k]);
                lo[k] = f2bf(res[k] - bf2f(hi[k]));
            }
            size_t base = ((size_t)b * 384 + ch) * HWP + u * 4;
            *(ushort4*)&qh[base] = make_ushort4(hi[0], hi[1], hi[2], hi[3]);
            *(ushort4*)&ql[base] = make_ushort4(lo[0], lo[1], lo[2], lo[3]);
        } else {
            *(float4*)&vv[((size_t)b * CC + (ch - 384)) * HWP + u * 4] =
                make_float4(res[0], res[1], res[2], res[3]);
        }
    }
    if (ch < 384) {
        #pragma unroll
        for (int off = 32; off > 0; off >>= 1) ssum += __shfl_down(ssum, off);
        __shared__ float red[4];
        if ((t & 63) == 0) red[t >> 6] = ssum;
        __syncthreads();
        if (t == 0) {
            float tot = red[0] + red[1] + red[2] + red[3];
            inv[b * 384 + ch] = 1.f / fmaxf(sqrtf(tot), 1e-12f);
        }
    }
}

// ============================================================
// stacked Gram via MFMA (proven, unchanged)
// ============================================================
__global__ __launch_bounds__(256) void gram_mfma(const ushort* __restrict__ qhx,
    const ushort* __restrict__ qlx, const ushort* __restrict__ qhy,
    const ushort* __restrict__ qly, float* __restrict__ spart)
{
    __shared__ __align__(16) ushort As[96 * 64];
    __shared__ __align__(16) ushort Bs[96 * 64];
    const int chunk = blockIdx.x, bh = blockIdx.y;
    const int b = bh >> 2, h = bh & 3;
    const int t = threadIdx.x;
    const int lane = t & 63, w = t >> 6;
    const int wm = w >> 1, wn = w & 1;
    const int fr = lane & 15, kg = lane >> 4;

    const size_t qbase = ((size_t)b * 384 + h * DH) * HWP;
    const size_t kbase = ((size_t)b * 384 + 192 + h * DH) * HWP;

    f32x4 acc[3][3] = {};

    for (int term = 0; term < 3; term++) {
        const ushort* Aqx = (term == 2) ? qlx : qhx;
        const ushort* Aqy = (term == 2) ? qly : qhy;
        const ushort* Bkx = (term == 1) ? qlx : qhx;
        const ushort* Bky = (term == 1) ? qly : qhy;
        for (int ks = 0; ks < 8; ks++) {
            const int n0 = chunk * 512 + ks * 64;
            #pragma unroll
            for (int i = 0; i < 3; i++) {
                int u = i * 256 + w * 64 + lane;
                int r = u >> 3, c = u & 7;
                int cs = c ^ (r & 7);
                const ushort* ga = ((r < DH) ? (Aqx + qbase + (size_t)r * HWP)
                                             : (Aqy + qbase + (size_t)(r - DH) * HWP))
                                   + n0 + cs * 8;
                __builtin_amdgcn_global_load_lds(AS1(ga), AS3(&As[(size_t)(i * 4 + w) * 512]), 16, 0, 0);
                const ushort* gb = ((r < DH) ? (Bkx + kbase + (size_t)r * HWP)
                                             : (Bky + kbase + (size_t)(r - DH) * HWP))
                                   + n0 + cs * 8;
                __builtin_amdgcn_global_load_lds(AS1(gb), AS3(&Bs[(size_t)(i * 4 + w) * 512]), 16, 0, 0);
            }
            __syncthreads();
            #pragma unroll
            for (int kq = 0; kq < 8; kq += 4) {
                bf16x8 af[3], bfr[3];
                #pragma unroll
                for (int m = 0; m < 3; m++) {
                    int R = wm * DH + m * 16 + fr;
                    int unit = R * 8 + ((kq + kg) ^ (R & 7));
                    af[m] = *(const bf16x8*)&As[unit * 8];
                }
                #pragma unroll
                for (int n = 0; n < 3; n++) {
                    int R = wn * DH + n * 16 + fr;
                    int unit = R * 8 + ((kq + kg) ^ (R & 7));
                    bfr[n] = *(const bf16x8*)&Bs[unit * 8];
                }
                #pragma unroll
                for (int m = 0; m < 3; m++)
                    #pragma unroll
                    for (int n = 0; n < 3; n++)
                        acc[m][n] = __builtin_amdgcn_mfma_f32_16x16x32_bf16(af[m], bfr[n], acc[m][n], 0, 0, 0);
            }
            __syncthreads();
        }
    }

    float* sp = spart + ((size_t)chunk * 32 + bh) * 9216;
    #pragma unroll
    for (int m = 0; m < 3; m++) {
        int row = wm * DH + m * 16 + kg * 4;
        #pragma unroll
        for (int n = 0; n < 3; n++) {
            int col = wn * DH + n * 16 + fr;
            #pragma unroll
            for (int r = 0; r < 4; r++)
                sp[(row + r) * 96 + col] = acc[m][n][r];
        }
    }
}

// ============================================================
// combine split-K partials, scale, softmax; emit bf16 coefficient matrix
// M''(96 x 384): six BK=64 chunks [Mhx|Mhy|Mlx|Mly|Mhx|Mhy], pad cols zeroed
// ============================================================
__global__ __launch_bounds__(256) void softmax_kernel(const float* __restrict__ spart,
    const float* __restrict__ invx, const float* __restrict__ invy,
    const float* __restrict__ temp, ushort* __restrict__ mpp)
{
    __shared__ float G[96][97];
    const int bh = blockIdx.x, b = bh >> 2, h = bh & 3;
    const int t = threadIdx.x;
    const float ts = temp[h];
    for (int i = 0; i < 36; i++) {
        int f = t + 256 * i;
        float s = 0.f;
        #pragma unroll
        for (int cch = 0; cch < 8; cch++)
            s += spart[((size_t)cch * 32 + bh) * 9216 + f];
        int r = f / 96, c = f % 96;
        float iq = (r < DH) ? invx[b*384 + h*DH + r] : invy[b*384 + h*DH + (r-DH)];
        float ik = (c < DH) ? invx[b*384 + CC + h*DH + c] : invy[b*384 + CC + h*DH + (c-DH)];
        G[r][c] = s * iq * ik * ts;
    }
    __syncthreads();
    if (t < 192) {
        int r = t >> 1, hf = t & 1;
        float* rowp = &G[r][hf * DH];
        float m = rowp[0];
        for (int i = 1; i < DH; i++) m = fmaxf(m, rowp[i]);
        float s = 0.f;
        for (int i = 0; i < DH; i++) { float e = __expf(rowp[i] - m); rowp[i] = e; s += e; }
        float inv = 1.f / s;
        for (int i = 0; i < DH; i++) rowp[i] *= inv;
    }
    __syncthreads();
    ushort* mo = mpp + (size_t)bh * 96 * 384;
    for (int i = 0; i < 36; i++) {
        int f = t + 256 * i;                 // 96 rows x 96 pad cols
        int r = f / 96, p = f % 96;
        int ch = p >> 4, j = p & 15;
        mo[(size_t)r * 384 + ch * 64 + 48 + j] = 0;
    }
    for (int i = 0; i < 36; i++) {
        int f = t + 256 * i;
        int r = f / 96, c = f % 96;
        float v;
        if (c < DH) v = (r < DH) ? G[DH + r][c] : G[r - DH][c];
        else        v = G[r][c];
        ushort hi = f2bf(v);
        ushort lo = f2bf(v - bf2f(hi));
        size_t rb = (size_t)r * 384;
        if (c < DH) {
            mo[rb + c] = hi;
            mo[rb + 128 + c] = lo;
            mo[rb + 256 + c] = hi;
        } else {
            int cp = c - DH;
            mo[rb + 64 + cp] = hi;
            mo[rb + 192 + cp] = lo;
            mo[rb + 320 + cp] = hi;
        }
    }
}

// ============================================================
// output GEMM via MFMA (proven, unchanged)
// ============================================================
__global__ __launch_bounds__(256) void outmm_mfma(const ushort* __restrict__ VTx,
    const ushort* __restrict__ VTy, const ushort* __restrict__ mpp,
    float* __restrict__ out)
{
    __shared__ __align__(16) ushort As[96 * 64];
    __shared__ __align__(16) ushort Bs[128 * 64];
    const int t = threadIdx.x;
    const int lane = t & 63, w = t >> 6;
    const int wm = w >> 1, wn = w & 1;
    const int fr = lane & 15, kg = lane >> 4;
    const int nc = blockIdx.x, bh = blockIdx.y;
    const int b = bh >> 2, h = bh & 3;
    const int n0 = nc * 128;
    const ushort* mp = mpp + (size_t)bh * 96 * 384;

    f32x4 acc[3][4] = {};

    for (int kc = 0; kc < 6; kc++) {
        const ushort* Vsrc = (kc & 1) ? VTy : VTx;
        const int coff = ((kc < 4) ? 0 : 192) + h * DH;
        #pragma unroll
        for (int i = 0; i < 3; i++) {
            int u = i * 256 + w * 64 + lane;
            int r = u >> 3, c = u & 7;
            int cs = c ^ (r & 7);
            const ushort* ga = mp + (size_t)r * 384 + kc * 64 + cs * 8;
            __builtin_amdgcn_global_load_lds(AS1(ga), AS3(&As[(size_t)(i * 4 + w) * 512]), 16, 0, 0);
        }
        #pragma unroll
        for (int i = 0; i < 4; i++) {
            int u = i * 256 + w * 64 + lane;
            int r = u >> 3, c = u & 7;
            int cs = c ^ (r & 7);
            const ushort* gb = Vsrc + ((size_t)(b * HWP + n0 + r)) * 384 + coff + cs * 8;
            __builtin_amdgcn_global_load_lds(AS1(gb), AS3(&Bs[(size_t)(i * 4 + w) * 512]), 16, 0, 0);
        }
        __syncthreads();
        #pragma unroll
        for (int kq = 0; kq < 8; kq += 4) {
            bf16x8 af[3], bfr[4];
            #pragma unroll
            for (int m = 0; m < 3; m++) {
                int R = wm * DH + m * 16 + fr;
                int unit = R * 8 + ((kq + kg) ^ (R & 7));
                af[m] = *(const bf16x8*)&As[unit * 8];
            }
            #pragma unroll
            for (int n = 0; n < 4; n++) {
                int R = wn * 64 + n * 16 + fr;
                int unit = R * 8 + ((kq + kg) ^ (R & 7));
                bfr[n] = *(const bf16x8*)&Bs[unit * 8];
            }
            #pragma unroll
            for (int m = 0; m < 3; m++)
                #pragma unroll
                for (int n = 0; n < 4; n++)
                    acc[m][n] = __builtin_amdgcn_mfma_f32_16x16x32_bf16(af[m], bfr[n], acc[m][n], 0, 0, 0);
        }
        __syncthreads();
    }

    #pragma unroll
    for (int m = 0; m < 3; m++) {
        int row = wm * DH + m * 16 + kg * 4;
        #pragma unroll
        for (int n = 0; n < 4; n++) {
            int col = n0 + wn * 64 + n * 16 + fr;
            #pragma unroll
            for (int r = 0; r < 4; r++) {
                int rr = row + r;
                float* dst = (rr < DH)
                    ? (out + (size_t)b * X_B + (h * DH + rr) * HWP + col)
                    : (out + OUT_HALF + (size_t)b * X_B + (h * DH + rr - DH) * HWP + col);
                *dst = acc[m][n][r];
            }
        }
    }
}

// ============================================================
extern "C" void kernel_launch(void* const* d_in, const int* in_sizes, int n_in,
                              void* d_out, int out_size, void* d_ws, size_t ws_size,
                              hipStream_t stream)
{
    const float* x  = (const float*)d_in[0];
    const float* y  = (const float*)d_in[1];
    const float* wq = (const float*)d_in[2];
    const float* wd = (const float*)d_in[3];
    const float* tp = (const float*)d_in[4];
    float* out = (float*)d_out;
    float* ws = (float*)d_ws;

    // ---- workspace layout (float units), identical to the round-7 PASSING build
    const size_t QKF = 6291456;   // floats per q/k hi-or-lo ushort array (25.2 MB)
    const size_t VF  = 6291456;   // floats per v fp32 array
    const size_t T1F = 9437184;   // t1 region floats (37.7 MB, 4 batches packed)
    const size_t XTF = 6291456;   // XT ushort array in floats
    const size_t WCF = 122880;

    ushort* qhx = (ushort*)ws;
    ushort* qlx = (ushort*)(ws + QKF);
    ushort* qhy = (ushort*)(ws + 2 * QKF);
    ushort* qly = (ushort*)(ws + 3 * QKF);
    float*  vx  = ws + 4 * QKF;
    float*  vy  = vx + VF;
    float*  t1r = vy + VF;                        // 9.44M floats
    unsigned* t1p = (unsigned*)t1r;               // [4]*576*4096 packed uints
    ushort* XT  = (ushort*)(t1r + T1F);
    ushort* Wc  = (ushort*)(t1r + T1F + XTF);
    float*  invx = t1r + T1F + XTF + WCF;
    float*  invy = invx + 3072;
    // aliases into t1 region (dead after last dw):
    ushort* VTy  = (ushort*)t1r;                                  // 6.29M floats
    float*  spart = t1r + 6291456;                                // 2.36M floats
    ushort* Mpp  = (ushort*)(t1r + 6291456 + 2359296);            // 0.59M floats
    // alias over dead XT:
    ushort* VTx  = XT;

    wconvert_kernel<<<240, 256, 0, stream>>>(wq, Wc);

    // tensor x
    convert_kernel<<<dim3(64, 3, BB), 256, 0, stream>>>(x, XT);
    conv1x1_mfma<<<640, 256, 0, stream>>>(XT, Wc, t1p, 0);
    dw3x3_kernel<<<4 * C3, 256, 0, stream>>>(t1p, wd, qhx, qlx, vx, invx, 0);
    conv1x1_mfma<<<640, 256, 0, stream>>>(XT, Wc, t1p, 4);
    dw3x3_kernel<<<4 * C3, 256, 0, stream>>>(t1p, wd, qhx, qlx, vx, invx, 4);

    // tensor y
    convert_kernel<<<dim3(64, 3, BB), 256, 0, stream>>>(y, XT);
    conv1x1_mfma<<<640, 256, 0, stream>>>(XT, Wc, t1p, 0);
    dw3x3_kernel<<<4 * C3, 256, 0, stream>>>(t1p, wd, qhy, qly, vy, invy, 0);
    conv1x1_mfma<<<640, 256, 0, stream>>>(XT, Wc, t1p, 4);
    dw3x3_kernel<<<4 * C3, 256, 0, stream>>>(t1p, wd, qhy, qly, vy, invy, 4);

    // transpose v to XT-format; VTx over dead XT, VTy over dead t1
    convert_kernel<<<dim3(64, 3, BB), 256, 0, stream>>>(vx, VTx);
    convert_kernel<<<dim3(64, 3, BB), 256, 0, stream>>>(vy, VTy);

    gram_mfma<<<dim3(8, 32), 256, 0, stream>>>(qhx, qlx, qhy, qly, spart);
    softmax_kernel<<<32, 256, 0, stream>>>(spart, invx, invy, tp, Mpp);
    outmm_mfma<<<dim3(HWP / 128, 32), 256, 0, stream>>>(VTx, VTy, Mpp, out);
}

// Round 9
// 267.232 us; speedup vs baseline: 1.1804x; 1.0740x over previous
//
#include <hip/hip_runtime.h>

// ---- problem constants ----
#define CC   192                 // C
#define C3   576                 // 3C
#define HH   64
#define WW   64
#define HWP  4096                // H*W
#define BB   8
#define DH   48                  // C/HEADS
#define QKV_B (C3*HWP)           // elements per batch of conv-out tensor
#define X_B   (CC*HWP)
#define OUT_HALF ((size_t)BB*X_B)

typedef short bf16x8 __attribute__((ext_vector_type(8)));
typedef float f32x4  __attribute__((ext_vector_type(4)));

#define AS1(p) ((__attribute__((address_space(1))) void*)(p))
#define AS3(p) ((__attribute__((address_space(3))) void*)(p))

__device__ __forceinline__ ushort f2bf(float v) {
    union { float f; unsigned u; } a; a.f = v;
    unsigned r = a.u + 0x7FFF + ((a.u >> 16) & 1);   // RNE
    return (ushort)(r >> 16);
}
__device__ __forceinline__ float bf2f(ushort h) {
    union { float f; unsigned u; } a; a.u = ((unsigned)h) << 16; return a.f;
}

// ============================================================
// in (b,192,4096) fp32 -> out (b,4096,384) bf16: cols 0..191 hi, 192..383 lo
// (used for x, y, and for transposing vx, vy)
// ============================================================
__global__ __launch_bounds__(256) void convert_kernel(const float* __restrict__ in,
    ushort* __restrict__ xt)
{
    __shared__ float L[64][65];
    const int n0 = blockIdx.x * 64, c0 = blockIdx.y * 64, b = blockIdx.z;
    const int t = threadIdx.x;
    const float* ip = in + (size_t)b * X_B;
    #pragma unroll
    for (int i = 0; i < 16; i++) {
        int e = t + 256 * i;
        int r = e >> 6, col = e & 63;
        L[r][col] = ip[(size_t)(c0 + r) * HWP + n0 + col];
    }
    __syncthreads();
    #pragma unroll
    for (int i = 0; i < 4; i++) {
        int e = t + 256 * i;
        int n = e >> 4, c4 = e & 15;
        ushort hi[4], lo[4];
        #pragma unroll
        for (int j = 0; j < 4; j++) {
            float v = L[c4 * 4 + j][n];
            hi[j] = f2bf(v);
            lo[j] = f2bf(v - bf2f(hi[j]));
        }
        size_t base = ((size_t)(b * HWP + n0 + n)) * 384 + c0 + c4 * 4;
        *(ushort4*)&xt[base]       = make_ushort4(hi[0], hi[1], hi[2], hi[3]);
        *(ushort4*)&xt[base + 192] = make_ushort4(lo[0], lo[1], lo[2], lo[3]);
    }
}

// ============================================================
// w_qkv -> Wc(640,384) bf16 hi|lo, zero-padded rows
// ============================================================
__global__ __launch_bounds__(256) void wconvert_kernel(const float* __restrict__ wq,
    ushort* __restrict__ wc)
{
    int e = (blockIdx.x * 256 + threadIdx.x) * 4;
    int oc = e / 384, k = e % 384;
    ushort o[4] = {0, 0, 0, 0};
    if (oc < C3) {
        int kk = (k < 192) ? k : (k - 192);
        #pragma unroll
        for (int j = 0; j < 4; j++) {
            float v = wq[oc * CC + kk + j];
            ushort h = f2bf(v);
            o[j] = (k < 192) ? h : f2bf(v - bf2f(h));
        }
    }
    *(ushort4*)&wc[e] = make_ushort4(o[0], o[1], o[2], o[3]);
}

// ============================================================
// conv1x1 via MFMA, BK=32 double-buffered, ALL 8 batches: grid 1280 =
// 8 XCD x 32 nt x 5 mi -> exactly 5 blocks/CU, full residency, each XCD
// owns one batch (3.1 MB XT slice fits its 4 MB L2).
// Paired-row LDS swizzle: unit u -> rp=u>>3, p=(u&7)^(rp&7), r=(rp<<1)|(p>>2),
// c=p&3 (8 bank clusters, 2-way = free). Packed (lo<<16|hi) epilogue.
// ============================================================
__global__ __launch_bounds__(256) void conv1x1_mfma(const ushort* __restrict__ XT,
    const ushort* __restrict__ Wc, unsigned* __restrict__ op)
{
    __shared__ __align__(16) ushort Asb[2][128 * 32];   // 2 x 8 KB
    __shared__ __align__(16) ushort Bsb[2][128 * 32];   // 2 x 8 KB
    const int t = threadIdx.x;
    const int lane = t & 63, w = t >> 6;
    const int wm = w >> 1, wn = w & 1;
    const int fr = lane & 15, kg = lane >> 4;
    // decode: 1280 = 8 xcd x (32 nt x 5 mi); batch == xcd
    const int g = blockIdx.x;
    const int xcd = g & 7, s = g >> 3;          // s in [0,160)
    const int bg = xcd;
    const int nt = s / 5;                       // 0..31
    const int mi = s % 5;
    const int n0 = nt * 128;
    const int m0 = mi * 128;

    f32x4 acc[4][4] = {};

    auto STAGE = [&](int buf, int kc) {
        // term 0: Whi*Xhi (kc 0-5), term 1: Whi*Xlo (6-11), term 2: Wlo*Xhi (12-17)
        int km = (kc < 6) ? kc : ((kc < 12) ? kc - 6 : kc - 12);
        int cA = ((kc < 12) ? 0 : 192) + km * 32;
        int cB = ((kc >= 6 && kc < 12) ? 192 : 0) + km * 32;
        #pragma unroll
        for (int i = 0; i < 2; i++) {
            int u = i * 256 + w * 64 + lane;    // unit id 0..511 (16B units)
            int rp = u >> 3;
            int p = (u & 7) ^ (rp & 7);
            int r = (rp << 1) | (p >> 2);
            int c = p & 3;
            const ushort* ga = Wc + (size_t)(m0 + r) * 384 + cA + c * 8;
            __builtin_amdgcn_global_load_lds(AS1(ga), AS3(&Asb[buf][(i * 256 + w * 64) * 8]), 16, 0, 0);
            const ushort* gb = XT + ((size_t)(bg * HWP + n0 + r)) * 384 + cB + c * 8;
            __builtin_amdgcn_global_load_lds(AS1(gb), AS3(&Bsb[buf][(i * 256 + w * 64) * 8]), 16, 0, 0);
        }
    };

    STAGE(0, 0);
    __syncthreads();                 // tile 0 resident
    int cur = 0;
    for (int kc = 0; kc < 18; kc++) {
        if (kc < 17) STAGE(cur ^ 1, kc + 1);    // prefetch next tile under compute
        bf16x8 af[4], bfr[4];
        #pragma unroll
        for (int m = 0; m < 4; m++) {
            int R = wm * 64 + m * 16 + fr;
            int unit = (R >> 1) * 8 + ((((R & 1) << 2) | kg) ^ ((R >> 1) & 7));
            af[m] = *(const bf16x8*)&Asb[cur][unit * 8];
        }
        #pragma unroll
        for (int n = 0; n < 4; n++) {
            int R = wn * 64 + n * 16 + fr;
            int unit = (R >> 1) * 8 + ((((R & 1) << 2) | kg) ^ ((R >> 1) & 7));
            bfr[n] = *(const bf16x8*)&Bsb[cur][unit * 8];
        }
        #pragma unroll
        for (int m = 0; m < 4; m++)
            #pragma unroll
            for (int n = 0; n < 4; n++)
                acc[m][n] = __builtin_amdgcn_mfma_f32_16x16x32_bf16(af[m], bfr[n], acc[m][n], 0, 0, 0);
        __syncthreads();             // prefetch done + WAR safe
        cur ^= 1;
    }

    unsigned* ob = op + (size_t)bg * QKV_B;
    #pragma unroll
    for (int m = 0; m < 4; m++) {
        int oc = m0 + wm * 64 + m * 16 + kg * 4;
        #pragma unroll
        for (int n = 0; n < 4; n++) {
            int col = n0 + wn * 64 + n * 16 + fr;
            #pragma unroll
            for (int r = 0; r < 4; r++) {
                if (oc + r < C3) {
                    float v = acc[m][n][r];
                    ushort hi = f2bf(v);
                    ushort lo = f2bf(v - bf2f(hi));
                    ob[(size_t)(oc + r) * HWP + col] = ((unsigned)lo << 16) | hi;
                }
            }
        }
    }
}

// ============================================================
// depthwise 3x3 reading packed-uint t1 (all 8 batches, one launch);
// fused q/k hi-lo emission + L2 norm; v emitted fp32
// ============================================================
__global__ __launch_bounds__(256) void dw3x3_kernel(const unsigned* __restrict__ inp,
    const float* __restrict__ wd,
    ushort* __restrict__ qh, ushort* __restrict__ ql,
    float* __restrict__ vv, float* __restrict__ inv)
{
    __shared__ float P[66][72];
    const int bc = blockIdx.x;          // b*576 + ch
    const int b = bc / C3, ch = bc % C3;
    const int t = threadIdx.x;
    const unsigned* ip = inp + (size_t)bc * HWP;
    float wr[9];
    #pragma unroll
    for (int k = 0; k < 9; k++) wr[k] = wd[ch * 9 + k];
    for (int i = t; i < 66 * 72; i += 256) ((float*)P)[i] = 0.f;
    __syncthreads();
    #pragma unroll
    for (int i = 0; i < 4; i++) {
        int u = t + 256 * i;
        int y = u >> 4, cg = u & 15;
        uint4 p4 = *(const uint4*)&ip[u * 4];
        P[1 + y][4 + cg * 4 + 0] = bf2f((ushort)(p4.x & 0xFFFF)) + bf2f((ushort)(p4.x >> 16));
        P[1 + y][4 + cg * 4 + 1] = bf2f((ushort)(p4.y & 0xFFFF)) + bf2f((ushort)(p4.y >> 16));
        P[1 + y][4 + cg * 4 + 2] = bf2f((ushort)(p4.z & 0xFFFF)) + bf2f((ushort)(p4.z >> 16));
        P[1 + y][4 + cg * 4 + 3] = bf2f((ushort)(p4.w & 0xFFFF)) + bf2f((ushort)(p4.w >> 16));
    }
    __syncthreads();

    float ssum = 0.f;
    #pragma unroll
    for (int i = 0; i < 4; i++) {
        int u = t + 256 * i;
        int y0 = u >> 4;
        int x0 = (u & 15) * 4;
        float res[4] = {0.f, 0.f, 0.f, 0.f};
        #pragma unroll
        for (int dy = 0; dy < 3; dy++) {
            float4 A = *(float4*)&P[y0 + dy][x0];
            float4 Bv = *(float4*)&P[y0 + dy][x0 + 4];
            float4 Cv = *(float4*)&P[y0 + dy][x0 + 8];
            float c0 = A.w, c1 = Bv.x, c2 = Bv.y, c3 = Bv.z, c4 = Bv.w, c5 = Cv.x;
            float w0 = wr[dy*3], w1 = wr[dy*3+1], w2 = wr[dy*3+2];
            res[0] += w0*c0 + w1*c1 + w2*c2;
            res[1] += w0*c1 + w1*c2 + w2*c3;
            res[2] += w0*c2 + w1*c3 + w2*c4;
            res[3] += w0*c3 + w1*c4 + w2*c5;
        }
        #pragma unroll
        for (int k = 0; k < 4; k++) ssum += res[k] * res[k];
        if (ch < 384) {
            ushort hi[4], lo[4];
            #pragma unroll
            for (int k = 0; k < 4; k++) {
                hi[k] = f2bf(res[k]);
                lo[k] = f2bf(res[k] - bf2f(hi[k]));
            }
            size_t base = ((size_t)b * 384 + ch) * HWP + u * 4;
            *(ushort4*)&qh[base] = make_ushort4(hi[0], hi[1], hi[2], hi[3]);
            *(ushort4*)&ql[base] = make_ushort4(lo[0], lo[1], lo[2], lo[3]);
        } else {
            *(float4*)&vv[((size_t)b * CC + (ch - 384)) * HWP + u * 4] =
                make_float4(res[0], res[1], res[2], res[3]);
        }
    }
    if (ch < 384) {
        #pragma unroll
        for (int off = 32; off > 0; off >>= 1) ssum += __shfl_down(ssum, off);
        __shared__ float red[4];
        if ((t & 63) == 0) red[t >> 6] = ssum;
        __syncthreads();
        if (t == 0) {
            float tot = red[0] + red[1] + red[2] + red[3];
            inv[b * 384 + ch] = 1.f / fmaxf(sqrtf(tot), 1e-12f);
        }
    }
}

// ============================================================
// stacked Gram via MFMA (proven, unchanged)
// ============================================================
__global__ __launch_bounds__(256) void gram_mfma(const ushort* __restrict__ qhx,
    const ushort* __restrict__ qlx, const ushort* __restrict__ qhy,
    const ushort* __restrict__ qly, float* __restrict__ spart)
{
    __shared__ __align__(16) ushort As[96 * 64];
    __shared__ __align__(16) ushort Bs[96 * 64];
    const int chunk = blockIdx.x, bh = blockIdx.y;
    const int b = bh >> 2, h = bh & 3;
    const int t = threadIdx.x;
    const int lane = t & 63, w = t >> 6;
    const int wm = w >> 1, wn = w & 1;
    const int fr = lane & 15, kg = lane >> 4;

    const size_t qbase = ((size_t)b * 384 + h * DH) * HWP;
    const size_t kbase = ((size_t)b * 384 + 192 + h * DH) * HWP;

    f32x4 acc[3][3] = {};

    for (int term = 0; term < 3; term++) {
        const ushort* Aqx = (term == 2) ? qlx : qhx;
        const ushort* Aqy = (term == 2) ? qly : qhy;
        const ushort* Bkx = (term == 1) ? qlx : qhx;
        const ushort* Bky = (term == 1) ? qly : qhy;
        for (int ks = 0; ks < 8; ks++) {
            const int n0 = chunk * 512 + ks * 64;
            #pragma unroll
            for (int i = 0; i < 3; i++) {
                int u = i * 256 + w * 64 + lane;
                int r = u >> 3, c = u & 7;
                int cs = c ^ (r & 7);
                const ushort* ga = ((r < DH) ? (Aqx + qbase + (size_t)r * HWP)
                                             : (Aqy + qbase + (size_t)(r - DH) * HWP))
                                   + n0 + cs * 8;
                __builtin_amdgcn_global_load_lds(AS1(ga), AS3(&As[(size_t)(i * 4 + w) * 512]), 16, 0, 0);
                const ushort* gb = ((r < DH) ? (Bkx + kbase + (size_t)r * HWP)
                                             : (Bky + kbase + (size_t)(r - DH) * HWP))
                                   + n0 + cs * 8;
                __builtin_amdgcn_global_load_lds(AS1(gb), AS3(&Bs[(size_t)(i * 4 + w) * 512]), 16, 0, 0);
            }
            __syncthreads();
            #pragma unroll
            for (int kq = 0; kq < 8; kq += 4) {
                bf16x8 af[3], bfr[3];
                #pragma unroll
                for (int m = 0; m < 3; m++) {
                    int R = wm * DH + m * 16 + fr;
                    int unit = R * 8 + ((kq + kg) ^ (R & 7));
                    af[m] = *(const bf16x8*)&As[unit * 8];
                }
                #pragma unroll
                for (int n = 0; n < 3; n++) {
                    int R = wn * DH + n * 16 + fr;
                    int unit = R * 8 + ((kq + kg) ^ (R & 7));
                    bfr[n] = *(const bf16x8*)&Bs[unit * 8];
                }
                #pragma unroll
                for (int m = 0; m < 3; m++)
                    #pragma unroll
                    for (int n = 0; n < 3; n++)
                        acc[m][n] = __builtin_amdgcn_mfma_f32_16x16x32_bf16(af[m], bfr[n], acc[m][n], 0, 0, 0);
            }
            __syncthreads();
        }
    }

    float* sp = spart + ((size_t)chunk * 32 + bh) * 9216;
    #pragma unroll
    for (int m = 0; m < 3; m++) {
        int row = wm * DH + m * 16 + kg * 4;
        #pragma unroll
        for (int n = 0; n < 3; n++) {
            int col = wn * DH + n * 16 + fr;
            #pragma unroll
            for (int r = 0; r < 4; r++)
                sp[(row + r) * 96 + col] = acc[m][n][r];
        }
    }
}

// ============================================================
// combine split-K partials, scale, softmax; emit bf16 coefficient matrix
// M''(96 x 384): six BK=64 chunks [Mhx|Mhy|Mlx|Mly|Mhx|Mhy], pad cols zeroed
// ============================================================
__global__ __launch_bounds__(256) void softmax_kernel(const float* __restrict__ spart,
    const float* __restrict__ invx, const float* __restrict__ invy,
    const float* __restrict__ temp, ushort* __restrict__ mpp)
{
    __shared__ float G[96][97];
    const int bh = blockIdx.x, b = bh >> 2, h = bh & 3;
    const int t = threadIdx.x;
    const float ts = temp[h];
    for (int i = 0; i < 36; i++) {
        int f = t + 256 * i;
        float s = 0.f;
        #pragma unroll
        for (int cch = 0; cch < 8; cch++)
            s += spart[((size_t)cch * 32 + bh) * 9216 + f];
        int r = f / 96, c = f % 96;
        float iq = (r < DH) ? invx[b*384 + h*DH + r] : invy[b*384 + h*DH + (r-DH)];
        float ik = (c < DH) ? invx[b*384 + CC + h*DH + c] : invy[b*384 + CC + h*DH + (c-DH)];
        G[r][c] = s * iq * ik * ts;
    }
    __syncthreads();
    if (t < 192) {
        int r = t >> 1, hf = t & 1;
        float* rowp = &G[r][hf * DH];
        float m = rowp[0];
        for (int i = 1; i < DH; i++) m = fmaxf(m, rowp[i]);
        float s = 0.f;
        for (int i = 0; i < DH; i++) { float e = __expf(rowp[i] - m); rowp[i] = e; s += e; }
        float inv = 1.f / s;
        for (int i = 0; i < DH; i++) rowp[i] *= inv;
    }
    __syncthreads();
    ushort* mo = mpp + (size_t)bh * 96 * 384;
    for (int i = 0; i < 36; i++) {
        int f = t + 256 * i;                 // 96 rows x 96 pad cols
        int r = f / 96, p = f % 96;
        int ch = p >> 4, j = p & 15;
        mo[(size_t)r * 384 + ch * 64 + 48 + j] = 0;
    }
    for (int i = 0; i < 36; i++) {
        int f = t + 256 * i;
        int r = f / 96, c = f % 96;
        float v;
        if (c < DH) v = (r < DH) ? G[DH + r][c] : G[r - DH][c];
        else        v = G[r][c];
        ushort hi = f2bf(v);
        ushort lo = f2bf(v - bf2f(hi));
        size_t rb = (size_t)r * 384;
        if (c < DH) {
            mo[rb + c] = hi;
            mo[rb + 128 + c] = lo;
            mo[rb + 256 + c] = hi;
        } else {
            int cp = c - DH;
            mo[rb + 64 + cp] = hi;
            mo[rb + 192 + cp] = lo;
            mo[rb + 320 + cp] = hi;
        }
    }
}

// ============================================================
// output GEMM via MFMA (proven, unchanged)
// ============================================================
__global__ __launch_bounds__(256) void outmm_mfma(const ushort* __restrict__ VTx,
    const ushort* __restrict__ VTy, const ushort* __restrict__ mpp,
    float* __restrict__ out)
{
    __shared__ __align__(16) ushort As[96 * 64];
    __shared__ __align__(16) ushort Bs[128 * 64];
    const int t = threadIdx.x;
    const int lane = t & 63, w = t >> 6;
    const int wm = w >> 1, wn = w & 1;
    const int fr = lane & 15, kg = lane >> 4;
    const int nc = blockIdx.x, bh = blockIdx.y;
    const int b = bh >> 2, h = bh & 3;
    const int n0 = nc * 128;
    const ushort* mp = mpp + (size_t)bh * 96 * 384;

    f32x4 acc[3][4] = {};

    for (int kc = 0; kc < 6; kc++) {
        const ushort* Vsrc = (kc & 1) ? VTy : VTx;
        const int coff = ((kc < 4) ? 0 : 192) + h * DH;
        #pragma unroll
        for (int i = 0; i < 3; i++) {
            int u = i * 256 + w * 64 + lane;
            int r = u >> 3, c = u & 7;
            int cs = c ^ (r & 7);
            const ushort* ga = mp + (size_t)r * 384 + kc * 64 + cs * 8;
            __builtin_amdgcn_global_load_lds(AS1(ga), AS3(&As[(size_t)(i * 4 + w) * 512]), 16, 0, 0);
        }
        #pragma unroll
        for (int i = 0; i < 4; i++) {
            int u = i * 256 + w * 64 + lane;
            int r = u >> 3, c = u & 7;
            int cs = c ^ (r & 7);
            const ushort* gb = Vsrc + ((size_t)(b * HWP + n0 + r)) * 384 + coff + cs * 8;
            __builtin_amdgcn_global_load_lds(AS1(gb), AS3(&Bs[(size_t)(i * 4 + w) * 512]), 16, 0, 0);
        }
        __syncthreads();
        #pragma unroll
        for (int kq = 0; kq < 8; kq += 4) {
            bf16x8 af[3], bfr[4];
            #pragma unroll
            for (int m = 0; m < 3; m++) {
                int R = wm * DH + m * 16 + fr;
                int unit = R * 8 + ((kq + kg) ^ (R & 7));
                af[m] = *(const bf16x8*)&As[unit * 8];
            }
            #pragma unroll
            for (int n = 0; n < 4; n++) {
                int R = wn * 64 + n * 16 + fr;
                int unit = R * 8 + ((kq + kg) ^ (R & 7));
                bfr[n] = *(const bf16x8*)&Bs[unit * 8];
            }
            #pragma unroll
            for (int m = 0; m < 3; m++)
                #pragma unroll
                for (int n = 0; n < 4; n++)
                    acc[m][n] = __builtin_amdgcn_mfma_f32_16x16x32_bf16(af[m], bfr[n], acc[m][n], 0, 0, 0);
        }
        __syncthreads();
    }

    #pragma unroll
    for (int m = 0; m < 3; m++) {
        int row = wm * DH + m * 16 + kg * 4;
        #pragma unroll
        for (int n = 0; n < 4; n++) {
            int col = n0 + wn * 64 + n * 16 + fr;
            #pragma unroll
            for (int r = 0; r < 4; r++) {
                int rr = row + r;
                float* dst = (rr < DH)
                    ? (out + (size_t)b * X_B + (h * DH + rr) * HWP + col)
                    : (out + OUT_HALF + (size_t)b * X_B + (h * DH + rr - DH) * HWP + col);
                *dst = acc[m][n][r];
            }
        }
    }
}

// ============================================================
extern "C" void kernel_launch(void* const* d_in, const int* in_sizes, int n_in,
                              void* d_out, int out_size, void* d_ws, size_t ws_size,
                              hipStream_t stream)
{
    const float* x  = (const float*)d_in[0];
    const float* y  = (const float*)d_in[1];
    const float* wq = (const float*)d_in[2];
    const float* wd = (const float*)d_in[3];
    const float* tp = (const float*)d_in[4];
    float* out = (float*)d_out;
    float* ws = (float*)d_ws;

    // ---- workspace layout (float units), peak 226.5 MB (ws = 256 MB) ----
    // QKF = elements of one q/k hi-or-lo array in float units:
    //   [8][384][4096] ushort = 12,582,912 ushort = 6,291,456 floats (25.2 MB)
    const size_t QKF = 6291456;
    ushort* qhx = (ushort*)(ws);                 // region A
    ushort* qlx = (ushort*)(ws + QKF);
    float*  vx  = ws + 2 * QKF;                  // [8][192][4096] fp32, 25.2 MB
    ushort* qhy = (ushort*)(ws + 3 * QKF);       // region B
    ushort* qly = (ushort*)(ws + 4 * QKF);
    float*  vy  = ws + 5 * QKF;
    float*  t1r = ws + 6 * QKF;                  // region C: 18,874,368 floats (75.5 MB)
    unsigned* t1p = (unsigned*)t1r;              // [8][576][4096] packed uints
    float*  invx = ws + 6 * QKF + 18874368;      // tail: 3072 + 3072 floats
    float*  invy = invx + 3072;
    // aliases over region B (dead until dw-y writes it):
    ushort* XT  = qhy;                           // [8][4096][384] ushort = QKF floats
    ushort* Wc  = qly;                           // 245,760 ushort
    // aliases over region C (dead after dw-y):
    ushort* VTx  = (ushort*)t1r;                 // QKF floats
    ushort* VTy  = (ushort*)(t1r + QKF);
    float*  spart = t1r + 2 * QKF;               // 2,359,296 floats
    ushort* Mpp  = (ushort*)(t1r + 2 * QKF + 2359296);   // 1,179,648 ushort

    wconvert_kernel<<<240, 256, 0, stream>>>(wq, Wc);

    // tensor x: convert -> conv (8 batches) -> dw (8 batches)
    convert_kernel<<<dim3(64, 3, BB), 256, 0, stream>>>(x, XT);
    conv1x1_mfma<<<1280, 256, 0, stream>>>(XT, Wc, t1p);
    dw3x3_kernel<<<BB * C3, 256, 0, stream>>>(t1p, wd, qhx, qlx, vx, invx);

    // tensor y (XT/Wc regions overwritten only after conv-y by dw-y)
    convert_kernel<<<dim3(64, 3, BB), 256, 0, stream>>>(y, XT);
    conv1x1_mfma<<<1280, 256, 0, stream>>>(XT, Wc, t1p);
    dw3x3_kernel<<<BB * C3, 256, 0, stream>>>(t1p, wd, qhy, qly, vy, invy);

    // transpose v to XT-format into dead t1 region
    convert_kernel<<<dim3(64, 3, BB), 256, 0, stream>>>(vx, VTx);
    convert_kernel<<<dim3(64, 3, BB), 256, 0, stream>>>(vy, VTy);

    gram_mfma<<<dim3(8, 32), 256, 0, stream>>>(qhx, qlx, qhy, qly, spart);
    softmax_kernel<<<32, 256, 0, stream>>>(spart, invx, invy, tp, Mpp);
    outmm_mfma<<<dim3(HWP / 128, 32), 256, 0, stream>>>(VTx, VTy, Mpp, out);
}

// Round 10
// 232.515 us; speedup vs baseline: 1.3566x; 1.1493x over previous
//
#include <hip/hip_runtime.h>

// ---- problem constants ----
#define CC   192                 // C
#define C3   576                 // 3C
#define HH   64
#define WW   64
#define HWP  4096                // H*W
#define BB   8
#define DH   48                  // C/HEADS
#define QKV_B (C3*HWP)           // elements per batch of conv-out tensor
#define X_B   (CC*HWP)
#define OUT_HALF ((size_t)BB*X_B)

typedef short bf16x8 __attribute__((ext_vector_type(8)));
typedef float f32x4  __attribute__((ext_vector_type(4)));

#define AS1(p) ((__attribute__((address_space(1))) void*)(p))
#define AS3(p) ((__attribute__((address_space(3))) void*)(p))

__device__ __forceinline__ ushort f2bf(float v) {
    union { float f; unsigned u; } a; a.f = v;
    unsigned r = a.u + 0x7FFF + ((a.u >> 16) & 1);   // RNE
    return (ushort)(r >> 16);
}
__device__ __forceinline__ float bf2f(ushort h) {
    union { float f; unsigned u; } a; a.u = ((unsigned)h) << 16; return a.f;
}

// ============================================================
// in (b,192,4096) fp32 -> out (b,4096,384) bf16 hi|lo (for v transpose)
// ============================================================
__global__ __launch_bounds__(256) void convert_kernel(const float* __restrict__ in,
    ushort* __restrict__ xt)
{
    __shared__ float L[64][65];
    const int n0 = blockIdx.x * 64, c0 = blockIdx.y * 64, b = blockIdx.z;
    const int t = threadIdx.x;
    const float* ip = in + (size_t)b * X_B;
    #pragma unroll
    for (int i = 0; i < 16; i++) {
        int e = t + 256 * i;
        int r = e >> 6, col = e & 63;
        L[r][col] = ip[(size_t)(c0 + r) * HWP + n0 + col];
    }
    __syncthreads();
    #pragma unroll
    for (int i = 0; i < 4; i++) {
        int e = t + 256 * i;
        int n = e >> 4, c4 = e & 15;
        ushort hi[4], lo[4];
        #pragma unroll
        for (int j = 0; j < 4; j++) {
            float v = L[c4 * 4 + j][n];
            hi[j] = f2bf(v);
            lo[j] = f2bf(v - bf2f(hi[j]));
        }
        size_t base = ((size_t)(b * HWP + n0 + n)) * 384 + c0 + c4 * 4;
        *(ushort4*)&xt[base]       = make_ushort4(hi[0], hi[1], hi[2], hi[3]);
        *(ushort4*)&xt[base + 192] = make_ushort4(lo[0], lo[1], lo[2], lo[3]);
    }
}

// ============================================================
// in (b,192,4096) fp32 -> out (b,4096,192) bf16 SINGLE (conv input X)
// ============================================================
__global__ __launch_bounds__(256) void convert_single_kernel(const float* __restrict__ in,
    ushort* __restrict__ xt)
{
    __shared__ float L[64][65];
    const int n0 = blockIdx.x * 64, c0 = blockIdx.y * 64, b = blockIdx.z;
    const int t = threadIdx.x;
    const float* ip = in + (size_t)b * X_B;
    #pragma unroll
    for (int i = 0; i < 16; i++) {
        int e = t + 256 * i;
        int r = e >> 6, col = e & 63;
        L[r][col] = ip[(size_t)(c0 + r) * HWP + n0 + col];
    }
    __syncthreads();
    #pragma unroll
    for (int i = 0; i < 4; i++) {
        int e = t + 256 * i;
        int n = e >> 4, c4 = e & 15;
        ushort hi[4];
        #pragma unroll
        for (int j = 0; j < 4; j++)
            hi[j] = f2bf(L[c4 * 4 + j][n]);
        size_t base = ((size_t)(b * HWP + n0 + n)) * 192 + c0 + c4 * 4;
        *(ushort4*)&xt[base] = make_ushort4(hi[0], hi[1], hi[2], hi[3]);
    }
}

// ============================================================
// w_qkv -> Wc(640,384) bf16 hi|lo, zero-padded rows
// ============================================================
__global__ __launch_bounds__(256) void wconvert_kernel(const float* __restrict__ wq,
    ushort* __restrict__ wc)
{
    int e = (blockIdx.x * 256 + threadIdx.x) * 4;
    int oc = e / 384, k = e % 384;
    ushort o[4] = {0, 0, 0, 0};
    if (oc < C3) {
        int kk = (k < 192) ? k : (k - 192);
        #pragma unroll
        for (int j = 0; j < 4; j++) {
            float v = wq[oc * CC + kk + j];
            ushort h = f2bf(v);
            o[j] = (k < 192) ? h : f2bf(v - bf2f(h));
        }
    }
    *(ushort4*)&wc[e] = make_ushort4(o[0], o[1], o[2], o[3]);
}

// ============================================================
// conv1x1 via MFMA: t1 = (Whi + Wlo) * X  with X single bf16.
// Shared staging: per physical BK=32 chunk stage {Whi, Wlo, X} ONCE, run
// both terms' MFMAs from it (144 KB staged / tile vs round-9's 288 KB).
// 6 chunks, double-buffered (48 KB LDS -> 3 blocks/CU). Grid 1280 =
// 8 XCD x 32 nt x 5 mi, batch == XCD (L2 locality). Paired-row swizzle
// (proven round 9, 0 bank conflicts). Packed (lo<<16|hi) epilogue.
// ============================================================
__global__ __launch_bounds__(256) void conv1x1_mfma(const ushort* __restrict__ XT,
    const ushort* __restrict__ Wc, unsigned* __restrict__ op)
{
    __shared__ __align__(16) ushort Wh[2][128 * 32];    // 2 x 8 KB
    __shared__ __align__(16) ushort Wl[2][128 * 32];    // 2 x 8 KB
    __shared__ __align__(16) ushort Xs[2][128 * 32];    // 2 x 8 KB
    const int t = threadIdx.x;
    const int lane = t & 63, w = t >> 6;
    const int wm = w >> 1, wn = w & 1;
    const int fr = lane & 15, kg = lane >> 4;
    const int g = blockIdx.x;
    const int xcd = g & 7, s = g >> 3;          // s in [0,160)
    const int bg = xcd;
    const int nt = s / 5;                       // 0..31
    const int mi = s % 5;
    const int n0 = nt * 128;
    const int m0 = mi * 128;

    f32x4 acc[4][4] = {};

    auto STAGE = [&](int buf, int ck) {
        const int k0 = ck * 32;
        #pragma unroll
        for (int i = 0; i < 2; i++) {
            int u = i * 256 + w * 64 + lane;    // unit id 0..511 (16B units)
            int rp = u >> 3;
            int p = (u & 7) ^ (rp & 7);
            int r = (rp << 1) | (p >> 2);
            int c = p & 3;
            const ushort* gwh = Wc + (size_t)(m0 + r) * 384 + k0 + c * 8;
            __builtin_amdgcn_global_load_lds(AS1(gwh), AS3(&Wh[buf][(i * 256 + w * 64) * 8]), 16, 0, 0);
            const ushort* gwl = Wc + (size_t)(m0 + r) * 384 + 192 + k0 + c * 8;
            __builtin_amdgcn_global_load_lds(AS1(gwl), AS3(&Wl[buf][(i * 256 + w * 64) * 8]), 16, 0, 0);
            const ushort* gx = XT + ((size_t)(bg * HWP + n0 + r)) * 192 + k0 + c * 8;
            __builtin_amdgcn_global_load_lds(AS1(gx), AS3(&Xs[buf][(i * 256 + w * 64) * 8]), 16, 0, 0);
        }
    };

    STAGE(0, 0);
    __syncthreads();                 // chunk 0 resident
    int cur = 0;
    for (int ck = 0; ck < 6; ck++) {
        if (ck < 5) STAGE(cur ^ 1, ck + 1);     // prefetch next chunk under compute
        bf16x8 afh[4], afl[4], bfr[4];
        #pragma unroll
        for (int m = 0; m < 4; m++) {
            int R = wm * 64 + m * 16 + fr;
            int unit = (R >> 1) * 8 + ((((R & 1) << 2) | kg) ^ ((R >> 1) & 7));
            afh[m] = *(const bf16x8*)&Wh[cur][unit * 8];
            afl[m] = *(const bf16x8*)&Wl[cur][unit * 8];
        }
        #pragma unroll
        for (int n = 0; n < 4; n++) {
            int R = wn * 64 + n * 16 + fr;
            int unit = (R >> 1) * 8 + ((((R & 1) << 2) | kg) ^ ((R >> 1) & 7));
            bfr[n] = *(const bf16x8*)&Xs[cur][unit * 8];
        }
        #pragma unroll
        for (int m = 0; m < 4; m++)
            #pragma unroll
            for (int n = 0; n < 4; n++)
                acc[m][n] = __builtin_amdgcn_mfma_f32_16x16x32_bf16(afh[m], bfr[n], acc[m][n], 0, 0, 0);
        #pragma unroll
        for (int m = 0; m < 4; m++)
            #pragma unroll
            for (int n = 0; n < 4; n++)
                acc[m][n] = __builtin_amdgcn_mfma_f32_16x16x32_bf16(afl[m], bfr[n], acc[m][n], 0, 0, 0);
        __syncthreads();             // prefetch done + WAR safe
        cur ^= 1;
    }

    unsigned* ob = op + (size_t)bg * QKV_B;
    #pragma unroll
    for (int m = 0; m < 4; m++) {
        int oc = m0 + wm * 64 + m * 16 + kg * 4;
        #pragma unroll
        for (int n = 0; n < 4; n++) {
            int col = n0 + wn * 64 + n * 16 + fr;
            #pragma unroll
            for (int r = 0; r < 4; r++) {
                if (oc + r < C3) {
                    float v = acc[m][n][r];
                    ushort hi = f2bf(v);
                    ushort lo = f2bf(v - bf2f(hi));
                    ob[(size_t)(oc + r) * HWP + col] = ((unsigned)lo << 16) | hi;
                }
            }
        }
    }
}

// ============================================================
// depthwise 3x3 reading packed-uint t1 (all 8 batches, one launch);
// fused q/k hi-lo emission + L2 norm; v emitted fp32
// ============================================================
__global__ __launch_bounds__(256) void dw3x3_kernel(const unsigned* __restrict__ inp,
    const float* __restrict__ wd,
    ushort* __restrict__ qh, ushort* __restrict__ ql,
    float* __restrict__ vv, float* __restrict__ inv)
{
    __shared__ float P[66][72];
    const int bc = blockIdx.x;          // b*576 + ch
    const int b = bc / C3, ch = bc % C3;
    const int t = threadIdx.x;
    const unsigned* ip = inp + (size_t)bc * HWP;
    float wr[9];
    #pragma unroll
    for (int k = 0; k < 9; k++) wr[k] = wd[ch * 9 + k];
    for (int i = t; i < 66 * 72; i += 256) ((float*)P)[i] = 0.f;
    __syncthreads();
    #pragma unroll
    for (int i = 0; i < 4; i++) {
        int u = t + 256 * i;
        int y = u >> 4, cg = u & 15;
        uint4 p4 = *(const uint4*)&ip[u * 4];
        P[1 + y][4 + cg * 4 + 0] = bf2f((ushort)(p4.x & 0xFFFF)) + bf2f((ushort)(p4.x >> 16));
        P[1 + y][4 + cg * 4 + 1] = bf2f((ushort)(p4.y & 0xFFFF)) + bf2f((ushort)(p4.y >> 16));
        P[1 + y][4 + cg * 4 + 2] = bf2f((ushort)(p4.z & 0xFFFF)) + bf2f((ushort)(p4.z >> 16));
        P[1 + y][4 + cg * 4 + 3] = bf2f((ushort)(p4.w & 0xFFFF)) + bf2f((ushort)(p4.w >> 16));
    }
    __syncthreads();

    float ssum = 0.f;
    #pragma unroll
    for (int i = 0; i < 4; i++) {
        int u = t + 256 * i;
        int y0 = u >> 4;
        int x0 = (u & 15) * 4;
        float res[4] = {0.f, 0.f, 0.f, 0.f};
        #pragma unroll
        for (int dy = 0; dy < 3; dy++) {
            float4 A = *(float4*)&P[y0 + dy][x0];
            float4 Bv = *(float4*)&P[y0 + dy][x0 + 4];
            float4 Cv = *(float4*)&P[y0 + dy][x0 + 8];
            float c0 = A.w, c1 = Bv.x, c2 = Bv.y, c3 = Bv.z, c4 = Bv.w, c5 = Cv.x;
            float w0 = wr[dy*3], w1 = wr[dy*3+1], w2 = wr[dy*3+2];
            res[0] += w0*c0 + w1*c1 + w2*c2;
            res[1] += w0*c1 + w1*c2 + w2*c3;
            res[2] += w0*c2 + w1*c3 + w2*c4;
            res[3] += w0*c3 + w1*c4 + w2*c5;
        }
        #pragma unroll
        for (int k = 0; k < 4; k++) ssum += res[k] * res[k];
        if (ch < 384) {
            ushort hi[4], lo[4];
            #pragma unroll
            for (int k = 0; k < 4; k++) {
                hi[k] = f2bf(res[k]);
                lo[k] = f2bf(res[k] - bf2f(hi[k]));
            }
            size_t base = ((size_t)b * 384 + ch) * HWP + u * 4;
            *(ushort4*)&qh[base] = make_ushort4(hi[0], hi[1], hi[2], hi[3]);
            *(ushort4*)&ql[base] = make_ushort4(lo[0], lo[1], lo[2], lo[3]);
        } else {
            *(float4*)&vv[((size_t)b * CC + (ch - 384)) * HWP + u * 4] =
                make_float4(res[0], res[1], res[2], res[3]);
        }
    }
    if (ch < 384) {
        #pragma unroll
        for (int off = 32; off > 0; off >>= 1) ssum += __shfl_down(ssum, off);
        __shared__ float red[4];
        if ((t & 63) == 0) red[t >> 6] = ssum;
        __syncthreads();
        if (t == 0) {
            float tot = red[0] + red[1] + red[2] + red[3];
            inv[b * 384 + ch] = 1.f / fmaxf(sqrtf(tot), 1e-12f);
        }
    }
}

// ============================================================
// stacked Gram via MFMA (proven, unchanged)
// ============================================================
__global__ __launch_bounds__(256) void gram_mfma(const ushort* __restrict__ qhx,
    const ushort* __restrict__ qlx, const ushort* __restrict__ qhy,
    const ushort* __restrict__ qly, float* __restrict__ spart)
{
    __shared__ __align__(16) ushort As[96 * 64];
    __shared__ __align__(16) ushort Bs[96 * 64];
    const int chunk = blockIdx.x, bh = blockIdx.y;
    const int b = bh >> 2, h = bh & 3;
    const int t = threadIdx.x;
    const int lane = t & 63, w = t >> 6;
    const int wm = w >> 1, wn = w & 1;
    const int fr = lane & 15, kg = lane >> 4;

    const size_t qbase = ((size_t)b * 384 + h * DH) * HWP;
    const size_t kbase = ((size_t)b * 384 + 192 + h * DH) * HWP;

    f32x4 acc[3][3] = {};

    for (int term = 0; term < 3; term++) {
        const ushort* Aqx = (term == 2) ? qlx : qhx;
        const ushort* Aqy = (term == 2) ? qly : qhy;
        const ushort* Bkx = (term == 1) ? qlx : qhx;
        const ushort* Bky = (term == 1) ? qly : qhy;
        for (int ks = 0; ks < 8; ks++) {
            const int n0 = chunk * 512 + ks * 64;
            #pragma unroll
            for (int i = 0; i < 3; i++) {
                int u = i * 256 + w * 64 + lane;
                int r = u >> 3, c = u & 7;
                int cs = c ^ (r & 7);
                const ushort* ga = ((r < DH) ? (Aqx + qbase + (size_t)r * HWP)
                                             : (Aqy + qbase + (size_t)(r - DH) * HWP))
                                   + n0 + cs * 8;
                __builtin_amdgcn_global_load_lds(AS1(ga), AS3(&As[(size_t)(i * 4 + w) * 512]), 16, 0, 0);
                const ushort* gb = ((r < DH) ? (Bkx + kbase + (size_t)r * HWP)
                                             : (Bky + kbase + (size_t)(r - DH) * HWP))
                                   + n0 + cs * 8;
                __builtin_amdgcn_global_load_lds(AS1(gb), AS3(&Bs[(size_t)(i * 4 + w) * 512]), 16, 0, 0);
            }
            __syncthreads();
            #pragma unroll
            for (int kq = 0; kq < 8; kq += 4) {
                bf16x8 af[3], bfr[3];
                #pragma unroll
                for (int m = 0; m < 3; m++) {
                    int R = wm * DH + m * 16 + fr;
                    int unit = R * 8 + ((kq + kg) ^ (R & 7));
                    af[m] = *(const bf16x8*)&As[unit * 8];
                }
                #pragma unroll
                for (int n = 0; n < 3; n++) {
                    int R = wn * DH + n * 16 + fr;
                    int unit = R * 8 + ((kq + kg) ^ (R & 7));
                    bfr[n] = *(const bf16x8*)&Bs[unit * 8];
                }
                #pragma unroll
                for (int m = 0; m < 3; m++)
                    #pragma unroll
                    for (int n = 0; n < 3; n++)
                        acc[m][n] = __builtin_amdgcn_mfma_f32_16x16x32_bf16(af[m], bfr[n], acc[m][n], 0, 0, 0);
            }
            __syncthreads();
        }
    }

    float* sp = spart + ((size_t)chunk * 32 + bh) * 9216;
    #pragma unroll
    for (int m = 0; m < 3; m++) {
        int row = wm * DH + m * 16 + kg * 4;
        #pragma unroll
        for (int n = 0; n < 3; n++) {
            int col = wn * DH + n * 16 + fr;
            #pragma unroll
            for (int r = 0; r < 4; r++)
                sp[(row + r) * 96 + col] = acc[m][n][r];
        }
    }
}

// ============================================================
// combine split-K partials, scale, softmax; emit bf16 coefficient matrix
// M''(96 x 384): six BK=64 chunks [Mhx|Mhy|Mlx|Mly|Mhx|Mhy], pad cols zeroed
// ============================================================
__global__ __launch_bounds__(256) void softmax_kernel(const float* __restrict__ spart,
    const float* __restrict__ invx, const float* __restrict__ invy,
    const float* __restrict__ temp, ushort* __restrict__ mpp)
{
    __shared__ float G[96][97];
    const int bh = blockIdx.x, b = bh >> 2, h = bh & 3;
    const int t = threadIdx.x;
    const float ts = temp[h];
    for (int i = 0; i < 36; i++) {
        int f = t + 256 * i;
        float s = 0.f;
        #pragma unroll
        for (int cch = 0; cch < 8; cch++)
            s += spart[((size_t)cch * 32 + bh) * 9216 + f];
        int r = f / 96, c = f % 96;
        float iq = (r < DH) ? invx[b*384 + h*DH + r] : invy[b*384 + h*DH + (r-DH)];
        float ik = (c < DH) ? invx[b*384 + CC + h*DH + c] : invy[b*384 + CC + h*DH + (c-DH)];
        G[r][c] = s * iq * ik * ts;
    }
    __syncthreads();
    if (t < 192) {
        int r = t >> 1, hf = t & 1;
        float* rowp = &G[r][hf * DH];
        float m = rowp[0];
        for (int i = 1; i < DH; i++) m = fmaxf(m, rowp[i]);
        float s = 0.f;
        for (int i = 0; i < DH; i++) { float e = __expf(rowp[i] - m); rowp[i] = e; s += e; }
        float inv = 1.f / s;
        for (int i = 0; i < DH; i++) rowp[i] *= inv;
    }
    __syncthreads();
    ushort* mo = mpp + (size_t)bh * 96 * 384;
    for (int i = 0; i < 36; i++) {
        int f = t + 256 * i;                 // 96 rows x 96 pad cols
        int r = f / 96, p = f % 96;
        int ch = p >> 4, j = p & 15;
        mo[(size_t)r * 384 + ch * 64 + 48 + j] = 0;
    }
    for (int i = 0; i < 36; i++) {
        int f = t + 256 * i;
        int r = f / 96, c = f % 96;
        float v;
        if (c < DH) v = (r < DH) ? G[DH + r][c] : G[r - DH][c];
        else        v = G[r][c];
        ushort hi = f2bf(v);
        ushort lo = f2bf(v - bf2f(hi));
        size_t rb = (size_t)r * 384;
        if (c < DH) {
            mo[rb + c] = hi;
            mo[rb + 128 + c] = lo;
            mo[rb + 256 + c] = hi;
        } else {
            int cp = c - DH;
            mo[rb + 64 + cp] = hi;
            mo[rb + 192 + cp] = lo;
            mo[rb + 320 + cp] = hi;
        }
    }
}

// ============================================================
// output GEMM via MFMA (proven, unchanged)
// ============================================================
__global__ __launch_bounds__(256) void outmm_mfma(const ushort* __restrict__ VTx,
    const ushort* __restrict__ VTy, const ushort* __restrict__ mpp,
    float* __restrict__ out)
{
    __shared__ __align__(16) ushort As[96 * 64];
    __shared__ __align__(16) ushort Bs[128 * 64];
    const int t = threadIdx.x;
    const int lane = t & 63, w = t >> 6;
    const int wm = w >> 1, wn = w & 1;
    const int fr = lane & 15, kg = lane >> 4;
    const int nc = blockIdx.x, bh = blockIdx.y;
    const int b = bh >> 2, h = bh & 3;
    const int n0 = nc * 128;
    const ushort* mp = mpp + (size_t)bh * 96 * 384;

    f32x4 acc[3][4] = {};

    for (int kc = 0; kc < 6; kc++) {
        const ushort* Vsrc = (kc & 1) ? VTy : VTx;
        const int coff = ((kc < 4) ? 0 : 192) + h * DH;
        #pragma unroll
        for (int i = 0; i < 3; i++) {
            int u = i * 256 + w * 64 + lane;
            int r = u >> 3, c = u & 7;
            int cs = c ^ (r & 7);
            const ushort* ga = mp + (size_t)r * 384 + kc * 64 + cs * 8;
            __builtin_amdgcn_global_load_lds(AS1(ga), AS3(&As[(size_t)(i * 4 + w) * 512]), 16, 0, 0);
        }
        #pragma unroll
        for (int i = 0; i < 4; i++) {
            int u = i * 256 + w * 64 + lane;
            int r = u >> 3, c = u & 7;
            int cs = c ^ (r & 7);
            const ushort* gb = Vsrc + ((size_t)(b * HWP + n0 + r)) * 384 + coff + cs * 8;
            __builtin_amdgcn_global_load_lds(AS1(gb), AS3(&Bs[(size_t)(i * 4 + w) * 512]), 16, 0, 0);
        }
        __syncthreads();
        #pragma unroll
        for (int kq = 0; kq < 8; kq += 4) {
            bf16x8 af[3], bfr[4];
            #pragma unroll
            for (int m = 0; m < 3; m++) {
                int R = wm * DH + m * 16 + fr;
                int unit = R * 8 + ((kq + kg) ^ (R & 7));
                af[m] = *(const bf16x8*)&As[unit * 8];
            }
            #pragma unroll
            for (int n = 0; n < 4; n++) {
                int R = wn * 64 + n * 16 + fr;
                int unit = R * 8 + ((kq + kg) ^ (R & 7));
                bfr[n] = *(const bf16x8*)&Bs[unit * 8];
            }
            #pragma unroll
            for (int m = 0; m < 3; m++)
                #pragma unroll
                for (int n = 0; n < 4; n++)
                    acc[m][n] = __builtin_amdgcn_mfma_f32_16x16x32_bf16(af[m], bfr[n], acc[m][n], 0, 0, 0);
        }
        __syncthreads();
    }

    #pragma unroll
    for (int m = 0; m < 3; m++) {
        int row = wm * DH + m * 16 + kg * 4;
        #pragma unroll
        for (int n = 0; n < 4; n++) {
            int col = n0 + wn * 64 + n * 16 + fr;
            #pragma unroll
            for (int r = 0; r < 4; r++) {
                int rr = row + r;
                float* dst = (rr < DH)
                    ? (out + (size_t)b * X_B + (h * DH + rr) * HWP + col)
                    : (out + OUT_HALF + (size_t)b * X_B + (h * DH + rr - DH) * HWP + col);
                *dst = acc[m][n][r];
            }
        }
    }
}

// ============================================================
extern "C" void kernel_launch(void* const* d_in, const int* in_sizes, int n_in,
                              void* d_out, int out_size, void* d_ws, size_t ws_size,
                              hipStream_t stream)
{
    const float* x  = (const float*)d_in[0];
    const float* y  = (const float*)d_in[1];
    const float* wq = (const float*)d_in[2];
    const float* wd = (const float*)d_in[3];
    const float* tp = (const float*)d_in[4];
    float* out = (float*)d_out;
    float* ws = (float*)d_ws;

    // ---- workspace layout (float units), same region plan as round 9 ----
    const size_t QKF = 6291456;                  // 25.2 MB regions
    ushort* qhx = (ushort*)(ws);                 // region A
    ushort* qlx = (ushort*)(ws + QKF);
    float*  vx  = ws + 2 * QKF;
    ushort* qhy = (ushort*)(ws + 3 * QKF);       // region B
    ushort* qly = (ushort*)(ws + 4 * QKF);
    float*  vy  = ws + 5 * QKF;
    float*  t1r = ws + 6 * QKF;                  // region C: 75.5 MB
    unsigned* t1p = (unsigned*)t1r;              // [8][576][4096] packed uints
    float*  invx = ws + 6 * QKF + 18874368;
    float*  invy = invx + 3072;
    // aliases over region B (dead until dw-y writes it):
    ushort* XT  = qhy;                           // now [8][4096][192] ushort (12.6 MB)
    ushort* Wc  = qly;                           // 245,760 ushort
    // aliases over region C (dead after dw-y):
    ushort* VTx  = (ushort*)t1r;
    ushort* VTy  = (ushort*)(t1r + QKF);
    float*  spart = t1r + 2 * QKF;
    ushort* Mpp  = (ushort*)(t1r + 2 * QKF + 2359296);

    wconvert_kernel<<<240, 256, 0, stream>>>(wq, Wc);

    // tensor x: convert (single bf16) -> conv (8 batches) -> dw (8 batches)
    convert_single_kernel<<<dim3(64, 3, BB), 256, 0, stream>>>(x, XT);
    conv1x1_mfma<<<1280, 256, 0, stream>>>(XT, Wc, t1p);
    dw3x3_kernel<<<BB * C3, 256, 0, stream>>>(t1p, wd, qhx, qlx, vx, invx);

    // tensor y
    convert_single_kernel<<<dim3(64, 3, BB), 256, 0, stream>>>(y, XT);
    conv1x1_mfma<<<1280, 256, 0, stream>>>(XT, Wc, t1p);
    dw3x3_kernel<<<BB * C3, 256, 0, stream>>>(t1p, wd, qhy, qly, vy, invy);

    // transpose v to hi/lo VT format into dead t1 region
    convert_kernel<<<dim3(64, 3, BB), 256, 0, stream>>>(vx, VTx);
    convert_kernel<<<dim3(64, 3, BB), 256, 0, stream>>>(vy, VTy);

    gram_mfma<<<dim3(8, 32), 256, 0, stream>>>(qhx, qlx, qhy, qly, spart);
    softmax_kernel<<<32, 256, 0, stream>>>(spart, invx, invy, tp, Mpp);
    outmm_mfma<<<dim3(HWP / 128, 32), 256, 0, stream>>>(VTx, VTy, Mpp, out);
}

// Round 11
// 195.665 us; speedup vs baseline: 1.6121x; 1.1883x over previous
//
#include <hip/hip_runtime.h>

// ---- problem constants ----
#define CC   192                 // C
#define C3   576                 // 3C
#define HH   64
#define WW   64
#define HWP  4096                // H*W
#define BB   8
#define DH   48                  // C/HEADS
#define QKV_B (C3*HWP)           // elements per batch of conv-out tensor
#define X_B   (CC*HWP)
#define OUT_HALF ((size_t)BB*X_B)

typedef short bf16x8 __attribute__((ext_vector_type(8)));
typedef float f32x4  __attribute__((ext_vector_type(4)));

#define AS1(p) ((__attribute__((address_space(1))) void*)(p))
#define AS3(p) ((__attribute__((address_space(3))) void*)(p))

__device__ __forceinline__ ushort f2bf(float v) {
    union { float f; unsigned u; } a; a.f = v;
    unsigned r = a.u + 0x7FFF + ((a.u >> 16) & 1);   // RNE
    return (ushort)(r >> 16);
}
__device__ __forceinline__ float bf2f(ushort h) {
    union { float f; unsigned u; } a; a.u = ((unsigned)h) << 16; return a.f;
}

// ============================================================
// in (b,192,4096) fp32 -> out (b,4096,384) bf16 hi|lo (for v transpose only)
// ============================================================
__global__ __launch_bounds__(256) void convert_kernel(const float* __restrict__ in,
    ushort* __restrict__ xt)
{
    __shared__ float L[64][65];
    const int n0 = blockIdx.x * 64, c0 = blockIdx.y * 64, b = blockIdx.z;
    const int t = threadIdx.x;
    const float* ip = in + (size_t)b * X_B;
    #pragma unroll
    for (int i = 0; i < 16; i++) {
        int e = t + 256 * i;
        int r = e >> 6, col = e & 63;
        L[r][col] = ip[(size_t)(c0 + r) * HWP + n0 + col];
    }
    __syncthreads();
    #pragma unroll
    for (int i = 0; i < 4; i++) {
        int e = t + 256 * i;
        int n = e >> 4, c4 = e & 15;
        ushort hi[4], lo[4];
        #pragma unroll
        for (int j = 0; j < 4; j++) {
            float v = L[c4 * 4 + j][n];
            hi[j] = f2bf(v);
            lo[j] = f2bf(v - bf2f(hi[j]));
        }
        size_t base = ((size_t)(b * HWP + n0 + n)) * 384 + c0 + c4 * 4;
        *(ushort4*)&xt[base]       = make_ushort4(hi[0], hi[1], hi[2], hi[3]);
        *(ushort4*)&xt[base + 192] = make_ushort4(lo[0], lo[1], lo[2], lo[3]);
    }
}

// ============================================================
// in (b,192,4096) fp32 -> out (b,4096,192) bf16 SINGLE (conv input X)
// ============================================================
__global__ __launch_bounds__(256) void convert_single_kernel(const float* __restrict__ in,
    ushort* __restrict__ xt)
{
    __shared__ float L[64][65];
    const int n0 = blockIdx.x * 64, c0 = blockIdx.y * 64, b = blockIdx.z;
    const int t = threadIdx.x;
    const float* ip = in + (size_t)b * X_B;
    #pragma unroll
    for (int i = 0; i < 16; i++) {
        int e = t + 256 * i;
        int r = e >> 6, col = e & 63;
        L[r][col] = ip[(size_t)(c0 + r) * HWP + n0 + col];
    }
    __syncthreads();
    #pragma unroll
    for (int i = 0; i < 4; i++) {
        int e = t + 256 * i;
        int n = e >> 4, c4 = e & 15;
        ushort hi[4];
        #pragma unroll
        for (int j = 0; j < 4; j++)
            hi[j] = f2bf(L[c4 * 4 + j][n]);
        size_t base = ((size_t)(b * HWP + n0 + n)) * 192 + c0 + c4 * 4;
        *(ushort4*)&xt[base] = make_ushort4(hi[0], hi[1], hi[2], hi[3]);
    }
}

// ============================================================
// w_qkv -> Wc(640,192) bf16 SINGLE, zero-padded rows 576..639
// ============================================================
__global__ __launch_bounds__(256) void wconvert_kernel(const float* __restrict__ wq,
    ushort* __restrict__ wc)
{
    int e = (blockIdx.x * 256 + threadIdx.x) * 4;    // 640*192 total
    int oc = e / 192, k = e % 192;
    ushort o[4] = {0, 0, 0, 0};
    if (oc < C3) {
        #pragma unroll
        for (int j = 0; j < 4; j++)
            o[j] = f2bf(wq[oc * CC + k + j]);
    }
    *(ushort4*)&wc[e] = make_ushort4(o[0], o[1], o[2], o[3]);
}

// ============================================================
// conv1x1 via MFMA: t1 = W * X, both single bf16. 6 chunks BK=32,
// double-buffered (32 KB LDS -> 5 blocks/CU). Grid 1280 = 8 XCD x 32 nt x
// 5 mi, batch == XCD (L2 locality). Paired-row swizzle (0 bank conflicts).
// Packed (lo<<16|hi) fp32-grade t1 epilogue.
// ============================================================
__global__ __launch_bounds__(256) void conv1x1_mfma(const ushort* __restrict__ XT,
    const ushort* __restrict__ Wc, unsigned* __restrict__ op)
{
    __shared__ __align__(16) ushort Wh[2][128 * 32];    // 2 x 8 KB
    __shared__ __align__(16) ushort Xs[2][128 * 32];    // 2 x 8 KB
    const int t = threadIdx.x;
    const int lane = t & 63, w = t >> 6;
    const int wm = w >> 1, wn = w & 1;
    const int fr = lane & 15, kg = lane >> 4;
    const int g = blockIdx.x;
    const int xcd = g & 7, s = g >> 3;          // s in [0,160)
    const int bg = xcd;
    const int nt = s / 5;                       // 0..31
    const int mi = s % 5;
    const int n0 = nt * 128;
    const int m0 = mi * 128;

    f32x4 acc[4][4] = {};

    auto STAGE = [&](int buf, int ck) {
        const int k0 = ck * 32;
        #pragma unroll
        for (int i = 0; i < 2; i++) {
            int u = i * 256 + w * 64 + lane;    // unit id 0..511 (16B units)
            int rp = u >> 3;
            int p = (u & 7) ^ (rp & 7);
            int r = (rp << 1) | (p >> 2);
            int c = p & 3;
            const ushort* gwh = Wc + (size_t)(m0 + r) * 192 + k0 + c * 8;
            __builtin_amdgcn_global_load_lds(AS1(gwh), AS3(&Wh[buf][(i * 256 + w * 64) * 8]), 16, 0, 0);
            const ushort* gx = XT + ((size_t)(bg * HWP + n0 + r)) * 192 + k0 + c * 8;
            __builtin_amdgcn_global_load_lds(AS1(gx), AS3(&Xs[buf][(i * 256 + w * 64) * 8]), 16, 0, 0);
        }
    };

    STAGE(0, 0);
    __syncthreads();                 // chunk 0 resident
    int cur = 0;
    for (int ck = 0; ck < 6; ck++) {
        if (ck < 5) STAGE(cur ^ 1, ck + 1);     // prefetch next chunk under compute
        bf16x8 afh[4], bfr[4];
        #pragma unroll
        for (int m = 0; m < 4; m++) {
            int R = wm * 64 + m * 16 + fr;
            int unit = (R >> 1) * 8 + ((((R & 1) << 2) | kg) ^ ((R >> 1) & 7));
            afh[m] = *(const bf16x8*)&Wh[cur][unit * 8];
        }
        #pragma unroll
        for (int n = 0; n < 4; n++) {
            int R = wn * 64 + n * 16 + fr;
            int unit = (R >> 1) * 8 + ((((R & 1) << 2) | kg) ^ ((R >> 1) & 7));
            bfr[n] = *(const bf16x8*)&Xs[cur][unit * 8];
        }
        #pragma unroll
        for (int m = 0; m < 4; m++)
            #pragma unroll
            for (int n = 0; n < 4; n++)
                acc[m][n] = __builtin_amdgcn_mfma_f32_16x16x32_bf16(afh[m], bfr[n], acc[m][n], 0, 0, 0);
        __syncthreads();             // prefetch done + WAR safe
        cur ^= 1;
    }

    unsigned* ob = op + (size_t)bg * QKV_B;
    #pragma unroll
    for (int m = 0; m < 4; m++) {
        int oc = m0 + wm * 64 + m * 16 + kg * 4;
        #pragma unroll
        for (int n = 0; n < 4; n++) {
            int col = n0 + wn * 64 + n * 16 + fr;
            #pragma unroll
            for (int r = 0; r < 4; r++) {
                if (oc + r < C3) {
                    float v = acc[m][n][r];
                    ushort hi = f2bf(v);
                    ushort lo = f2bf(v - bf2f(hi));
                    ob[(size_t)(oc + r) * HWP + col] = ((unsigned)lo << 16) | hi;
                }
            }
        }
    }
}

// ============================================================
// depthwise 3x3 reading packed-uint t1 (8 batches); q/k emitted single bf16
// + fused L2 norm; v emitted fp32
// ============================================================
__global__ __launch_bounds__(256) void dw3x3_kernel(const unsigned* __restrict__ inp,
    const float* __restrict__ wd,
    ushort* __restrict__ qh,
    float* __restrict__ vv, float* __restrict__ inv)
{
    __shared__ float P[66][72];
    const int bc = blockIdx.x;          // b*576 + ch
    const int b = bc / C3, ch = bc % C3;
    const int t = threadIdx.x;
    const unsigned* ip = inp + (size_t)bc * HWP;
    float wr[9];
    #pragma unroll
    for (int k = 0; k < 9; k++) wr[k] = wd[ch * 9 + k];
    for (int i = t; i < 66 * 72; i += 256) ((float*)P)[i] = 0.f;
    __syncthreads();
    #pragma unroll
    for (int i = 0; i < 4; i++) {
        int u = t + 256 * i;
        int y = u >> 4, cg = u & 15;
        uint4 p4 = *(const uint4*)&ip[u * 4];
        P[1 + y][4 + cg * 4 + 0] = bf2f((ushort)(p4.x & 0xFFFF)) + bf2f((ushort)(p4.x >> 16));
        P[1 + y][4 + cg * 4 + 1] = bf2f((ushort)(p4.y & 0xFFFF)) + bf2f((ushort)(p4.y >> 16));
        P[1 + y][4 + cg * 4 + 2] = bf2f((ushort)(p4.z & 0xFFFF)) + bf2f((ushort)(p4.z >> 16));
        P[1 + y][4 + cg * 4 + 3] = bf2f((ushort)(p4.w & 0xFFFF)) + bf2f((ushort)(p4.w >> 16));
    }
    __syncthreads();

    float ssum = 0.f;
    #pragma unroll
    for (int i = 0; i < 4; i++) {
        int u = t + 256 * i;
        int y0 = u >> 4;
        int x0 = (u & 15) * 4;
        float res[4] = {0.f, 0.f, 0.f, 0.f};
        #pragma unroll
        for (int dy = 0; dy < 3; dy++) {
            float4 A = *(float4*)&P[y0 + dy][x0];
            float4 Bv = *(float4*)&P[y0 + dy][x0 + 4];
            float4 Cv = *(float4*)&P[y0 + dy][x0 + 8];
            float c0 = A.w, c1 = Bv.x, c2 = Bv.y, c3 = Bv.z, c4 = Bv.w, c5 = Cv.x;
            float w0 = wr[dy*3], w1 = wr[dy*3+1], w2 = wr[dy*3+2];
            res[0] += w0*c0 + w1*c1 + w2*c2;
            res[1] += w0*c1 + w1*c2 + w2*c3;
            res[2] += w0*c2 + w1*c3 + w2*c4;
            res[3] += w0*c3 + w1*c4 + w2*c5;
        }
        #pragma unroll
        for (int k = 0; k < 4; k++) ssum += res[k] * res[k];
        if (ch < 384) {
            size_t base = ((size_t)b * 384 + ch) * HWP + u * 4;
            *(ushort4*)&qh[base] = make_ushort4(f2bf(res[0]), f2bf(res[1]),
                                                f2bf(res[2]), f2bf(res[3]));
        } else {
            *(float4*)&vv[((size_t)b * CC + (ch - 384)) * HWP + u * 4] =
                make_float4(res[0], res[1], res[2], res[3]);
        }
    }
    if (ch < 384) {
        #pragma unroll
        for (int off = 32; off > 0; off >>= 1) ssum += __shfl_down(ssum, off);
        __shared__ float red[4];
        if ((t & 63) == 0) red[t >> 6] = ssum;
        __syncthreads();
        if (t == 0) {
            float tot = red[0] + red[1] + red[2] + red[3];
            inv[b * 384 + ch] = 1.f / fmaxf(sqrtf(tot), 1e-12f);
        }
    }
}

// ============================================================
// stacked Gram via MFMA, SINGLE-term bf16 (error sigma ~2.5e-5, negligible):
// G(96x96) = [qx;qy]*[kx;ky]^T per (b,h), split-K over n (8 chunks x 512)
// ============================================================
__global__ __launch_bounds__(256) void gram_mfma(const ushort* __restrict__ qhx,
    const ushort* __restrict__ qhy, float* __restrict__ spart)
{
    __shared__ __align__(16) ushort As[96 * 64];
    __shared__ __align__(16) ushort Bs[96 * 64];
    const int chunk = blockIdx.x, bh = blockIdx.y;
    const int b = bh >> 2, h = bh & 3;
    const int t = threadIdx.x;
    const int lane = t & 63, w = t >> 6;
    const int wm = w >> 1, wn = w & 1;
    const int fr = lane & 15, kg = lane >> 4;

    const size_t qbase = ((size_t)b * 384 + h * DH) * HWP;
    const size_t kbase = ((size_t)b * 384 + 192 + h * DH) * HWP;

    f32x4 acc[3][3] = {};

    for (int ks = 0; ks < 8; ks++) {
        const int n0 = chunk * 512 + ks * 64;
        #pragma unroll
        for (int i = 0; i < 3; i++) {
            int u = i * 256 + w * 64 + lane;
            int r = u >> 3, c = u & 7;
            int cs = c ^ (r & 7);
            const ushort* ga = ((r < DH) ? (qhx + qbase + (size_t)r * HWP)
                                         : (qhy + qbase + (size_t)(r - DH) * HWP))
                               + n0 + cs * 8;
            __builtin_amdgcn_global_load_lds(AS1(ga), AS3(&As[(size_t)(i * 4 + w) * 512]), 16, 0, 0);
            const ushort* gb = ((r < DH) ? (qhx + kbase + (size_t)r * HWP)
                                         : (qhy + kbase + (size_t)(r - DH) * HWP))
                               + n0 + cs * 8;
            __builtin_amdgcn_global_load_lds(AS1(gb), AS3(&Bs[(size_t)(i * 4 + w) * 512]), 16, 0, 0);
        }
        __syncthreads();
        #pragma unroll
        for (int kq = 0; kq < 8; kq += 4) {
            bf16x8 af[3], bfr[3];
            #pragma unroll
            for (int m = 0; m < 3; m++) {
                int R = wm * DH + m * 16 + fr;
                int unit = R * 8 + ((kq + kg) ^ (R & 7));
                af[m] = *(const bf16x8*)&As[unit * 8];
            }
            #pragma unroll
            for (int n = 0; n < 3; n++) {
                int R = wn * DH + n * 16 + fr;
                int unit = R * 8 + ((kq + kg) ^ (R & 7));
                bfr[n] = *(const bf16x8*)&Bs[unit * 8];
            }
            #pragma unroll
            for (int m = 0; m < 3; m++)
                #pragma unroll
                for (int n = 0; n < 3; n++)
                    acc[m][n] = __builtin_amdgcn_mfma_f32_16x16x32_bf16(af[m], bfr[n], acc[m][n], 0, 0, 0);
        }
        __syncthreads();
    }

    float* sp = spart + ((size_t)chunk * 32 + bh) * 9216;
    #pragma unroll
    for (int m = 0; m < 3; m++) {
        int row = wm * DH + m * 16 + kg * 4;
        #pragma unroll
        for (int n = 0; n < 3; n++) {
            int col = wn * DH + n * 16 + fr;
            #pragma unroll
            for (int r = 0; r < 4; r++)
                sp[(row + r) * 96 + col] = acc[m][n][r];
        }
    }
}

// ============================================================
// combine split-K partials, scale, softmax; emit SINGLE-bf16 coefficient
// matrix M'(96 x 128): two BK=64 chunks [Mx|My], cols 48..63 of each zeroed.
// (M single is safe: coef ~0.02, bf16 err x V random-walks to sigma ~7e-5.)
// ============================================================
__global__ __launch_bounds__(256) void softmax_kernel(const float* __restrict__ spart,
    const float* __restrict__ invx, const float* __restrict__ invy,
    const float* __restrict__ temp, ushort* __restrict__ mpp)
{
    __shared__ float G[96][97];
    const int bh = blockIdx.x, b = bh >> 2, h = bh & 3;
    const int t = threadIdx.x;
    const float ts = temp[h];
    for (int i = 0; i < 36; i++) {
        int f = t + 256 * i;
        float s = 0.f;
        #pragma unroll
        for (int cch = 0; cch < 8; cch++)
            s += spart[((size_t)cch * 32 + bh) * 9216 + f];
        int r = f / 96, c = f % 96;
        float iq = (r < DH) ? invx[b*384 + h*DH + r] : invy[b*384 + h*DH + (r-DH)];
        float ik = (c < DH) ? invx[b*384 + CC + h*DH + c] : invy[b*384 + CC + h*DH + (c-DH)];
        G[r][c] = s * iq * ik * ts;
    }
    __syncthreads();
    if (t < 192) {
        int r = t >> 1, hf = t & 1;
        float* rowp = &G[r][hf * DH];
        float m = rowp[0];
        for (int i = 1; i < DH; i++) m = fmaxf(m, rowp[i]);
        float s = 0.f;
        for (int i = 0; i < DH; i++) { float e = __expf(rowp[i] - m); rowp[i] = e; s += e; }
        float inv = 1.f / s;
        for (int i = 0; i < DH; i++) rowp[i] *= inv;
    }
    __syncthreads();
    ushort* mo = mpp + (size_t)bh * 96 * 128;
    for (int i = 0; i < 12; i++) {
        int f = t + 256 * i;                 // 96 rows x 32 pad cols
        int r = f / 32, p = f % 32;
        int ch = p >> 4, j = p & 15;
        mo[(size_t)r * 128 + ch * 64 + 48 + j] = 0;
    }
    for (int i = 0; i < 36; i++) {
        int f = t + 256 * i;
        int r = f / 96, c = f % 96;
        float v;
        if (c < DH) v = (r < DH) ? G[DH + r][c] : G[r - DH][c];
        else        v = G[r][c];
        ushort hi = f2bf(v);
        if (c < DH) mo[(size_t)r * 128 + c] = hi;
        else        mo[(size_t)r * 128 + 64 + (c - DH)] = hi;
    }
}

// ============================================================
// output GEMM via MFMA: Out(96x4096) = M'(96x128) * [Vhx;Vhy;Vlx;Vly]
// 4 chunks: A = [Mx|My|Mx|My], B = V hi then lo (V keeps hi/lo — payload).
// ============================================================
__global__ __launch_bounds__(256) void outmm_mfma(const ushort* __restrict__ VTx,
    const ushort* __restrict__ VTy, const ushort* __restrict__ mpp,
    float* __restrict__ out)
{
    __shared__ __align__(16) ushort As[96 * 64];
    __shared__ __align__(16) ushort Bs[128 * 64];
    const int t = threadIdx.x;
    const int lane = t & 63, w = t >> 6;
    const int wm = w >> 1, wn = w & 1;
    const int fr = lane & 15, kg = lane >> 4;
    const int nc = blockIdx.x, bh = blockIdx.y;
    const int b = bh >> 2, h = bh & 3;
    const int n0 = nc * 128;
    const ushort* mp = mpp + (size_t)bh * 96 * 128;

    f32x4 acc[3][4] = {};

    for (int kc = 0; kc < 4; kc++) {
        const ushort* Vsrc = (kc & 1) ? VTy : VTx;
        const int coff = ((kc < 2) ? 0 : 192) + h * DH;
        const int aoff = (kc & 1) * 64;
        #pragma unroll
        for (int i = 0; i < 3; i++) {
            int u = i * 256 + w * 64 + lane;
            int r = u >> 3, c = u & 7;
            int cs = c ^ (r & 7);
            const ushort* ga = mp + (size_t)r * 128 + aoff + cs * 8;
            __builtin_amdgcn_global_load_lds(AS1(ga), AS3(&As[(size_t)(i * 4 + w) * 512]), 16, 0, 0);
        }
        #pragma unroll
        for (int i = 0; i < 4; i++) {
            int u = i * 256 + w * 64 + lane;
            int r = u >> 3, c = u & 7;
            int cs = c ^ (r & 7);
            const ushort* gb = Vsrc + ((size_t)(b * HWP + n0 + r)) * 384 + coff + cs * 8;
            __builtin_amdgcn_global_load_lds(AS1(gb), AS3(&Bs[(size_t)(i * 4 + w) * 512]), 16, 0, 0);
        }
        __syncthreads();
        #pragma unroll
        for (int kq = 0; kq < 8; kq += 4) {
            bf16x8 af[3], bfr[4];
            #pragma unroll
            for (int m = 0; m < 3; m++) {
                int R = wm * DH + m * 16 + fr;
                int unit = R * 8 + ((kq + kg) ^ (R & 7));
                af[m] = *(const bf16x8*)&As[unit * 8];
            }
            #pragma unroll
            for (int n = 0; n < 4; n++) {
                int R = wn * 64 + n * 16 + fr;
                int unit = R * 8 + ((kq + kg) ^ (R & 7));
                bfr[n] = *(const bf16x8*)&Bs[unit * 8];
            }
            #pragma unroll
            for (int m = 0; m < 3; m++)
                #pragma unroll
                for (int n = 0; n < 4; n++)
                    acc[m][n] = __builtin_amdgcn_mfma_f32_16x16x32_bf16(af[m], bfr[n], acc[m][n], 0, 0, 0);
        }
        __syncthreads();
    }

    #pragma unroll
    for (int m = 0; m < 3; m++) {
        int row = wm * DH + m * 16 + kg * 4;
        #pragma unroll
        for (int n = 0; n < 4; n++) {
            int col = n0 + wn * 64 + n * 16 + fr;
            #pragma unroll
            for (int r = 0; r < 4; r++) {
                int rr = row + r;
                float* dst = (rr < DH)
                    ? (out + (size_t)b * X_B + (h * DH + rr) * HWP + col)
                    : (out + OUT_HALF + (size_t)b * X_B + (h * DH + rr - DH) * HWP + col);
                *dst = acc[m][n][r];
            }
        }
    }
}

// ============================================================
extern "C" void kernel_launch(void* const* d_in, const int* in_sizes, int n_in,
                              void* d_out, int out_size, void* d_ws, size_t ws_size,
                              hipStream_t stream)
{
    const float* x  = (const float*)d_in[0];
    const float* y  = (const float*)d_in[1];
    const float* wq = (const float*)d_in[2];
    const float* wd = (const float*)d_in[3];
    const float* tp = (const float*)d_in[4];
    float* out = (float*)d_out;
    float* ws = (float*)d_ws;

    // ---- workspace layout (float units), total ~189 MB of 256 MB ----
    const size_t QKF = 6291456;                  // 25.2 MB per region
    ushort* qhx = (ushort*)(ws);                 // [8][384][4096] bf16 single
    float*  vx  = ws + QKF;                      // [8][192][4096] fp32
    ushort* qhy = (ushort*)(ws + 2 * QKF);
    float*  vy  = ws + 3 * QKF;
    float*  t1r = ws + 4 * QKF;                  // 18,874,368 floats (75.5 MB)
    unsigned* t1p = (unsigned*)t1r;              // [8][576][4096] packed uints
    ushort* XT  = (ushort*)(ws + 4 * QKF + 18874368);        // [8][4096][192] bf16
    ushort* Wc  = (ushort*)(ws + 4 * QKF + 18874368 + 3145728); // [640][192] bf16
    float*  invx = ws + 4 * QKF + 18874368 + 3145728 + 61440;
    float*  invy = invx + 3072;
    // aliases over t1 region (dead after dw-y):
    ushort* VTx  = (ushort*)t1r;                 // [8][4096][384] bf16 hi/lo
    ushort* VTy  = (ushort*)(t1r + QKF);
    float*  spart = t1r + 2 * QKF;               // 2,359,296 floats
    ushort* Mpp  = (ushort*)(t1r + 2 * QKF + 2359296);   // [32][96][128] ushort

    wconvert_kernel<<<120, 256, 0, stream>>>(wq, Wc);

    // tensor x: convert (single bf16) -> conv (8 batches) -> dw (8 batches)
    convert_single_kernel<<<dim3(64, 3, BB), 256, 0, stream>>>(x, XT);
    conv1x1_mfma<<<1280, 256, 0, stream>>>(XT, Wc, t1p);
    dw3x3_kernel<<<BB * C3, 256, 0, stream>>>(t1p, wd, qhx, vx, invx);

    // tensor y
    convert_single_kernel<<<dim3(64, 3, BB), 256, 0, stream>>>(y, XT);
    conv1x1_mfma<<<1280, 256, 0, stream>>>(XT, Wc, t1p);
    dw3x3_kernel<<<BB * C3, 256, 0, stream>>>(t1p, wd, qhy, vy, invy);

    // transpose v to hi/lo VT format into dead t1 region
    convert_kernel<<<dim3(64, 3, BB), 256, 0, stream>>>(vx, VTx);
    convert_kernel<<<dim3(64, 3, BB), 256, 0, stream>>>(vy, VTy);

    gram_mfma<<<dim3(8, 32), 256, 0, stream>>>(qhx, qhy, spart);
    softmax_kernel<<<32, 256, 0, stream>>>(spart, invx, invy, tp, Mpp);
    outmm_mfma<<<dim3(HWP / 128, 32), 256, 0, stream>>>(VTx, VTy, Mpp, out);
}

// Round 12
// 161.292 us; speedup vs baseline: 1.9557x; 1.2131x over previous
//
#include <hip/hip_runtime.h>

// ---- problem constants ----
#define CC   192                 // C
#define C3   576                 // 3C
#define HH   64
#define WW   64
#define HWP  4096                // H*W
#define BB   8
#define DH   48                  // C/HEADS
#define QKV_B (C3*HWP)           // elements per batch of conv-out tensor
#define X_B   (CC*HWP)
#define OUT_HALF ((size_t)BB*X_B)

typedef short bf16x8 __attribute__((ext_vector_type(8)));
typedef float f32x4  __attribute__((ext_vector_type(4)));

#define AS1(p) ((__attribute__((address_space(1))) void*)(p))
#define AS3(p) ((__attribute__((address_space(3))) void*)(p))

__device__ __forceinline__ ushort f2bf(float v) {
    union { float f; unsigned u; } a; a.f = v;
    unsigned r = a.u + 0x7FFF + ((a.u >> 16) & 1);   // RNE
    return (ushort)(r >> 16);
}
__device__ __forceinline__ float bf2f(ushort h) {
    union { float f; unsigned u; } a; a.u = ((unsigned)h) << 16; return a.f;
}

// ============================================================
// in (b,192,4096) fp32 -> out (b,4096,192) bf16 SINGLE (conv input X)
// ============================================================
__global__ __launch_bounds__(256) void convert_single_kernel(const float* __restrict__ in,
    ushort* __restrict__ xt)
{
    __shared__ float L[64][65];
    const int n0 = blockIdx.x * 64, c0 = blockIdx.y * 64, b = blockIdx.z;
    const int t = threadIdx.x;
    const float* ip = in + (size_t)b * X_B;
    #pragma unroll
    for (int i = 0; i < 16; i++) {
        int e = t + 256 * i;
        int r = e >> 6, col = e & 63;
        L[r][col] = ip[(size_t)(c0 + r) * HWP + n0 + col];
    }
    __syncthreads();
    #pragma unroll
    for (int i = 0; i < 4; i++) {
        int e = t + 256 * i;
        int n = e >> 4, c4 = e & 15;
        ushort hi[4];
        #pragma unroll
        for (int j = 0; j < 4; j++)
            hi[j] = f2bf(L[c4 * 4 + j][n]);
        size_t base = ((size_t)(b * HWP + n0 + n)) * 192 + c0 + c4 * 4;
        *(ushort4*)&xt[base] = make_ushort4(hi[0], hi[1], hi[2], hi[3]);
    }
}

// ============================================================
// v bf16 (b,192,4096) -> VT (b,4096,192) bf16 transpose
// ============================================================
__global__ __launch_bounds__(256) void vtrans_kernel(const ushort* __restrict__ in,
    ushort* __restrict__ vt)
{
    __shared__ __align__(16) ushort L[64][72];
    const int n0 = blockIdx.x * 64, c0 = blockIdx.y * 64, b = blockIdx.z;
    const int t = threadIdx.x;
    const ushort* ip = in + (size_t)b * X_B;
    #pragma unroll
    for (int i = 0; i < 2; i++) {
        int e = t + 256 * i;            // 512 units of 8 ushorts
        int r = e >> 3, u8 = e & 7;
        *(bf16x8*)&L[r][u8 * 8] = *(const bf16x8*)&ip[(size_t)(c0 + r) * HWP + n0 + u8 * 8];
    }
    __syncthreads();
    #pragma unroll
    for (int i = 0; i < 4; i++) {
        int e = t + 256 * i;            // 1024: 64 n x 16 c4
        int n = e >> 4, c4 = e & 15;
        ushort o[4];
        #pragma unroll
        for (int j = 0; j < 4; j++) o[j] = L[c4 * 4 + j][n];
        *(ushort4*)&vt[((size_t)(b * HWP + n0 + n)) * 192 + c0 + c4 * 4] =
            make_ushort4(o[0], o[1], o[2], o[3]);
    }
}

// ============================================================
// w_qkv -> Wc(640,192) bf16 SINGLE, zero-padded rows 576..639
// ============================================================
__global__ __launch_bounds__(256) void wconvert_kernel(const float* __restrict__ wq,
    ushort* __restrict__ wc)
{
    int e = (blockIdx.x * 256 + threadIdx.x) * 4;    // 640*192 total
    int oc = e / 192, k = e % 192;
    ushort o[4] = {0, 0, 0, 0};
    if (oc < C3) {
        #pragma unroll
        for (int j = 0; j < 4; j++)
            o[j] = f2bf(wq[oc * CC + k + j]);
    }
    *(ushort4*)&wc[e] = make_ushort4(o[0], o[1], o[2], o[3]);
}

// ============================================================
// conv1x1 via MFMA: t1 = W * X, all single bf16. 6 chunks BK=32, dbuf.
// Grid 1280 = 8 XCD x 32 nt x 5 mi, batch == XCD. Paired-row swizzle.
// Epilogue: stage 128x128 bf16 tile through the (dead) staging LDS, then
// fully-coalesced 16B row-major stores (t1 now single bf16 = 37.7 MB).
// ============================================================
__global__ __launch_bounds__(256) void conv1x1_mfma(const ushort* __restrict__ XT,
    const ushort* __restrict__ Wc, ushort* __restrict__ t1s)
{
    __shared__ __align__(16) ushort Sall[4][128 * 32];   // Wh=Sall[0..1], Xs=Sall[2..3]
    const int t = threadIdx.x;
    const int lane = t & 63, w = t >> 6;
    const int wm = w >> 1, wn = w & 1;
    const int fr = lane & 15, kg = lane >> 4;
    const int g = blockIdx.x;
    const int xcd = g & 7, s = g >> 3;          // s in [0,160)
    const int bg = xcd;
    const int nt = s / 5;                       // 0..31
    const int mi = s % 5;
    const int n0 = nt * 128;
    const int m0 = mi * 128;

    f32x4 acc[4][4] = {};

    auto STAGE = [&](int buf, int ck) {
        const int k0 = ck * 32;
        #pragma unroll
        for (int i = 0; i < 2; i++) {
            int u = i * 256 + w * 64 + lane;    // unit id 0..511 (16B units)
            int rp = u >> 3;
            int p = (u & 7) ^ (rp & 7);
            int r = (rp << 1) | (p >> 2);
            int c = p & 3;
            const ushort* gwh = Wc + (size_t)(m0 + r) * 192 + k0 + c * 8;
            __builtin_amdgcn_global_load_lds(AS1(gwh), AS3(&Sall[buf][(i * 256 + w * 64) * 8]), 16, 0, 0);
            const ushort* gx = XT + ((size_t)(bg * HWP + n0 + r)) * 192 + k0 + c * 8;
            __builtin_amdgcn_global_load_lds(AS1(gx), AS3(&Sall[2 + buf][(i * 256 + w * 64) * 8]), 16, 0, 0);
        }
    };

    STAGE(0, 0);
    __syncthreads();                 // chunk 0 resident
    int cur = 0;
    for (int ck = 0; ck < 6; ck++) {
        if (ck < 5) STAGE(cur ^ 1, ck + 1);     // prefetch next chunk under compute
        bf16x8 afh[4], bfr[4];
        #pragma unroll
        for (int m = 0; m < 4; m++) {
            int R = wm * 64 + m * 16 + fr;
            int unit = (R >> 1) * 8 + ((((R & 1) << 2) | kg) ^ ((R >> 1) & 7));
            afh[m] = *(const bf16x8*)&Sall[cur][unit * 8];
        }
        #pragma unroll
        for (int n = 0; n < 4; n++) {
            int R = wn * 64 + n * 16 + fr;
            int unit = (R >> 1) * 8 + ((((R & 1) << 2) | kg) ^ ((R >> 1) & 7));
            bfr[n] = *(const bf16x8*)&Sall[2 + cur][unit * 8];
        }
        #pragma unroll
        for (int m = 0; m < 4; m++)
            #pragma unroll
            for (int n = 0; n < 4; n++)
                acc[m][n] = __builtin_amdgcn_mfma_f32_16x16x32_bf16(afh[m], bfr[n], acc[m][n], 0, 0, 0);
        __syncthreads();             // prefetch done + WAR safe
        cur ^= 1;
    }

    // epilogue: acc -> LDS bf16 tile -> coalesced 16B stores
    ushort (*E)[128] = (ushort(*)[128])Sall;
    #pragma unroll
    for (int m = 0; m < 4; m++) {
        int rl = wm * 64 + m * 16 + kg * 4;
        #pragma unroll
        for (int n = 0; n < 4; n++) {
            int cl = wn * 64 + n * 16 + fr;
            #pragma unroll
            for (int r = 0; r < 4; r++)
                E[rl + r][cl] = f2bf(acc[m][n][r]);
        }
    }
    __syncthreads();
    ushort* ob = t1s + (size_t)bg * QKV_B;
    #pragma unroll
    for (int i = 0; i < 8; i++) {
        int u = t + 256 * i;            // 0..2047: 128 rows x 16 col-units
        int row = u >> 4, c8 = u & 15;
        int oc = m0 + row;
        if (oc < C3)
            *(bf16x8*)&ob[(size_t)oc * HWP + n0 + c8 * 8] = *(bf16x8*)&E[row][c8 * 8];
    }
}

// ============================================================
// depthwise 3x3 reading single-bf16 t1 (8 batches); q/k bf16 + fused L2
// norm; v emitted bf16 [c][n]
// ============================================================
__global__ __launch_bounds__(256) void dw3x3_kernel(const ushort* __restrict__ inp,
    const float* __restrict__ wd,
    ushort* __restrict__ qh, ushort* __restrict__ vv, float* __restrict__ inv)
{
    __shared__ float P[66][72];
    const int bc = blockIdx.x;          // b*576 + ch
    const int b = bc / C3, ch = bc % C3;
    const int t = threadIdx.x;
    const ushort* ip = inp + (size_t)bc * HWP;
    float wr[9];
    #pragma unroll
    for (int k = 0; k < 9; k++) wr[k] = wd[ch * 9 + k];
    for (int i = t; i < 66 * 72; i += 256) ((float*)P)[i] = 0.f;
    __syncthreads();
    #pragma unroll
    for (int i = 0; i < 2; i++) {
        int u = t + 256 * i;            // 512 units of 8 px
        int y = u >> 3, x0 = (u & 7) * 8;
        bf16x8 v8 = *(const bf16x8*)&ip[u * 8];
        #pragma unroll
        for (int j = 0; j < 8; j++)
            P[1 + y][4 + x0 + j] = bf2f((ushort)v8[j]);
    }
    __syncthreads();

    float ssum = 0.f;
    #pragma unroll
    for (int i = 0; i < 4; i++) {
        int u = t + 256 * i;
        int y0 = u >> 4;
        int x0 = (u & 15) * 4;
        float res[4] = {0.f, 0.f, 0.f, 0.f};
        #pragma unroll
        for (int dy = 0; dy < 3; dy++) {
            float4 A = *(float4*)&P[y0 + dy][x0];
            float4 Bv = *(float4*)&P[y0 + dy][x0 + 4];
            float4 Cv = *(float4*)&P[y0 + dy][x0 + 8];
            float c0 = A.w, c1 = Bv.x, c2 = Bv.y, c3 = Bv.z, c4 = Bv.w, c5 = Cv.x;
            float w0 = wr[dy*3], w1 = wr[dy*3+1], w2 = wr[dy*3+2];
            res[0] += w0*c0 + w1*c1 + w2*c2;
            res[1] += w0*c1 + w1*c2 + w2*c3;
            res[2] += w0*c2 + w1*c3 + w2*c4;
            res[3] += w0*c3 + w1*c4 + w2*c5;
        }
        #pragma unroll
        for (int k = 0; k < 4; k++) ssum += res[k] * res[k];
        if (ch < 384) {
            size_t base = ((size_t)b * 384 + ch) * HWP + u * 4;
            *(ushort4*)&qh[base] = make_ushort4(f2bf(res[0]), f2bf(res[1]),
                                                f2bf(res[2]), f2bf(res[3]));
        } else {
            size_t base = ((size_t)b * CC + (ch - 384)) * HWP + u * 4;
            *(ushort4*)&vv[base] = make_ushort4(f2bf(res[0]), f2bf(res[1]),
                                                f2bf(res[2]), f2bf(res[3]));
        }
    }
    if (ch < 384) {
        #pragma unroll
        for (int off = 32; off > 0; off >>= 1) ssum += __shfl_down(ssum, off);
        __shared__ float red[4];
        if ((t & 63) == 0) red[t >> 6] = ssum;
        __syncthreads();
        if (t == 0) {
            float tot = red[0] + red[1] + red[2] + red[3];
            inv[b * 384 + ch] = 1.f / fmaxf(sqrtf(tot), 1e-12f);
        }
    }
}

// ============================================================
// stacked Gram via MFMA, single bf16 (proven, unchanged)
// ============================================================
__global__ __launch_bounds__(256) void gram_mfma(const ushort* __restrict__ qhx,
    const ushort* __restrict__ qhy, float* __restrict__ spart)
{
    __shared__ __align__(16) ushort As[96 * 64];
    __shared__ __align__(16) ushort Bs[96 * 64];
    const int chunk = blockIdx.x, bh = blockIdx.y;
    const int b = bh >> 2, h = bh & 3;
    const int t = threadIdx.x;
    const int lane = t & 63, w = t >> 6;
    const int wm = w >> 1, wn = w & 1;
    const int fr = lane & 15, kg = lane >> 4;

    const size_t qbase = ((size_t)b * 384 + h * DH) * HWP;
    const size_t kbase = ((size_t)b * 384 + 192 + h * DH) * HWP;

    f32x4 acc[3][3] = {};

    for (int ks = 0; ks < 8; ks++) {
        const int n0 = chunk * 512 + ks * 64;
        #pragma unroll
        for (int i = 0; i < 3; i++) {
            int u = i * 256 + w * 64 + lane;
            int r = u >> 3, c = u & 7;
            int cs = c ^ (r & 7);
            const ushort* ga = ((r < DH) ? (qhx + qbase + (size_t)r * HWP)
                                         : (qhy + qbase + (size_t)(r - DH) * HWP))
                               + n0 + cs * 8;
            __builtin_amdgcn_global_load_lds(AS1(ga), AS3(&As[(size_t)(i * 4 + w) * 512]), 16, 0, 0);
            const ushort* gb = ((r < DH) ? (qhx + kbase + (size_t)r * HWP)
                                         : (qhy + kbase + (size_t)(r - DH) * HWP))
                               + n0 + cs * 8;
            __builtin_amdgcn_global_load_lds(AS1(gb), AS3(&Bs[(size_t)(i * 4 + w) * 512]), 16, 0, 0);
        }
        __syncthreads();
        #pragma unroll
        for (int kq = 0; kq < 8; kq += 4) {
            bf16x8 af[3], bfr[3];
            #pragma unroll
            for (int m = 0; m < 3; m++) {
                int R = wm * DH + m * 16 + fr;
                int unit = R * 8 + ((kq + kg) ^ (R & 7));
                af[m] = *(const bf16x8*)&As[unit * 8];
            }
            #pragma unroll
            for (int n = 0; n < 3; n++) {
                int R = wn * DH + n * 16 + fr;
                int unit = R * 8 + ((kq + kg) ^ (R & 7));
                bfr[n] = *(const bf16x8*)&Bs[unit * 8];
            }
            #pragma unroll
            for (int m = 0; m < 3; m++)
                #pragma unroll
                for (int n = 0; n < 3; n++)
                    acc[m][n] = __builtin_amdgcn_mfma_f32_16x16x32_bf16(af[m], bfr[n], acc[m][n], 0, 0, 0);
        }
        __syncthreads();
    }

    float* sp = spart + ((size_t)chunk * 32 + bh) * 9216;
    #pragma unroll
    for (int m = 0; m < 3; m++) {
        int row = wm * DH + m * 16 + kg * 4;
        #pragma unroll
        for (int n = 0; n < 3; n++) {
            int col = wn * DH + n * 16 + fr;
            #pragma unroll
            for (int r = 0; r < 4; r++)
                sp[(row + r) * 96 + col] = acc[m][n][r];
        }
    }
}

// ============================================================
// combine split-K partials, scale, softmax; emit single-bf16 coefficient
// matrix M'(96 x 128): two BK=64 chunks [Mx|My], cols 48..63 of each zeroed
// ============================================================
__global__ __launch_bounds__(256) void softmax_kernel(const float* __restrict__ spart,
    const float* __restrict__ invx, const float* __restrict__ invy,
    const float* __restrict__ temp, ushort* __restrict__ mpp)
{
    __shared__ float G[96][97];
    const int bh = blockIdx.x, b = bh >> 2, h = bh & 3;
    const int t = threadIdx.x;
    const float ts = temp[h];
    for (int i = 0; i < 36; i++) {
        int f = t + 256 * i;
        float s = 0.f;
        #pragma unroll
        for (int cch = 0; cch < 8; cch++)
            s += spart[((size_t)cch * 32 + bh) * 9216 + f];
        int r = f / 96, c = f % 96;
        float iq = (r < DH) ? invx[b*384 + h*DH + r] : invy[b*384 + h*DH + (r-DH)];
        float ik = (c < DH) ? invx[b*384 + CC + h*DH + c] : invy[b*384 + CC + h*DH + (c-DH)];
        G[r][c] = s * iq * ik * ts;
    }
    __syncthreads();
    if (t < 192) {
        int r = t >> 1, hf = t & 1;
        float* rowp = &G[r][hf * DH];
        float m = rowp[0];
        for (int i = 1; i < DH; i++) m = fmaxf(m, rowp[i]);
        float s = 0.f;
        for (int i = 0; i < DH; i++) { float e = __expf(rowp[i] - m); rowp[i] = e; s += e; }
        float inv = 1.f / s;
        for (int i = 0; i < DH; i++) rowp[i] *= inv;
    }
    __syncthreads();
    ushort* mo = mpp + (size_t)bh * 96 * 128;
    for (int i = 0; i < 12; i++) {
        int f = t + 256 * i;                 // 96 rows x 32 pad cols
        int r = f / 32, p = f % 32;
        int ch = p >> 4, j = p & 15;
        mo[(size_t)r * 128 + ch * 64 + 48 + j] = 0;
    }
    for (int i = 0; i < 36; i++) {
        int f = t + 256 * i;
        int r = f / 96, c = f % 96;
        float v;
        if (c < DH) v = (r < DH) ? G[DH + r][c] : G[r - DH][c];
        else        v = G[r][c];
        ushort hi = f2bf(v);
        if (c < DH) mo[(size_t)r * 128 + c] = hi;
        else        mo[(size_t)r * 128 + 64 + (c - DH)] = hi;
    }
}

// ============================================================
// output GEMM via MFMA: Out(96x4096) = M'(96x128) * [Vx;Vy], V single bf16.
// 2 chunks; B reads wrap (c8 -= 192) so the h=3 slice never reads OOB —
// wrapped K-rows 48..63 multiply the zeroed A cols (finite, annihilated).
// ============================================================
__global__ __launch_bounds__(256) void outmm_mfma(const ushort* __restrict__ VTx,
    const ushort* __restrict__ VTy, const ushort* __restrict__ mpp,
    float* __restrict__ out)
{
    __shared__ __align__(16) ushort As[96 * 64];
    __shared__ __align__(16) ushort Bs[128 * 64];
    const int t = threadIdx.x;
    const int lane = t & 63, w = t >> 6;
    const int wm = w >> 1, wn = w & 1;
    const int fr = lane & 15, kg = lane >> 4;
    const int nc = blockIdx.x, bh = blockIdx.y;
    const int b = bh >> 2, h = bh & 3;
    const int n0 = nc * 128;
    const ushort* mp = mpp + (size_t)bh * 96 * 128;

    f32x4 acc[3][4] = {};

    for (int kc = 0; kc < 2; kc++) {
        const ushort* Vsrc = kc ? VTy : VTx;
        const int coff = h * DH;
        const int aoff = kc * 64;
        #pragma unroll
        for (int i = 0; i < 3; i++) {
            int u = i * 256 + w * 64 + lane;
            int r = u >> 3, c = u & 7;
            int cs = c ^ (r & 7);
            const ushort* ga = mp + (size_t)r * 128 + aoff + cs * 8;
            __builtin_amdgcn_global_load_lds(AS1(ga), AS3(&As[(size_t)(i * 4 + w) * 512]), 16, 0, 0);
        }
        #pragma unroll
        for (int i = 0; i < 4; i++) {
            int u = i * 256 + w * 64 + lane;
            int r = u >> 3, c = u & 7;
            int cs = c ^ (r & 7);
            int c8 = coff + cs * 8;
            if (c8 >= 192) c8 -= 192;       // wrap: lands on zero-A K-rows
            const ushort* gb = Vsrc + ((size_t)(b * HWP + n0 + r)) * 192 + c8;
            __builtin_amdgcn_global_load_lds(AS1(gb), AS3(&Bs[(size_t)(i * 4 + w) * 512]), 16, 0, 0);
        }
        __syncthreads();
        #pragma unroll
        for (int kq = 0; kq < 8; kq += 4) {
            bf16x8 af[3], bfr[4];
            #pragma unroll
            for (int m = 0; m < 3; m++) {
                int R = wm * DH + m * 16 + fr;
                int unit = R * 8 + ((kq + kg) ^ (R & 7));
                af[m] = *(const bf16x8*)&As[unit * 8];
            }
            #pragma unroll
            for (int n = 0; n < 4; n++) {
                int R = wn * 64 + n * 16 + fr;
                int unit = R * 8 + ((kq + kg) ^ (R & 7));
                bfr[n] = *(const bf16x8*)&Bs[unit * 8];
            }
            #pragma unroll
            for (int m = 0; m < 3; m++)
                #pragma unroll
                for (int n = 0; n < 4; n++)
                    acc[m][n] = __builtin_amdgcn_mfma_f32_16x16x32_bf16(af[m], bfr[n], acc[m][n], 0, 0, 0);
        }
        __syncthreads();
    }

    #pragma unroll
    for (int m = 0; m < 3; m++) {
        int row = wm * DH + m * 16 + kg * 4;
        #pragma unroll
        for (int n = 0; n < 4; n++) {
            int col = n0 + wn * 64 + n * 16 + fr;
            #pragma unroll
            for (int r = 0; r < 4; r++) {
                int rr = row + r;
                float* dst = (rr < DH)
                    ? (out + (size_t)b * X_B + (h * DH + rr) * HWP + col)
                    : (out + OUT_HALF + (size_t)b * X_B + (h * DH + rr - DH) * HWP + col);
                *dst = acc[m][n][r];
            }
        }
    }
}

// ============================================================
extern "C" void kernel_launch(void* const* d_in, const int* in_sizes, int n_in,
                              void* d_out, int out_size, void* d_ws, size_t ws_size,
                              hipStream_t stream)
{
    const float* x  = (const float*)d_in[0];
    const float* y  = (const float*)d_in[1];
    const float* wq = (const float*)d_in[2];
    const float* wd = (const float*)d_in[3];
    const float* tp = (const float*)d_in[4];
    float* out = (float*)d_out;
    float* ws = (float*)d_ws;

    // ---- workspace layout (float units), total ~126 MB ----
    const size_t QKF = 6291456;   // q/k bf16 [8][384][4096] in float units
    const size_t VBF = 3145728;   // v/XT bf16 [8][192][4096] in float units
    const size_t T1F = 9437184;   // t1 bf16 [8][576][4096] in float units / alias region

    ushort* qhx = (ushort*)(ws);
    ushort* vxs = (ushort*)(ws + QKF);
    ushort* qhy = (ushort*)(ws + QKF + VBF);
    ushort* vys = (ushort*)(ws + 2 * QKF + VBF);
    float*  t1base = ws + 2 * QKF + 2 * VBF;
    ushort* t1s = (ushort*)t1base;               // [8][576][4096] bf16
    ushort* XT  = (ushort*)(t1base + T1F);       // [8][4096][192] bf16
    ushort* Wc  = (ushort*)(t1base + T1F + VBF); // [640][192] bf16
    float*  invx = t1base + T1F + VBF + 61440;
    float*  invy = invx + 3072;
    // aliases over t1s region (dead after dw-y):
    ushort* VTx  = t1s;                                  // VBF floats
    ushort* VTy  = (ushort*)(t1base + VBF);
    float*  spart = t1base + 2 * VBF;                    // 2,359,296 floats
    ushort* Mpp  = (ushort*)(t1base + 2 * VBF + 2359296);

    wconvert_kernel<<<120, 256, 0, stream>>>(wq, Wc);

    // tensor x: convert -> conv -> dw
    convert_single_kernel<<<dim3(64, 3, BB), 256, 0, stream>>>(x, XT);
    conv1x1_mfma<<<1280, 256, 0, stream>>>(XT, Wc, t1s);
    dw3x3_kernel<<<BB * C3, 256, 0, stream>>>(t1s, wd, qhx, vxs, invx);

    // tensor y
    convert_single_kernel<<<dim3(64, 3, BB), 256, 0, stream>>>(y, XT);
    conv1x1_mfma<<<1280, 256, 0, stream>>>(XT, Wc, t1s);
    dw3x3_kernel<<<BB * C3, 256, 0, stream>>>(t1s, wd, qhy, vys, invy);

    // transpose v (bf16) into dead t1 region
    vtrans_kernel<<<dim3(64, 3, BB), 256, 0, stream>>>(vxs, VTx);
    vtrans_kernel<<<dim3(64, 3, BB), 256, 0, stream>>>(vys, VTy);

    gram_mfma<<<dim3(8, 32), 256, 0, stream>>>(qhx, qhy, spart);
    softmax_kernel<<<32, 256, 0, stream>>>(spart, invx, invy, tp, Mpp);
    outmm_mfma<<<dim3(HWP / 128, 32), 256, 0, stream>>>(VTx, VTy, Mpp, out);
}

// Round 13
// 158.420 us; speedup vs baseline: 1.9912x; 1.0181x over previous
//
#include <hip/hip_runtime.h>

// ---- problem constants ----
#define CC   192                 // C
#define C3   576                 // 3C
#define HH   64
#define WW   64
#define HWP  4096                // H*W
#define BB   8
#define DH   48                  // C/HEADS
#define QKV_B (C3*HWP)           // elements per batch of conv-out tensor
#define X_B   (CC*HWP)
#define OUT_HALF ((size_t)BB*X_B)

typedef short bf16x8 __attribute__((ext_vector_type(8)));
typedef float f32x4  __attribute__((ext_vector_type(4)));

#define AS1(p) ((__attribute__((address_space(1))) void*)(p))
#define AS3(p) ((__attribute__((address_space(3))) void*)(p))

__device__ __forceinline__ ushort f2bf(float v) {
    union { float f; unsigned u; } a; a.f = v;
    unsigned r = a.u + 0x7FFF + ((a.u >> 16) & 1);   // RNE
    return (ushort)(r >> 16);
}
__device__ __forceinline__ float bf2f(ushort h) {
    union { float f; unsigned u; } a; a.u = ((unsigned)h) << 16; return a.f;
}

// ============================================================
// {x,y} (b,192,4096) fp32 -> XT (tsr,b,4096,192) bf16 single. z in [0,16).
// ============================================================
__global__ __launch_bounds__(256) void convert_single_kernel(const float* __restrict__ x,
    const float* __restrict__ y, ushort* __restrict__ xt)
{
    __shared__ float L[64][65];
    const int n0 = blockIdx.x * 64, c0 = blockIdx.y * 64, z = blockIdx.z;
    const int t = threadIdx.x;
    const float* ip = ((z < 8) ? x : y) + (size_t)(z & 7) * X_B;
    #pragma unroll
    for (int i = 0; i < 16; i++) {
        int e = t + 256 * i;
        int r = e >> 6, col = e & 63;
        L[r][col] = ip[(size_t)(c0 + r) * HWP + n0 + col];
    }
    __syncthreads();
    #pragma unroll
    for (int i = 0; i < 4; i++) {
        int e = t + 256 * i;
        int n = e >> 4, c4 = e & 15;
        ushort hi[4];
        #pragma unroll
        for (int j = 0; j < 4; j++)
            hi[j] = f2bf(L[c4 * 4 + j][n]);
        size_t base = ((size_t)z * HWP + n0 + n) * 192 + c0 + c4 * 4;
        *(ushort4*)&xt[base] = make_ushort4(hi[0], hi[1], hi[2], hi[3]);
    }
}

// ============================================================
// v bf16 (16 batch-slices,192,4096) -> VT (...,4096,192) transpose. z in [0,16).
// ============================================================
__global__ __launch_bounds__(256) void vtrans_kernel(const ushort* __restrict__ in,
    ushort* __restrict__ vt)
{
    __shared__ __align__(16) ushort L[64][72];
    const int n0 = blockIdx.x * 64, c0 = blockIdx.y * 64, z = blockIdx.z;
    const int t = threadIdx.x;
    const ushort* ip = in + (size_t)z * X_B;
    #pragma unroll
    for (int i = 0; i < 2; i++) {
        int e = t + 256 * i;            // 512 units of 8 ushorts
        int r = e >> 3, u8 = e & 7;
        *(bf16x8*)&L[r][u8 * 8] = *(const bf16x8*)&ip[(size_t)(c0 + r) * HWP + n0 + u8 * 8];
    }
    __syncthreads();
    #pragma unroll
    for (int i = 0; i < 4; i++) {
        int e = t + 256 * i;            // 1024: 64 n x 16 c4
        int n = e >> 4, c4 = e & 15;
        ushort o[4];
        #pragma unroll
        for (int j = 0; j < 4; j++) o[j] = L[c4 * 4 + j][n];
        *(ushort4*)&vt[((size_t)z * HWP + n0 + n) * 192 + c0 + c4 * 4] =
            make_ushort4(o[0], o[1], o[2], o[3]);
    }
}

// ============================================================
// w_qkv -> Wc(640,192) bf16 SINGLE, zero-padded rows 576..639
// ============================================================
__global__ __launch_bounds__(256) void wconvert_kernel(const float* __restrict__ wq,
    ushort* __restrict__ wc)
{
    int e = (blockIdx.x * 256 + threadIdx.x) * 4;    // 640*192 total
    int oc = e / 192, k = e % 192;
    ushort o[4] = {0, 0, 0, 0};
    if (oc < C3) {
        #pragma unroll
        for (int j = 0; j < 4; j++)
            o[j] = f2bf(wq[oc * CC + k + j]);
    }
    *(ushort4*)&wc[e] = make_ushort4(o[0], o[1], o[2], o[3]);
}

// ============================================================
// conv1x1 via MFMA: t1 = W * X, single bf16. Tile 128m x 256n, 512 thr
// (8 waves 2x4, per-wave 64x64, acc[4][4] — proven fragment math).
// BK=32, 6 chunks, dbuf (48 KB -> 3 blocks/CU). Grid 1280 =
// 8 xcd(==batch) x {2 tsr x 16 nt x 5 mi}. Paired-row swizzle (2-way free).
// Epilogue: two 128x128 bf16 half-tiles staged via dead X LDS, 16B stores.
// ============================================================
__global__ __launch_bounds__(512) void conv1x1_mfma(const ushort* __restrict__ XT,
    const ushort* __restrict__ Wc, ushort* __restrict__ t1s)
{
    __shared__ __align__(16) ushort Wsb[2][128 * 32];   // 2 x 8 KB
    __shared__ __align__(16) ushort Xsb[2][256 * 32];   // 2 x 16 KB
    const int t = threadIdx.x;
    const int lane = t & 63, w = t >> 6;
    const int wm = w >> 2, wn = w & 3;
    const int fr = lane & 15, kg = lane >> 4;
    const int g = blockIdx.x;
    const int xcd = g & 7, s = g >> 3;          // s in [0,160)
    const int bg = xcd;
    const int tsr = s / 80;
    const int rem = s - tsr * 80;
    const int nt = rem / 5;                     // 0..15
    const int mi = rem % 5;
    const int n0 = nt * 256;
    const int m0 = mi * 128;
    const ushort* XTp = XT + (size_t)(tsr * 8 + bg) * (HWP * 192);

    f32x4 acc[4][4] = {};

    auto STAGE = [&](int buf, int ck) {
        const int k0 = ck * 32;
        {   // W: 512 units (1/thread), 128 rows x 4 units
            int u = t;
            int rp = u >> 3;
            int p = (u & 7) ^ (rp & 7);
            int r = (rp << 1) | (p >> 2);
            int c = p & 3;
            const ushort* gw = Wc + (size_t)(m0 + r) * 192 + k0 + c * 8;
            __builtin_amdgcn_global_load_lds(AS1(gw), AS3(&Wsb[buf][(size_t)t * 8]), 16, 0, 0);
        }
        #pragma unroll
        for (int i = 0; i < 2; i++) {   // X: 1024 units (2/thread), 256 rows x 4 units
            int u = i * 512 + t;
            int rp = u >> 3;
            int p = (u & 7) ^ (rp & 7);
            int r = (rp << 1) | (p >> 2);
            int c = p & 3;
            const ushort* gx = XTp + (size_t)(n0 + r) * 192 + k0 + c * 8;
            __builtin_amdgcn_global_load_lds(AS1(gx), AS3(&Xsb[buf][(size_t)(i * 512 + t) * 8]), 16, 0, 0);
        }
    };

    STAGE(0, 0);
    __syncthreads();                 // chunk 0 resident
    int cur = 0;
    for (int ck = 0; ck < 6; ck++) {
        if (ck < 5) STAGE(cur ^ 1, ck + 1);     // prefetch next chunk under compute
        bf16x8 afh[4], bfr[4];
        #pragma unroll
        for (int m = 0; m < 4; m++) {
            int R = wm * 64 + m * 16 + fr;      // [0,128)
            int unit = (R >> 1) * 8 + ((((R & 1) << 2) | kg) ^ ((R >> 1) & 7));
            afh[m] = *(const bf16x8*)&Wsb[cur][unit * 8];
        }
        #pragma unroll
        for (int n = 0; n < 4; n++) {
            int R = wn * 64 + n * 16 + fr;      // [0,256)
            int unit = (R >> 1) * 8 + ((((R & 1) << 2) | kg) ^ ((R >> 1) & 7));
            bfr[n] = *(const bf16x8*)&Xsb[cur][unit * 8];
        }
        #pragma unroll
        for (int m = 0; m < 4; m++)
            #pragma unroll
            for (int n = 0; n < 4; n++)
                acc[m][n] = __builtin_amdgcn_mfma_f32_16x16x32_bf16(afh[m], bfr[n], acc[m][n], 0, 0, 0);
        __syncthreads();             // prefetch done + WAR safe
        cur ^= 1;
    }

    // epilogue: two 128x128 half-tiles through Xsb (32 KB), coalesced stores
    ushort (*E)[128] = (ushort(*)[128])Xsb;
    ushort* ob = t1s + (size_t)tsr * ((size_t)BB * QKV_B) + (size_t)bg * QKV_B;
    #pragma unroll
    for (int hf = 0; hf < 2; hf++) {
        if (hf) __syncthreads();     // half-0 stores done before overwrite
        if ((wn >> 1) == hf) {
            int wn2 = wn & 1;
            #pragma unroll
            for (int m = 0; m < 4; m++) {
                int rl = wm * 64 + m * 16 + kg * 4;
                #pragma unroll
                for (int n = 0; n < 4; n++) {
                    int cl = wn2 * 64 + n * 16 + fr;
                    #pragma unroll
                    for (int r = 0; r < 4; r++)
                        E[rl + r][cl] = f2bf(acc[m][n][r]);
                }
            }
        }
        __syncthreads();
        #pragma unroll
        for (int i = 0; i < 4; i++) {
            int u = t + 512 * i;            // 2048: 128 rows x 16 col-units
            int row = u >> 4, c8 = u & 15;
            int oc = m0 + row;
            if (oc < C3)
                *(bf16x8*)&ob[(size_t)oc * HWP + n0 + hf * 128 + c8 * 8] =
                    *(bf16x8*)&E[row][c8 * 8];
        }
    }
}

// ============================================================
// depthwise 3x3, both tensors in one launch (grid 9216); q/k bf16 + fused
// L2 norm; v bf16
// ============================================================
__global__ __launch_bounds__(256) void dw3x3_kernel(const ushort* __restrict__ inp,
    const float* __restrict__ wd,
    ushort* __restrict__ qh0, ushort* __restrict__ vv0, float* __restrict__ inv0)
{
    __shared__ float P[66][72];
    const int bcg = blockIdx.x;
    const int tsr = bcg / (BB * C3);
    const int bc = bcg - tsr * (BB * C3);       // b*576 + ch
    const int b = bc / C3, ch = bc % C3;
    const int t = threadIdx.x;
    const ushort* ip = inp + (size_t)tsr * ((size_t)BB * QKV_B) + (size_t)bc * HWP;
    ushort* qh = qh0 + (size_t)tsr * 12582912;
    ushort* vv = vv0 + (size_t)tsr * 6291456;
    float* inv = inv0 + (size_t)tsr * 3072;
    float wr[9];
    #pragma unroll
    for (int k = 0; k < 9; k++) wr[k] = wd[ch * 9 + k];
    for (int i = t; i < 66 * 72; i += 256) ((float*)P)[i] = 0.f;
    __syncthreads();
    #pragma unroll
    for (int i = 0; i < 2; i++) {
        int u = t + 256 * i;            // 512 units of 8 px
        int y = u >> 3, x0 = (u & 7) * 8;
        bf16x8 v8 = *(const bf16x8*)&ip[u * 8];
        #pragma unroll
        for (int j = 0; j < 8; j++)
            P[1 + y][4 + x0 + j] = bf2f((ushort)v8[j]);
    }
    __syncthreads();

    float ssum = 0.f;
    #pragma unroll
    for (int i = 0; i < 4; i++) {
        int u = t + 256 * i;
        int y0 = u >> 4;
        int x0 = (u & 15) * 4;
        float res[4] = {0.f, 0.f, 0.f, 0.f};
        #pragma unroll
        for (int dy = 0; dy < 3; dy++) {
            float4 A = *(float4*)&P[y0 + dy][x0];
            float4 Bv = *(float4*)&P[y0 + dy][x0 + 4];
            float4 Cv = *(float4*)&P[y0 + dy][x0 + 8];
            float c0 = A.w, c1 = Bv.x, c2 = Bv.y, c3 = Bv.z, c4 = Bv.w, c5 = Cv.x;
            float w0 = wr[dy*3], w1 = wr[dy*3+1], w2 = wr[dy*3+2];
            res[0] += w0*c0 + w1*c1 + w2*c2;
            res[1] += w0*c1 + w1*c2 + w2*c3;
            res[2] += w0*c2 + w1*c3 + w2*c4;
            res[3] += w0*c3 + w1*c4 + w2*c5;
        }
        #pragma unroll
        for (int k = 0; k < 4; k++) ssum += res[k] * res[k];
        if (ch < 384) {
            size_t base = ((size_t)b * 384 + ch) * HWP + u * 4;
            *(ushort4*)&qh[base] = make_ushort4(f2bf(res[0]), f2bf(res[1]),
                                                f2bf(res[2]), f2bf(res[3]));
        } else {
            size_t base = ((size_t)b * CC + (ch - 384)) * HWP + u * 4;
            *(ushort4*)&vv[base] = make_ushort4(f2bf(res[0]), f2bf(res[1]),
                                                f2bf(res[2]), f2bf(res[3]));
        }
    }
    if (ch < 384) {
        #pragma unroll
        for (int off = 32; off > 0; off >>= 1) ssum += __shfl_down(ssum, off);
        __shared__ float red[4];
        if ((t & 63) == 0) red[t >> 6] = ssum;
        __syncthreads();
        if (t == 0) {
            float tot = red[0] + red[1] + red[2] + red[3];
            inv[b * 384 + ch] = 1.f / fmaxf(sqrtf(tot), 1e-12f);
        }
    }
}

// ============================================================
// stacked Gram via MFMA, single bf16 (proven, unchanged)
// ============================================================
__global__ __launch_bounds__(256) void gram_mfma(const ushort* __restrict__ qhx,
    const ushort* __restrict__ qhy, float* __restrict__ spart)
{
    __shared__ __align__(16) ushort As[96 * 64];
    __shared__ __align__(16) ushort Bs[96 * 64];
    const int chunk = blockIdx.x, bh = blockIdx.y;
    const int b = bh >> 2, h = bh & 3;
    const int t = threadIdx.x;
    const int lane = t & 63, w = t >> 6;
    const int wm = w >> 1, wn = w & 1;
    const int fr = lane & 15, kg = lane >> 4;

    const size_t qbase = ((size_t)b * 384 + h * DH) * HWP;
    const size_t kbase = ((size_t)b * 384 + 192 + h * DH) * HWP;

    f32x4 acc[3][3] = {};

    for (int ks = 0; ks < 8; ks++) {
        const int n0 = chunk * 512 + ks * 64;
        #pragma unroll
        for (int i = 0; i < 3; i++) {
            int u = i * 256 + w * 64 + lane;
            int r = u >> 3, c = u & 7;
            int cs = c ^ (r & 7);
            const ushort* ga = ((r < DH) ? (qhx + qbase + (size_t)r * HWP)
                                         : (qhy + qbase + (size_t)(r - DH) * HWP))
                               + n0 + cs * 8;
            __builtin_amdgcn_global_load_lds(AS1(ga), AS3(&As[(size_t)(i * 4 + w) * 512]), 16, 0, 0);
            const ushort* gb = ((r < DH) ? (qhx + kbase + (size_t)r * HWP)
                                         : (qhy + kbase + (size_t)(r - DH) * HWP))
                               + n0 + cs * 8;
            __builtin_amdgcn_global_load_lds(AS1(gb), AS3(&Bs[(size_t)(i * 4 + w) * 512]), 16, 0, 0);
        }
        __syncthreads();
        #pragma unroll
        for (int kq = 0; kq < 8; kq += 4) {
            bf16x8 af[3], bfr[3];
            #pragma unroll
            for (int m = 0; m < 3; m++) {
                int R = wm * DH + m * 16 + fr;
                int unit = R * 8 + ((kq + kg) ^ (R & 7));
                af[m] = *(const bf16x8*)&As[unit * 8];
            }
            #pragma unroll
            for (int n = 0; n < 3; n++) {
                int R = wn * DH + n * 16 + fr;
                int unit = R * 8 + ((kq + kg) ^ (R & 7));
                bfr[n] = *(const bf16x8*)&Bs[unit * 8];
            }
            #pragma unroll
            for (int m = 0; m < 3; m++)
                #pragma unroll
                for (int n = 0; n < 3; n++)
                    acc[m][n] = __builtin_amdgcn_mfma_f32_16x16x32_bf16(af[m], bfr[n], acc[m][n], 0, 0, 0);
        }
        __syncthreads();
    }

    float* sp = spart + ((size_t)chunk * 32 + bh) * 9216;
    #pragma unroll
    for (int m = 0; m < 3; m++) {
        int row = wm * DH + m * 16 + kg * 4;
        #pragma unroll
        for (int n = 0; n < 3; n++) {
            int col = wn * DH + n * 16 + fr;
            #pragma unroll
            for (int r = 0; r < 4; r++)
                sp[(row + r) * 96 + col] = acc[m][n][r];
        }
    }
}

// ============================================================
// combine split-K partials, scale, softmax; emit single-bf16 coefficient
// matrix M'(96 x 128): two BK=64 chunks [Mx|My], cols 48..63 of each zeroed
// ============================================================
__global__ __launch_bounds__(256) void softmax_kernel(const float* __restrict__ spart,
    const float* __restrict__ invx, const float* __restrict__ invy,
    const float* __restrict__ temp, ushort* __restrict__ mpp)
{
    __shared__ float G[96][97];
    const int bh = blockIdx.x, b = bh >> 2, h = bh & 3;
    const int t = threadIdx.x;
    const float ts = temp[h];
    for (int i = 0; i < 36; i++) {
        int f = t + 256 * i;
        float s = 0.f;
        #pragma unroll
        for (int cch = 0; cch < 8; cch++)
            s += spart[((size_t)cch * 32 + bh) * 9216 + f];
        int r = f / 96, c = f % 96;
        float iq = (r < DH) ? invx[b*384 + h*DH + r] : invy[b*384 + h*DH + (r-DH)];
        float ik = (c < DH) ? invx[b*384 + CC + h*DH + c] : invy[b*384 + CC + h*DH + (c-DH)];
        G[r][c] = s * iq * ik * ts;
    }
    __syncthreads();
    if (t < 192) {
        int r = t >> 1, hf = t & 1;
        float* rowp = &G[r][hf * DH];
        float m = rowp[0];
        for (int i = 1; i < DH; i++) m = fmaxf(m, rowp[i]);
        float s = 0.f;
        for (int i = 0; i < DH; i++) { float e = __expf(rowp[i] - m); rowp[i] = e; s += e; }
        float inv = 1.f / s;
        for (int i = 0; i < DH; i++) rowp[i] *= inv;
    }
    __syncthreads();
    ushort* mo = mpp + (size_t)bh * 96 * 128;
    for (int i = 0; i < 12; i++) {
        int f = t + 256 * i;                 // 96 rows x 32 pad cols
        int r = f / 32, p = f % 32;
        int ch = p >> 4, j = p & 15;
        mo[(size_t)r * 128 + ch * 64 + 48 + j] = 0;
    }
    for (int i = 0; i < 36; i++) {
        int f = t + 256 * i;
        int r = f / 96, c = f % 96;
        float v;
        if (c < DH) v = (r < DH) ? G[DH + r][c] : G[r - DH][c];
        else        v = G[r][c];
        ushort hi = f2bf(v);
        if (c < DH) mo[(size_t)r * 128 + c] = hi;
        else        mo[(size_t)r * 128 + 64 + (c - DH)] = hi;
    }
}

// ============================================================
// output GEMM via MFMA (proven round-12 kernel, unchanged)
// ============================================================
__global__ __launch_bounds__(256) void outmm_mfma(const ushort* __restrict__ VTx,
    const ushort* __restrict__ VTy, const ushort* __restrict__ mpp,
    float* __restrict__ out)
{
    __shared__ __align__(16) ushort As[96 * 64];
    __shared__ __align__(16) ushort Bs[128 * 64];
    const int t = threadIdx.x;
    const int lane = t & 63, w = t >> 6;
    const int wm = w >> 1, wn = w & 1;
    const int fr = lane & 15, kg = lane >> 4;
    const int nc = blockIdx.x, bh = blockIdx.y;
    const int b = bh >> 2, h = bh & 3;
    const int n0 = nc * 128;
    const ushort* mp = mpp + (size_t)bh * 96 * 128;

    f32x4 acc[3][4] = {};

    for (int kc = 0; kc < 2; kc++) {
        const ushort* Vsrc = kc ? VTy : VTx;
        const int coff = h * DH;
        const int aoff = kc * 64;
        #pragma unroll
        for (int i = 0; i < 3; i++) {
            int u = i * 256 + w * 64 + lane;
            int r = u >> 3, c = u & 7;
            int cs = c ^ (r & 7);
            const ushort* ga = mp + (size_t)r * 128 + aoff + cs * 8;
            __builtin_amdgcn_global_load_lds(AS1(ga), AS3(&As[(size_t)(i * 4 + w) * 512]), 16, 0, 0);
        }
        #pragma unroll
        for (int i = 0; i < 4; i++) {
            int u = i * 256 + w * 64 + lane;
            int r = u >> 3, c = u & 7;
            int cs = c ^ (r & 7);
            int c8 = coff + cs * 8;
            if (c8 >= 192) c8 -= 192;       // wrap: lands on zero-A K-rows
            const ushort* gb = Vsrc + ((size_t)(b * HWP + n0 + r)) * 192 + c8;
            __builtin_amdgcn_global_load_lds(AS1(gb), AS3(&Bs[(size_t)(i * 4 + w) * 512]), 16, 0, 0);
        }
        __syncthreads();
        #pragma unroll
        for (int kq = 0; kq < 8; kq += 4) {
            bf16x8 af[3], bfr[4];
            #pragma unroll
            for (int m = 0; m < 3; m++) {
                int R = wm * DH + m * 16 + fr;
                int unit = R * 8 + ((kq + kg) ^ (R & 7));
                af[m] = *(const bf16x8*)&As[unit * 8];
            }
            #pragma unroll
            for (int n = 0; n < 4; n++) {
                int R = wn * 64 + n * 16 + fr;
                int unit = R * 8 + ((kq + kg) ^ (R & 7));
                bfr[n] = *(const bf16x8*)&Bs[unit * 8];
            }
            #pragma unroll
            for (int m = 0; m < 3; m++)
                #pragma unroll
                for (int n = 0; n < 4; n++)
                    acc[m][n] = __builtin_amdgcn_mfma_f32_16x16x32_bf16(af[m], bfr[n], acc[m][n], 0, 0, 0);
        }
        __syncthreads();
    }

    #pragma unroll
    for (int m = 0; m < 3; m++) {
        int row = wm * DH + m * 16 + kg * 4;
        #pragma unroll
        for (int n = 0; n < 4; n++) {
            int col = n0 + wn * 64 + n * 16 + fr;
            #pragma unroll
            for (int r = 0; r < 4; r++) {
                int rr = row + r;
                float* dst = (rr < DH)
                    ? (out + (size_t)b * X_B + (h * DH + rr) * HWP + col)
                    : (out + OUT_HALF + (size_t)b * X_B + (h * DH + rr - DH) * HWP + col);
                *dst = acc[m][n][r];
            }
        }
    }
}

// ============================================================
extern "C" void kernel_launch(void* const* d_in, const int* in_sizes, int n_in,
                              void* d_out, int out_size, void* d_ws, size_t ws_size,
                              hipStream_t stream)
{
    const float* x  = (const float*)d_in[0];
    const float* y  = (const float*)d_in[1];
    const float* wq = (const float*)d_in[2];
    const float* wd = (const float*)d_in[3];
    const float* tp = (const float*)d_in[4];
    float* out = (float*)d_out;
    float* ws = (float*)d_ws;

    // ---- workspace layout (float units), total ~176 MB of 256 MB ----
    // qh: [2][8][384][4096] bf16 = 12,582,912 floats
    // v:  [2][8][192][4096] bf16 =  6,291,456 floats
    // t1: [2][8][576][4096] bf16 = 18,874,368 floats
    // XT: [2][8][4096][192] bf16 =  6,291,456 floats
    ushort* qh0 = (ushort*)ws;
    float*  v0f = ws + 12582912;
    ushort* v0  = (ushort*)v0f;
    float*  t10 = ws + 12582912 + 6291456;
    ushort* t1s = (ushort*)t10;
    ushort* XT  = (ushort*)(ws + 12582912 + 6291456 + 18874368);
    ushort* Wc  = (ushort*)(ws + 12582912 + 6291456 + 18874368 + 6291456);
    float*  inv0 = ws + 12582912 + 6291456 + 18874368 + 6291456 + 61440;
    float*  invx = inv0;
    float*  invy = inv0 + 3072;
    // aliases over t1 region (dead after dw):
    ushort* VTx  = t1s;                                  // 3,145,728 floats
    ushort* VTy  = (ushort*)(t10 + 3145728);
    float*  spart = t10 + 6291456;                       // 2,359,296 floats
    ushort* Mpp  = (ushort*)(t10 + 6291456 + 2359296);   // 196,608 floats
    // gram q pointers (contiguous x then y):
    ushort* qhx = qh0;
    ushort* qhy = qh0 + 12582912;

    wconvert_kernel<<<120, 256, 0, stream>>>(wq, Wc);

    // both tensors: convert -> conv -> dw (one dispatch each)
    convert_single_kernel<<<dim3(64, 3, 16), 256, 0, stream>>>(x, y, XT);
    conv1x1_mfma<<<1280, 512, 0, stream>>>(XT, Wc, t1s);
    dw3x3_kernel<<<2 * BB * C3, 256, 0, stream>>>(t1s, wd, qh0, v0, inv0);

    // transpose v (both tensors) into dead t1 region
    vtrans_kernel<<<dim3(64, 3, 16), 256, 0, stream>>>(v0, VTx);

    gram_mfma<<<dim3(8, 32), 256, 0, stream>>>(qhx, qhy, spart);
    softmax_kernel<<<32, 256, 0, stream>>>(spart, invx, invy, tp, Mpp);
    outmm_mfma<<<dim3(HWP / 128, 32), 256, 0, stream>>>(VTx, VTy, Mpp, out);
}

// Round 14
// 158.317 us; speedup vs baseline: 1.9924x; 1.0006x over previous
//
#include <hip/hip_runtime.h>

// ---- problem constants ----
#define CC   192                 // C
#define C3   576                 // 3C
#define HH   64
#define WW   64
#define HWP  4096                // H*W
#define BB   8
#define DH   48                  // C/HEADS
#define QKV_B (C3*HWP)           // elements per batch of conv-out tensor
#define X_B   (CC*HWP)
#define OUT_HALF ((size_t)BB*X_B)

typedef short bf16x8 __attribute__((ext_vector_type(8)));
typedef float f32x4  __attribute__((ext_vector_type(4)));

#define AS1(p) ((__attribute__((address_space(1))) void*)(p))
#define AS3(p) ((__attribute__((address_space(3))) void*)(p))

__device__ __forceinline__ ushort f2bf(float v) {
    union { float f; unsigned u; } a; a.f = v;
    unsigned r = a.u + 0x7FFF + ((a.u >> 16) & 1);   // RNE
    return (ushort)(r >> 16);
}
__device__ __forceinline__ float bf2f(ushort h) {
    union { float f; unsigned u; } a; a.u = ((unsigned)h) << 16; return a.f;
}

// ============================================================
// {x,y} (b,192,4096) fp32 -> XT (tsr,b,4096,192) bf16 single. z in [0,16).
// ============================================================
__global__ __launch_bounds__(256) void convert_single_kernel(const float* __restrict__ x,
    const float* __restrict__ y, ushort* __restrict__ xt)
{
    __shared__ float L[64][65];
    const int n0 = blockIdx.x * 64, c0 = blockIdx.y * 64, z = blockIdx.z;
    const int t = threadIdx.x;
    const float* ip = ((z < 8) ? x : y) + (size_t)(z & 7) * X_B;
    #pragma unroll
    for (int i = 0; i < 16; i++) {
        int e = t + 256 * i;
        int r = e >> 6, col = e & 63;
        L[r][col] = ip[(size_t)(c0 + r) * HWP + n0 + col];
    }
    __syncthreads();
    #pragma unroll
    for (int i = 0; i < 4; i++) {
        int e = t + 256 * i;
        int n = e >> 4, c4 = e & 15;
        ushort hi[4];
        #pragma unroll
        for (int j = 0; j < 4; j++)
            hi[j] = f2bf(L[c4 * 4 + j][n]);
        size_t base = ((size_t)z * HWP + n0 + n) * 192 + c0 + c4 * 4;
        *(ushort4*)&xt[base] = make_ushort4(hi[0], hi[1], hi[2], hi[3]);
    }
}

// ============================================================
// v bf16 (16 batch-slices,192,4096) -> VT (...,4096,192) transpose. z in [0,16).
// ============================================================
__global__ __launch_bounds__(256) void vtrans_kernel(const ushort* __restrict__ in,
    ushort* __restrict__ vt)
{
    __shared__ __align__(16) ushort L[64][72];
    const int n0 = blockIdx.x * 64, c0 = blockIdx.y * 64, z = blockIdx.z;
    const int t = threadIdx.x;
    const ushort* ip = in + (size_t)z * X_B;
    #pragma unroll
    for (int i = 0; i < 2; i++) {
        int e = t + 256 * i;            // 512 units of 8 ushorts
        int r = e >> 3, u8 = e & 7;
        *(bf16x8*)&L[r][u8 * 8] = *(const bf16x8*)&ip[(size_t)(c0 + r) * HWP + n0 + u8 * 8];
    }
    __syncthreads();
    #pragma unroll
    for (int i = 0; i < 4; i++) {
        int e = t + 256 * i;            // 1024: 64 n x 16 c4
        int n = e >> 4, c4 = e & 15;
        ushort o[4];
        #pragma unroll
        for (int j = 0; j < 4; j++) o[j] = L[c4 * 4 + j][n];
        *(ushort4*)&vt[((size_t)z * HWP + n0 + n) * 192 + c0 + c4 * 4] =
            make_ushort4(o[0], o[1], o[2], o[3]);
    }
}

// ============================================================
// w_qkv -> Wc(640,192) bf16 SINGLE, zero-padded rows 576..639
// ============================================================
__global__ __launch_bounds__(256) void wconvert_kernel(const float* __restrict__ wq,
    ushort* __restrict__ wc)
{
    int e = (blockIdx.x * 256 + threadIdx.x) * 4;    // 640*192 total
    int oc = e / 192, k = e % 192;
    ushort o[4] = {0, 0, 0, 0};
    if (oc < C3) {
        #pragma unroll
        for (int j = 0; j < 4; j++)
            o[j] = f2bf(wq[oc * CC + k + j]);
    }
    *(ushort4*)&wc[e] = make_ushort4(o[0], o[1], o[2], o[3]);
}

// ============================================================
// conv1x1 via MFMA (proven round-13 kernel, unchanged): tile 128x256,
// 512 thr, BK=32 dbuf, grid 1280, paired-row swizzle, bf16 epilogue.
// ============================================================
__global__ __launch_bounds__(512) void conv1x1_mfma(const ushort* __restrict__ XT,
    const ushort* __restrict__ Wc, ushort* __restrict__ t1s)
{
    __shared__ __align__(16) ushort Wsb[2][128 * 32];   // 2 x 8 KB
    __shared__ __align__(16) ushort Xsb[2][256 * 32];   // 2 x 16 KB
    const int t = threadIdx.x;
    const int lane = t & 63, w = t >> 6;
    const int wm = w >> 2, wn = w & 3;
    const int fr = lane & 15, kg = lane >> 4;
    const int g = blockIdx.x;
    const int xcd = g & 7, s = g >> 3;          // s in [0,160)
    const int bg = xcd;
    const int tsr = s / 80;
    const int rem = s - tsr * 80;
    const int nt = rem / 5;                     // 0..15
    const int mi = rem % 5;
    const int n0 = nt * 256;
    const int m0 = mi * 128;
    const ushort* XTp = XT + (size_t)(tsr * 8 + bg) * (HWP * 192);

    f32x4 acc[4][4] = {};

    auto STAGE = [&](int buf, int ck) {
        const int k0 = ck * 32;
        {   // W: 512 units (1/thread), 128 rows x 4 units
            int u = t;
            int rp = u >> 3;
            int p = (u & 7) ^ (rp & 7);
            int r = (rp << 1) | (p >> 2);
            int c = p & 3;
            const ushort* gw = Wc + (size_t)(m0 + r) * 192 + k0 + c * 8;
            __builtin_amdgcn_global_load_lds(AS1(gw), AS3(&Wsb[buf][(size_t)t * 8]), 16, 0, 0);
        }
        #pragma unroll
        for (int i = 0; i < 2; i++) {   // X: 1024 units (2/thread), 256 rows x 4 units
            int u = i * 512 + t;
            int rp = u >> 3;
            int p = (u & 7) ^ (rp & 7);
            int r = (rp << 1) | (p >> 2);
            int c = p & 3;
            const ushort* gx = XTp + (size_t)(n0 + r) * 192 + k0 + c * 8;
            __builtin_amdgcn_global_load_lds(AS1(gx), AS3(&Xsb[buf][(size_t)(i * 512 + t) * 8]), 16, 0, 0);
        }
    };

    STAGE(0, 0);
    __syncthreads();                 // chunk 0 resident
    int cur = 0;
    for (int ck = 0; ck < 6; ck++) {
        if (ck < 5) STAGE(cur ^ 1, ck + 1);     // prefetch next chunk under compute
        bf16x8 afh[4], bfr[4];
        #pragma unroll
        for (int m = 0; m < 4; m++) {
            int R = wm * 64 + m * 16 + fr;      // [0,128)
            int unit = (R >> 1) * 8 + ((((R & 1) << 2) | kg) ^ ((R >> 1) & 7));
            afh[m] = *(const bf16x8*)&Wsb[cur][unit * 8];
        }
        #pragma unroll
        for (int n = 0; n < 4; n++) {
            int R = wn * 64 + n * 16 + fr;      // [0,256)
            int unit = (R >> 1) * 8 + ((((R & 1) << 2) | kg) ^ ((R >> 1) & 7));
            bfr[n] = *(const bf16x8*)&Xsb[cur][unit * 8];
        }
        #pragma unroll
        for (int m = 0; m < 4; m++)
            #pragma unroll
            for (int n = 0; n < 4; n++)
                acc[m][n] = __builtin_amdgcn_mfma_f32_16x16x32_bf16(afh[m], bfr[n], acc[m][n], 0, 0, 0);
        __syncthreads();             // prefetch done + WAR safe
        cur ^= 1;
    }

    // epilogue: two 128x128 half-tiles through Xsb (32 KB), coalesced stores
    ushort (*E)[128] = (ushort(*)[128])Xsb;
    ushort* ob = t1s + (size_t)tsr * ((size_t)BB * QKV_B) + (size_t)bg * QKV_B;
    #pragma unroll
    for (int hf = 0; hf < 2; hf++) {
        if (hf) __syncthreads();     // half-0 stores done before overwrite
        if ((wn >> 1) == hf) {
            int wn2 = wn & 1;
            #pragma unroll
            for (int m = 0; m < 4; m++) {
                int rl = wm * 64 + m * 16 + kg * 4;
                #pragma unroll
                for (int n = 0; n < 4; n++) {
                    int cl = wn2 * 64 + n * 16 + fr;
                    #pragma unroll
                    for (int r = 0; r < 4; r++)
                        E[rl + r][cl] = f2bf(acc[m][n][r]);
                }
            }
        }
        __syncthreads();
        #pragma unroll
        for (int i = 0; i < 4; i++) {
            int u = t + 512 * i;            // 2048: 128 rows x 16 col-units
            int row = u >> 4, c8 = u & 15;
            int oc = m0 + row;
            if (oc < C3)
                *(bf16x8*)&ob[(size_t)oc * HWP + n0 + hf * 128 + c8 * 8] =
                    *(bf16x8*)&E[row][c8 * 8];
        }
    }
}

// ============================================================
// depthwise 3x3, both tensors in one launch (grid 9216); q/k bf16 + fused
// L2 norm; v bf16. P padded [66][76]: row stride 76 = 12 (mod 32) banks ->
// adjacent rows hit DISJOINT bank sets -> 2-way max (free). Fill uses
// 2 x float4 stores per thread (was 8 scalar stores, 4-way conflicted).
// ============================================================
__global__ __launch_bounds__(256) void dw3x3_kernel(const ushort* __restrict__ inp,
    const float* __restrict__ wd,
    ushort* __restrict__ qh0, ushort* __restrict__ vv0, float* __restrict__ inv0)
{
    __shared__ float P[66][76];
    const int bcg = blockIdx.x;
    const int tsr = bcg / (BB * C3);
    const int bc = bcg - tsr * (BB * C3);       // b*576 + ch
    const int b = bc / C3, ch = bc % C3;
    const int t = threadIdx.x;
    const ushort* ip = inp + (size_t)tsr * ((size_t)BB * QKV_B) + (size_t)bc * HWP;
    ushort* qh = qh0 + (size_t)tsr * 12582912;
    ushort* vv = vv0 + (size_t)tsr * 6291456;
    float* inv = inv0 + (size_t)tsr * 3072;
    float wr[9];
    #pragma unroll
    for (int k = 0; k < 9; k++) wr[k] = wd[ch * 9 + k];
    for (int i = t; i < 66 * 76; i += 256) ((float*)P)[i] = 0.f;
    __syncthreads();
    #pragma unroll
    for (int i = 0; i < 2; i++) {
        int u = t + 256 * i;            // 512 units of 8 px
        int y = u >> 3, x0 = (u & 7) * 8;
        bf16x8 v8 = *(const bf16x8*)&ip[u * 8];
        float f0 = bf2f((ushort)v8[0]), f1 = bf2f((ushort)v8[1]);
        float f2 = bf2f((ushort)v8[2]), f3 = bf2f((ushort)v8[3]);
        float f4 = bf2f((ushort)v8[4]), f5 = bf2f((ushort)v8[5]);
        float f6 = bf2f((ushort)v8[6]), f7 = bf2f((ushort)v8[7]);
        *(float4*)&P[1 + y][4 + x0]     = make_float4(f0, f1, f2, f3);
        *(float4*)&P[1 + y][4 + x0 + 4] = make_float4(f4, f5, f6, f7);
    }
    __syncthreads();

    float ssum = 0.f;
    #pragma unroll
    for (int i = 0; i < 4; i++) {
        int u = t + 256 * i;
        int y0 = u >> 4;
        int x0 = (u & 15) * 4;
        float res[4] = {0.f, 0.f, 0.f, 0.f};
        #pragma unroll
        for (int dy = 0; dy < 3; dy++) {
            float4 A = *(float4*)&P[y0 + dy][x0];
            float4 Bv = *(float4*)&P[y0 + dy][x0 + 4];
            float4 Cv = *(float4*)&P[y0 + dy][x0 + 8];
            float c0 = A.w, c1 = Bv.x, c2 = Bv.y, c3 = Bv.z, c4 = Bv.w, c5 = Cv.x;
            float w0 = wr[dy*3], w1 = wr[dy*3+1], w2 = wr[dy*3+2];
            res[0] += w0*c0 + w1*c1 + w2*c2;
            res[1] += w0*c1 + w1*c2 + w2*c3;
            res[2] += w0*c2 + w1*c3 + w2*c4;
            res[3] += w0*c3 + w1*c4 + w2*c5;
        }
        #pragma unroll
        for (int k = 0; k < 4; k++) ssum += res[k] * res[k];
        if (ch < 384) {
            size_t base = ((size_t)b * 384 + ch) * HWP + u * 4;
            *(ushort4*)&qh[base] = make_ushort4(f2bf(res[0]), f2bf(res[1]),
                                                f2bf(res[2]), f2bf(res[3]));
        } else {
            size_t base = ((size_t)b * CC + (ch - 384)) * HWP + u * 4;
            *(ushort4*)&vv[base] = make_ushort4(f2bf(res[0]), f2bf(res[1]),
                                                f2bf(res[2]), f2bf(res[3]));
        }
    }
    if (ch < 384) {
        #pragma unroll
        for (int off = 32; off > 0; off >>= 1) ssum += __shfl_down(ssum, off);
        __shared__ float red[4];
        if ((t & 63) == 0) red[t >> 6] = ssum;
        __syncthreads();
        if (t == 0) {
            float tot = red[0] + red[1] + red[2] + red[3];
            inv[b * 384 + ch] = 1.f / fmaxf(sqrtf(tot), 1e-12f);
        }
    }
}

// ============================================================
// stacked Gram via MFMA, single bf16 (proven, unchanged)
// ============================================================
__global__ __launch_bounds__(256) void gram_mfma(const ushort* __restrict__ qhx,
    const ushort* __restrict__ qhy, float* __restrict__ spart)
{
    __shared__ __align__(16) ushort As[96 * 64];
    __shared__ __align__(16) ushort Bs[96 * 64];
    const int chunk = blockIdx.x, bh = blockIdx.y;
    const int b = bh >> 2, h = bh & 3;
    const int t = threadIdx.x;
    const int lane = t & 63, w = t >> 6;
    const int wm = w >> 1, wn = w & 1;
    const int fr = lane & 15, kg = lane >> 4;

    const size_t qbase = ((size_t)b * 384 + h * DH) * HWP;
    const size_t kbase = ((size_t)b * 384 + 192 + h * DH) * HWP;

    f32x4 acc[3][3] = {};

    for (int ks = 0; ks < 8; ks++) {
        const int n0 = chunk * 512 + ks * 64;
        #pragma unroll
        for (int i = 0; i < 3; i++) {
            int u = i * 256 + w * 64 + lane;
            int r = u >> 3, c = u & 7;
            int cs = c ^ (r & 7);
            const ushort* ga = ((r < DH) ? (qhx + qbase + (size_t)r * HWP)
                                         : (qhy + qbase + (size_t)(r - DH) * HWP))
                               + n0 + cs * 8;
            __builtin_amdgcn_global_load_lds(AS1(ga), AS3(&As[(size_t)(i * 4 + w) * 512]), 16, 0, 0);
            const ushort* gb = ((r < DH) ? (qhx + kbase + (size_t)r * HWP)
                                         : (qhy + kbase + (size_t)(r - DH) * HWP))
                               + n0 + cs * 8;
            __builtin_amdgcn_global_load_lds(AS1(gb), AS3(&Bs[(size_t)(i * 4 + w) * 512]), 16, 0, 0);
        }
        __syncthreads();
        #pragma unroll
        for (int kq = 0; kq < 8; kq += 4) {
            bf16x8 af[3], bfr[3];
            #pragma unroll
            for (int m = 0; m < 3; m++) {
                int R = wm * DH + m * 16 + fr;
                int unit = R * 8 + ((kq + kg) ^ (R & 7));
                af[m] = *(const bf16x8*)&As[unit * 8];
            }
            #pragma unroll
            for (int n = 0; n < 3; n++) {
                int R = wn * DH + n * 16 + fr;
                int unit = R * 8 + ((kq + kg) ^ (R & 7));
                bfr[n] = *(const bf16x8*)&Bs[unit * 8];
            }
            #pragma unroll
            for (int m = 0; m < 3; m++)
                #pragma unroll
                for (int n = 0; n < 3; n++)
                    acc[m][n] = __builtin_amdgcn_mfma_f32_16x16x32_bf16(af[m], bfr[n], acc[m][n], 0, 0, 0);
        }
        __syncthreads();
    }

    float* sp = spart + ((size_t)chunk * 32 + bh) * 9216;
    #pragma unroll
    for (int m = 0; m < 3; m++) {
        int row = wm * DH + m * 16 + kg * 4;
        #pragma unroll
        for (int n = 0; n < 3; n++) {
            int col = wn * DH + n * 16 + fr;
            #pragma unroll
            for (int r = 0; r < 4; r++)
                sp[(row + r) * 96 + col] = acc[m][n][r];
        }
    }
}

// ============================================================
// combine split-K partials, scale, softmax; emit single-bf16 coefficient
// matrix M'(96 x 128): two BK=64 chunks [Mx|My], cols 48..63 of each zeroed
// ============================================================
__global__ __launch_bounds__(256) void softmax_kernel(const float* __restrict__ spart,
    const float* __restrict__ invx, const float* __restrict__ invy,
    const float* __restrict__ temp, ushort* __restrict__ mpp)
{
    __shared__ float G[96][97];
    const int bh = blockIdx.x, b = bh >> 2, h = bh & 3;
    const int t = threadIdx.x;
    const float ts = temp[h];
    for (int i = 0; i < 36; i++) {
        int f = t + 256 * i;
        float s = 0.f;
        #pragma unroll
        for (int cch = 0; cch < 8; cch++)
            s += spart[((size_t)cch * 32 + bh) * 9216 + f];
        int r = f / 96, c = f % 96;
        float iq = (r < DH) ? invx[b*384 + h*DH + r] : invy[b*384 + h*DH + (r-DH)];
        float ik = (c < DH) ? invx[b*384 + CC + h*DH + c] : invy[b*384 + CC + h*DH + (c-DH)];
        G[r][c] = s * iq * ik * ts;
    }
    __syncthreads();
    if (t < 192) {
        int r = t >> 1, hf = t & 1;
        float* rowp = &G[r][hf * DH];
        float m = rowp[0];
        for (int i = 1; i < DH; i++) m = fmaxf(m, rowp[i]);
        float s = 0.f;
        for (int i = 0; i < DH; i++) { float e = __expf(rowp[i] - m); rowp[i] = e; s += e; }
        float inv = 1.f / s;
        for (int i = 0; i < DH; i++) rowp[i] *= inv;
    }
    __syncthreads();
    ushort* mo = mpp + (size_t)bh * 96 * 128;
    for (int i = 0; i < 12; i++) {
        int f = t + 256 * i;                 // 96 rows x 32 pad cols
        int r = f / 32, p = f % 32;
        int ch = p >> 4, j = p & 15;
        mo[(size_t)r * 128 + ch * 64 + 48 + j] = 0;
    }
    for (int i = 0; i < 36; i++) {
        int f = t + 256 * i;
        int r = f / 96, c = f % 96;
        float v;
        if (c < DH) v = (r < DH) ? G[DH + r][c] : G[r - DH][c];
        else        v = G[r][c];
        ushort hi = f2bf(v);
        if (c < DH) mo[(size_t)r * 128 + c] = hi;
        else        mo[(size_t)r * 128 + 64 + (c - DH)] = hi;
    }
}

// ============================================================
// output GEMM via MFMA (proven, unchanged)
// ============================================================
__global__ __launch_bounds__(256) void outmm_mfma(const ushort* __restrict__ VTx,
    const ushort* __restrict__ VTy, const ushort* __restrict__ mpp,
    float* __restrict__ out)
{
    __shared__ __align__(16) ushort As[96 * 64];
    __shared__ __align__(16) ushort Bs[128 * 64];
    const int t = threadIdx.x;
    const int lane = t & 63, w = t >> 6;
    const int wm = w >> 1, wn = w & 1;
    const int fr = lane & 15, kg = lane >> 4;
    const int nc = blockIdx.x, bh = blockIdx.y;
    const int b = bh >> 2, h = bh & 3;
    const int n0 = nc * 128;
    const ushort* mp = mpp + (size_t)bh * 96 * 128;

    f32x4 acc[3][4] = {};

    for (int kc = 0; kc < 2; kc++) {
        const ushort* Vsrc = kc ? VTy : VTx;
        const int coff = h * DH;
        const int aoff = kc * 64;
        #pragma unroll
        for (int i = 0; i < 3; i++) {
            int u = i * 256 + w * 64 + lane;
            int r = u >> 3, c = u & 7;
            int cs = c ^ (r & 7);
            const ushort* ga = mp + (size_t)r * 128 + aoff + cs * 8;
            __builtin_amdgcn_global_load_lds(AS1(ga), AS3(&As[(size_t)(i * 4 + w) * 512]), 16, 0, 0);
        }
        #pragma unroll
        for (int i = 0; i < 4; i++) {
            int u = i * 256 + w * 64 + lane;
            int r = u >> 3, c = u & 7;
            int cs = c ^ (r & 7);
            int c8 = coff + cs * 8;
            if (c8 >= 192) c8 -= 192;       // wrap: lands on zero-A K-rows
            const ushort* gb = Vsrc + ((size_t)(b * HWP + n0 + r)) * 192 + c8;
            __builtin_amdgcn_global_load_lds(AS1(gb), AS3(&Bs[(size_t)(i * 4 + w) * 512]), 16, 0, 0);
        }
        __syncthreads();
        #pragma unroll
        for (int kq = 0; kq < 8; kq += 4) {
            bf16x8 af[3], bfr[4];
            #pragma unroll
            for (int m = 0; m < 3; m++) {
                int R = wm * DH + m * 16 + fr;
                int unit = R * 8 + ((kq + kg) ^ (R & 7));
                af[m] = *(const bf16x8*)&As[unit * 8];
            }
            #pragma unroll
            for (int n = 0; n < 4; n++) {
                int R = wn * 64 + n * 16 + fr;
                int unit = R * 8 + ((kq + kg) ^ (R & 7));
                bfr[n] = *(const bf16x8*)&Bs[unit * 8];
            }
            #pragma unroll
            for (int m = 0; m < 3; m++)
                #pragma unroll
                for (int n = 0; n < 4; n++)
                    acc[m][n] = __builtin_amdgcn_mfma_f32_16x16x32_bf16(af[m], bfr[n], acc[m][n], 0, 0, 0);
        }
        __syncthreads();
    }

    #pragma unroll
    for (int m = 0; m < 3; m++) {
        int row = wm * DH + m * 16 + kg * 4;
        #pragma unroll
        for (int n = 0; n < 4; n++) {
            int col = n0 + wn * 64 + n * 16 + fr;
            #pragma unroll
            for (int r = 0; r < 4; r++) {
                int rr = row + r;
                float* dst = (rr < DH)
                    ? (out + (size_t)b * X_B + (h * DH + rr) * HWP + col)
                    : (out + OUT_HALF + (size_t)b * X_B + (h * DH + rr - DH) * HWP + col);
                *dst = acc[m][n][r];
            }
        }
    }
}

// ============================================================
extern "C" void kernel_launch(void* const* d_in, const int* in_sizes, int n_in,
                              void* d_out, int out_size, void* d_ws, size_t ws_size,
                              hipStream_t stream)
{
    const float* x  = (const float*)d_in[0];
    const float* y  = (const float*)d_in[1];
    const float* wq = (const float*)d_in[2];
    const float* wd = (const float*)d_in[3];
    const float* tp = (const float*)d_in[4];
    float* out = (float*)d_out;
    float* ws = (float*)d_ws;

    // ---- workspace layout (float units), total ~176 MB of 256 MB ----
    ushort* qh0 = (ushort*)ws;
    float*  v0f = ws + 12582912;
    ushort* v0  = (ushort*)v0f;
    float*  t10 = ws + 12582912 + 6291456;
    ushort* t1s = (ushort*)t10;
    ushort* XT  = (ushort*)(ws + 12582912 + 6291456 + 18874368);
    ushort* Wc  = (ushort*)(ws + 12582912 + 6291456 + 18874368 + 6291456);
    float*  inv0 = ws + 12582912 + 6291456 + 18874368 + 6291456 + 61440;
    float*  invx = inv0;
    float*  invy = inv0 + 3072;
    // aliases over t1 region (dead after dw):
    ushort* VTx  = t1s;
    ushort* VTy  = (ushort*)(t10 + 3145728);
    float*  spart = t10 + 6291456;
    ushort* Mpp  = (ushort*)(t10 + 6291456 + 2359296);
    ushort* qhx = qh0;
    ushort* qhy = qh0 + 12582912;

    wconvert_kernel<<<120, 256, 0, stream>>>(wq, Wc);

    // both tensors: convert -> conv -> dw (one dispatch each)
    convert_single_kernel<<<dim3(64, 3, 16), 256, 0, stream>>>(x, y, XT);
    conv1x1_mfma<<<1280, 512, 0, stream>>>(XT, Wc, t1s);
    dw3x3_kernel<<<2 * BB * C3, 256, 0, stream>>>(t1s, wd, qh0, v0, inv0);

    // transpose v (both tensors) into dead t1 region
    vtrans_kernel<<<dim3(64, 3, 16), 256, 0, stream>>>(v0, VTx);

    gram_mfma<<<dim3(8, 32), 256, 0, stream>>>(qhx, qhy, spart);
    softmax_kernel<<<32, 256, 0, stream>>>(spart, invx, invy, tp, Mpp);
    outmm_mfma<<<dim3(HWP / 128, 32), 256, 0, stream>>>(VTx, VTy, Mpp, out);
}

// Round 15
// 142.371 us; speedup vs baseline: 2.2156x; 1.1120x over previous
//
#include <hip/hip_runtime.h>

// ---- problem constants ----
#define CC   192                 // C
#define C3   576                 // 3C
#define HH   64
#define WW   64
#define HWP  4096                // H*W
#define BB   8
#define DH   48                  // C/HEADS
#define QKV_B (C3*HWP)           // elements per batch of conv-out tensor
#define X_B   (CC*HWP)
#define OUT_HALF ((size_t)BB*X_B)

typedef short bf16x8 __attribute__((ext_vector_type(8)));
typedef float f32x4  __attribute__((ext_vector_type(4)));

#define AS1(p) ((__attribute__((address_space(1))) void*)(p))
#define AS3(p) ((__attribute__((address_space(3))) void*)(p))

__device__ __forceinline__ ushort f2bf(float v) {
    union { float f; unsigned u; } a; a.f = v;
    unsigned r = a.u + 0x7FFF + ((a.u >> 16) & 1);   // RNE
    return (ushort)(r >> 16);
}
__device__ __forceinline__ float bf2f(ushort h) {
    union { float f; unsigned u; } a; a.u = ((unsigned)h) << 16; return a.f;
}

// ============================================================
// {x,y} (b,192,4096) fp32 -> XT (tsr,b,4096,192) bf16 single. z in [0,16).
// ============================================================
__global__ __launch_bounds__(256) void convert_single_kernel(const float* __restrict__ x,
    const float* __restrict__ y, ushort* __restrict__ xt)
{
    __shared__ float L[64][65];
    const int n0 = blockIdx.x * 64, c0 = blockIdx.y * 64, z = blockIdx.z;
    const int t = threadIdx.x;
    const float* ip = ((z < 8) ? x : y) + (size_t)(z & 7) * X_B;
    #pragma unroll
    for (int i = 0; i < 16; i++) {
        int e = t + 256 * i;
        int r = e >> 6, col = e & 63;
        L[r][col] = ip[(size_t)(c0 + r) * HWP + n0 + col];
    }
    __syncthreads();
    #pragma unroll
    for (int i = 0; i < 4; i++) {
        int e = t + 256 * i;
        int n = e >> 4, c4 = e & 15;
        ushort hi[4];
        #pragma unroll
        for (int j = 0; j < 4; j++)
            hi[j] = f2bf(L[c4 * 4 + j][n]);
        size_t base = ((size_t)z * HWP + n0 + n) * 192 + c0 + c4 * 4;
        *(ushort4*)&xt[base] = make_ushort4(hi[0], hi[1], hi[2], hi[3]);
    }
}

// ============================================================
// v bf16 (16 batch-slices,192,4096) -> VT (...,4096,192) transpose. z in [0,16).
// ============================================================
__global__ __launch_bounds__(256) void vtrans_kernel(const ushort* __restrict__ in,
    ushort* __restrict__ vt)
{
    __shared__ __align__(16) ushort L[64][72];
    const int n0 = blockIdx.x * 64, c0 = blockIdx.y * 64, z = blockIdx.z;
    const int t = threadIdx.x;
    const ushort* ip = in + (size_t)z * X_B;
    #pragma unroll
    for (int i = 0; i < 2; i++) {
        int e = t + 256 * i;            // 512 units of 8 ushorts
        int r = e >> 3, u8 = e & 7;
        *(bf16x8*)&L[r][u8 * 8] = *(const bf16x8*)&ip[(size_t)(c0 + r) * HWP + n0 + u8 * 8];
    }
    __syncthreads();
    #pragma unroll
    for (int i = 0; i < 4; i++) {
        int e = t + 256 * i;            // 1024: 64 n x 16 c4
        int n = e >> 4, c4 = e & 15;
        ushort o[4];
        #pragma unroll
        for (int j = 0; j < 4; j++) o[j] = L[c4 * 4 + j][n];
        *(ushort4*)&vt[((size_t)z * HWP + n0 + n) * 192 + c0 + c4 * 4] =
            make_ushort4(o[0], o[1], o[2], o[3]);
    }
}

// ============================================================
// w_qkv -> Wc(640,192) bf16 SINGLE, zero-padded rows 576..639
// ============================================================
__global__ __launch_bounds__(256) void wconvert_kernel(const float* __restrict__ wq,
    ushort* __restrict__ wc)
{
    int e = (blockIdx.x * 256 + threadIdx.x) * 4;    // 640*192 total
    int oc = e / 192, k = e % 192;
    ushort o[4] = {0, 0, 0, 0};
    if (oc < C3) {
        #pragma unroll
        for (int j = 0; j < 4; j++)
            o[j] = f2bf(wq[oc * CC + k + j]);
    }
    *(ushort4*)&wc[e] = make_ushort4(o[0], o[1], o[2], o[3]);
}

// ============================================================
// conv1x1 via MFMA (proven, unchanged): tile 128x256, 512 thr, BK=32 dbuf,
// grid 1280, paired-row swizzle, bf16 epilogue.
// ============================================================
__global__ __launch_bounds__(512) void conv1x1_mfma(const ushort* __restrict__ XT,
    const ushort* __restrict__ Wc, ushort* __restrict__ t1s)
{
    __shared__ __align__(16) ushort Wsb[2][128 * 32];   // 2 x 8 KB
    __shared__ __align__(16) ushort Xsb[2][256 * 32];   // 2 x 16 KB
    const int t = threadIdx.x;
    const int lane = t & 63, w = t >> 6;
    const int wm = w >> 2, wn = w & 3;
    const int fr = lane & 15, kg = lane >> 4;
    const int g = blockIdx.x;
    const int xcd = g & 7, s = g >> 3;          // s in [0,160)
    const int bg = xcd;
    const int tsr = s / 80;
    const int rem = s - tsr * 80;
    const int nt = rem / 5;                     // 0..15
    const int mi = rem % 5;
    const int n0 = nt * 256;
    const int m0 = mi * 128;
    const ushort* XTp = XT + (size_t)(tsr * 8 + bg) * (HWP * 192);

    f32x4 acc[4][4] = {};

    auto STAGE = [&](int buf, int ck) {
        const int k0 = ck * 32;
        {   // W: 512 units (1/thread), 128 rows x 4 units
            int u = t;
            int rp = u >> 3;
            int p = (u & 7) ^ (rp & 7);
            int r = (rp << 1) | (p >> 2);
            int c = p & 3;
            const ushort* gw = Wc + (size_t)(m0 + r) * 192 + k0 + c * 8;
            __builtin_amdgcn_global_load_lds(AS1(gw), AS3(&Wsb[buf][(size_t)t * 8]), 16, 0, 0);
        }
        #pragma unroll
        for (int i = 0; i < 2; i++) {   // X: 1024 units (2/thread), 256 rows x 4 units
            int u = i * 512 + t;
            int rp = u >> 3;
            int p = (u & 7) ^ (rp & 7);
            int r = (rp << 1) | (p >> 2);
            int c = p & 3;
            const ushort* gx = XTp + (size_t)(n0 + r) * 192 + k0 + c * 8;
            __builtin_amdgcn_global_load_lds(AS1(gx), AS3(&Xsb[buf][(size_t)(i * 512 + t) * 8]), 16, 0, 0);
        }
    };

    STAGE(0, 0);
    __syncthreads();                 // chunk 0 resident
    int cur = 0;
    for (int ck = 0; ck < 6; ck++) {
        if (ck < 5) STAGE(cur ^ 1, ck + 1);     // prefetch next chunk under compute
        bf16x8 afh[4], bfr[4];
        #pragma unroll
        for (int m = 0; m < 4; m++) {
            int R = wm * 64 + m * 16 + fr;      // [0,128)
            int unit = (R >> 1) * 8 + ((((R & 1) << 2) | kg) ^ ((R >> 1) & 7));
            afh[m] = *(const bf16x8*)&Wsb[cur][unit * 8];
        }
        #pragma unroll
        for (int n = 0; n < 4; n++) {
            int R = wn * 64 + n * 16 + fr;      // [0,256)
            int unit = (R >> 1) * 8 + ((((R & 1) << 2) | kg) ^ ((R >> 1) & 7));
            bfr[n] = *(const bf16x8*)&Xsb[cur][unit * 8];
        }
        #pragma unroll
        for (int m = 0; m < 4; m++)
            #pragma unroll
            for (int n = 0; n < 4; n++)
                acc[m][n] = __builtin_amdgcn_mfma_f32_16x16x32_bf16(afh[m], bfr[n], acc[m][n], 0, 0, 0);
        __syncthreads();             // prefetch done + WAR safe
        cur ^= 1;
    }

    // epilogue: two 128x128 half-tiles through Xsb (32 KB), coalesced stores
    ushort (*E)[128] = (ushort(*)[128])Xsb;
    ushort* ob = t1s + (size_t)tsr * ((size_t)BB * QKV_B) + (size_t)bg * QKV_B;
    #pragma unroll
    for (int hf = 0; hf < 2; hf++) {
        if (hf) __syncthreads();     // half-0 stores done before overwrite
        if ((wn >> 1) == hf) {
            int wn2 = wn & 1;
            #pragma unroll
            for (int m = 0; m < 4; m++) {
                int rl = wm * 64 + m * 16 + kg * 4;
                #pragma unroll
                for (int n = 0; n < 4; n++) {
                    int cl = wn2 * 64 + n * 16 + fr;
                    #pragma unroll
                    for (int r = 0; r < 4; r++)
                        E[rl + r][cl] = f2bf(acc[m][n][r]);
                }
            }
        }
        __syncthreads();
        #pragma unroll
        for (int i = 0; i < 4; i++) {
            int u = t + 512 * i;            // 2048: 128 rows x 16 col-units
            int row = u >> 4, c8 = u & 15;
            int oc = m0 + row;
            if (oc < C3)
                *(bf16x8*)&ob[(size_t)oc * HWP + n0 + hf * 128 + c8 * 8] =
                    *(bf16x8*)&E[row][c8 * 8];
        }
    }
}

// ============================================================
// depthwise 3x3, both tensors (grid 9216). 4x4 register-blocked output per
// thread with rolling 3-row window: 18 ds_read_b128 / 16 px (was 36 / 16 px)
// — dw is LDS-read-instruction bound, this halves the budget. Same lane->
// column mapping (banking unchanged). q/k bf16 + fused L2 norm; v bf16.
// ============================================================
__global__ __launch_bounds__(256) void dw3x3_kernel(const ushort* __restrict__ inp,
    const float* __restrict__ wd,
    ushort* __restrict__ qh0, ushort* __restrict__ vv0, float* __restrict__ inv0)
{
    __shared__ float P[66][76];
    const int bcg = blockIdx.x;
    const int tsr = bcg / (BB * C3);
    const int bc = bcg - tsr * (BB * C3);       // b*576 + ch
    const int b = bc / C3, ch = bc % C3;
    const int t = threadIdx.x;
    const ushort* ip = inp + (size_t)tsr * ((size_t)BB * QKV_B) + (size_t)bc * HWP;
    ushort* qh = qh0 + (size_t)tsr * 12582912;
    ushort* vv = vv0 + (size_t)tsr * 6291456;
    float* inv = inv0 + (size_t)tsr * 3072;
    float wr[9];
    #pragma unroll
    for (int k = 0; k < 9; k++) wr[k] = wd[ch * 9 + k];
    for (int i = t; i < 66 * 76; i += 256) ((float*)P)[i] = 0.f;
    __syncthreads();
    #pragma unroll
    for (int i = 0; i < 2; i++) {
        int u = t + 256 * i;            // 512 units of 8 px
        int y = u >> 3, x0 = (u & 7) * 8;
        bf16x8 v8 = *(const bf16x8*)&ip[u * 8];
        float f0 = bf2f((ushort)v8[0]), f1 = bf2f((ushort)v8[1]);
        float f2 = bf2f((ushort)v8[2]), f3 = bf2f((ushort)v8[3]);
        float f4 = bf2f((ushort)v8[4]), f5 = bf2f((ushort)v8[5]);
        float f6 = bf2f((ushort)v8[6]), f7 = bf2f((ushort)v8[7]);
        *(float4*)&P[1 + y][4 + x0]     = make_float4(f0, f1, f2, f3);
        *(float4*)&P[1 + y][4 + x0 + 4] = make_float4(f4, f5, f6, f7);
    }
    __syncthreads();

    // thread (tx,ty): output rows y0..y0+3, cols x0..x0+3 (image coords)
    const int tx = t & 15, ty = t >> 4;
    const int x0 = tx * 4, y0 = ty * 4;

    float ssum = 0.f;
    // rolling 3-row window over P rows y0 .. y0+5
    float4 a0 = *(float4*)&P[y0][x0], b0 = *(float4*)&P[y0][x0 + 4], c0 = *(float4*)&P[y0][x0 + 8];
    float4 a1 = *(float4*)&P[y0 + 1][x0], b1 = *(float4*)&P[y0 + 1][x0 + 4], c1 = *(float4*)&P[y0 + 1][x0 + 8];
    #pragma unroll
    for (int r = 0; r < 4; r++) {
        float4 a2 = *(float4*)&P[y0 + r + 2][x0];
        float4 b2 = *(float4*)&P[y0 + r + 2][x0 + 4];
        float4 c2 = *(float4*)&P[y0 + r + 2][x0 + 8];
        float res[4] = {0.f, 0.f, 0.f, 0.f};
        {   // dy = 0 (weights wr[0..2]) on row-set 0
            float e0 = a0.w, e1 = b0.x, e2 = b0.y, e3 = b0.z, e4 = b0.w, e5 = c0.x;
            res[0] += wr[0]*e0 + wr[1]*e1 + wr[2]*e2;
            res[1] += wr[0]*e1 + wr[1]*e2 + wr[2]*e3;
            res[2] += wr[0]*e2 + wr[1]*e3 + wr[2]*e4;
            res[3] += wr[0]*e3 + wr[1]*e4 + wr[2]*e5;
        }
        {   // dy = 1
            float e0 = a1.w, e1 = b1.x, e2 = b1.y, e3 = b1.z, e4 = b1.w, e5 = c1.x;
            res[0] += wr[3]*e0 + wr[4]*e1 + wr[5]*e2;
            res[1] += wr[3]*e1 + wr[4]*e2 + wr[5]*e3;
            res[2] += wr[3]*e2 + wr[4]*e3 + wr[5]*e4;
            res[3] += wr[3]*e3 + wr[4]*e4 + wr[5]*e5;
        }
        {   // dy = 2
            float e0 = a2.w, e1 = b2.x, e2 = b2.y, e3 = b2.z, e4 = b2.w, e5 = c2.x;
            res[0] += wr[6]*e0 + wr[7]*e1 + wr[8]*e2;
            res[1] += wr[6]*e1 + wr[7]*e2 + wr[8]*e3;
            res[2] += wr[6]*e2 + wr[7]*e3 + wr[8]*e4;
            res[3] += wr[6]*e3 + wr[7]*e4 + wr[8]*e5;
        }
        #pragma unroll
        for (int k = 0; k < 4; k++) ssum += res[k] * res[k];
        int px = (y0 + r) * WW + x0;
        if (ch < 384) {
            size_t base = ((size_t)b * 384 + ch) * HWP + px;
            *(ushort4*)&qh[base] = make_ushort4(f2bf(res[0]), f2bf(res[1]),
                                                f2bf(res[2]), f2bf(res[3]));
        } else {
            size_t base = ((size_t)b * CC + (ch - 384)) * HWP + px;
            *(ushort4*)&vv[base] = make_ushort4(f2bf(res[0]), f2bf(res[1]),
                                                f2bf(res[2]), f2bf(res[3]));
        }
        // rotate window
        a0 = a1; b0 = b1; c0 = c1;
        a1 = a2; b1 = b2; c1 = c2;
    }
    if (ch < 384) {
        #pragma unroll
        for (int off = 32; off > 0; off >>= 1) ssum += __shfl_down(ssum, off);
        __shared__ float red[4];
        if ((t & 63) == 0) red[t >> 6] = ssum;
        __syncthreads();
        if (t == 0) {
            float tot = red[0] + red[1] + red[2] + red[3];
            inv[b * 384 + ch] = 1.f / fmaxf(sqrtf(tot), 1e-12f);
        }
    }
}

// ============================================================
// stacked Gram via MFMA, single bf16 (proven, unchanged)
// ============================================================
__global__ __launch_bounds__(256) void gram_mfma(const ushort* __restrict__ qhx,
    const ushort* __restrict__ qhy, float* __restrict__ spart)
{
    __shared__ __align__(16) ushort As[96 * 64];
    __shared__ __align__(16) ushort Bs[96 * 64];
    const int chunk = blockIdx.x, bh = blockIdx.y;
    const int b = bh >> 2, h = bh & 3;
    const int t = threadIdx.x;
    const int lane = t & 63, w = t >> 6;
    const int wm = w >> 1, wn = w & 1;
    const int fr = lane & 15, kg = lane >> 4;

    const size_t qbase = ((size_t)b * 384 + h * DH) * HWP;
    const size_t kbase = ((size_t)b * 384 + 192 + h * DH) * HWP;

    f32x4 acc[3][3] = {};

    for (int ks = 0; ks < 8; ks++) {
        const int n0 = chunk * 512 + ks * 64;
        #pragma unroll
        for (int i = 0; i < 3; i++) {
            int u = i * 256 + w * 64 + lane;
            int r = u >> 3, c = u & 7;
            int cs = c ^ (r & 7);
            const ushort* ga = ((r < DH) ? (qhx + qbase + (size_t)r * HWP)
                                         : (qhy + qbase + (size_t)(r - DH) * HWP))
                               + n0 + cs * 8;
            __builtin_amdgcn_global_load_lds(AS1(ga), AS3(&As[(size_t)(i * 4 + w) * 512]), 16, 0, 0);
            const ushort* gb = ((r < DH) ? (qhx + kbase + (size_t)r * HWP)
                                         : (qhy + kbase + (size_t)(r - DH) * HWP))
                               + n0 + cs * 8;
            __builtin_amdgcn_global_load_lds(AS1(gb), AS3(&Bs[(size_t)(i * 4 + w) * 512]), 16, 0, 0);
        }
        __syncthreads();
        #pragma unroll
        for (int kq = 0; kq < 8; kq += 4) {
            bf16x8 af[3], bfr[3];
            #pragma unroll
            for (int m = 0; m < 3; m++) {
                int R = wm * DH + m * 16 + fr;
                int unit = R * 8 + ((kq + kg) ^ (R & 7));
                af[m] = *(const bf16x8*)&As[unit * 8];
            }
            #pragma unroll
            for (int n = 0; n < 3; n++) {
                int R = wn * DH + n * 16 + fr;
                int unit = R * 8 + ((kq + kg) ^ (R & 7));
                bfr[n] = *(const bf16x8*)&Bs[unit * 8];
            }
            #pragma unroll
            for (int m = 0; m < 3; m++)
                #pragma unroll
                for (int n = 0; n < 3; n++)
                    acc[m][n] = __builtin_amdgcn_mfma_f32_16x16x32_bf16(af[m], bfr[n], acc[m][n], 0, 0, 0);
        }
        __syncthreads();
    }

    float* sp = spart + ((size_t)chunk * 32 + bh) * 9216;
    #pragma unroll
    for (int m = 0; m < 3; m++) {
        int row = wm * DH + m * 16 + kg * 4;
        #pragma unroll
        for (int n = 0; n < 3; n++) {
            int col = wn * DH + n * 16 + fr;
            #pragma unroll
            for (int r = 0; r < 4; r++)
                sp[(row + r) * 96 + col] = acc[m][n][r];
        }
    }
}

// ============================================================
// combine split-K partials, scale, softmax; emit single-bf16 coefficient
// matrix M'(96 x 128): two BK=64 chunks [Mx|My], cols 48..63 of each zeroed
// ============================================================
__global__ __launch_bounds__(256) void softmax_kernel(const float* __restrict__ spart,
    const float* __restrict__ invx, const float* __restrict__ invy,
    const float* __restrict__ temp, ushort* __restrict__ mpp)
{
    __shared__ float G[96][97];
    const int bh = blockIdx.x, b = bh >> 2, h = bh & 3;
    const int t = threadIdx.x;
    const float ts = temp[h];
    for (int i = 0; i < 36; i++) {
        int f = t + 256 * i;
        float s = 0.f;
        #pragma unroll
        for (int cch = 0; cch < 8; cch++)
            s += spart[((size_t)cch * 32 + bh) * 9216 + f];
        int r = f / 96, c = f % 96;
        float iq = (r < DH) ? invx[b*384 + h*DH + r] : invy[b*384 + h*DH + (r-DH)];
        float ik = (c < DH) ? invx[b*384 + CC + h*DH + c] : invy[b*384 + CC + h*DH + (c-DH)];
        G[r][c] = s * iq * ik * ts;
    }
    __syncthreads();
    if (t < 192) {
        int r = t >> 1, hf = t & 1;
        float* rowp = &G[r][hf * DH];
        float m = rowp[0];
        for (int i = 1; i < DH; i++) m = fmaxf(m, rowp[i]);
        float s = 0.f;
        for (int i = 0; i < DH; i++) { float e = __expf(rowp[i] - m); rowp[i] = e; s += e; }
        float inv = 1.f / s;
        for (int i = 0; i < DH; i++) rowp[i] *= inv;
    }
    __syncthreads();
    ushort* mo = mpp + (size_t)bh * 96 * 128;
    for (int i = 0; i < 12; i++) {
        int f = t + 256 * i;                 // 96 rows x 32 pad cols
        int r = f / 32, p = f % 32;
        int ch = p >> 4, j = p & 15;
        mo[(size_t)r * 128 + ch * 64 + 48 + j] = 0;
    }
    for (int i = 0; i < 36; i++) {
        int f = t + 256 * i;
        int r = f / 96, c = f % 96;
        float v;
        if (c < DH) v = (r < DH) ? G[DH + r][c] : G[r - DH][c];
        else        v = G[r][c];
        ushort hi = f2bf(v);
        if (c < DH) mo[(size_t)r * 128 + c] = hi;
        else        mo[(size_t)r * 128 + 64 + (c - DH)] = hi;
    }
}

// ============================================================
// output GEMM via MFMA (proven, unchanged)
// ============================================================
__global__ __launch_bounds__(256) void outmm_mfma(const ushort* __restrict__ VTx,
    const ushort* __restrict__ VTy, const ushort* __restrict__ mpp,
    float* __restrict__ out)
{
    __shared__ __align__(16) ushort As[96 * 64];
    __shared__ __align__(16) ushort Bs[128 * 64];
    const int t = threadIdx.x;
    const int lane = t & 63, w = t >> 6;
    const int wm = w >> 1, wn = w & 1;
    const int fr = lane & 15, kg = lane >> 4;
    const int nc = blockIdx.x, bh = blockIdx.y;
    const int b = bh >> 2, h = bh & 3;
    const int n0 = nc * 128;
    const ushort* mp = mpp + (size_t)bh * 96 * 128;

    f32x4 acc[3][4] = {};

    for (int kc = 0; kc < 2; kc++) {
        const ushort* Vsrc = kc ? VTy : VTx;
        const int coff = h * DH;
        const int aoff = kc * 64;
        #pragma unroll
        for (int i = 0; i < 3; i++) {
            int u = i * 256 + w * 64 + lane;
            int r = u >> 3, c = u & 7;
            int cs = c ^ (r & 7);
            const ushort* ga = mp + (size_t)r * 128 + aoff + cs * 8;
            __builtin_amdgcn_global_load_lds(AS1(ga), AS3(&As[(size_t)(i * 4 + w) * 512]), 16, 0, 0);
        }
        #pragma unroll
        for (int i = 0; i < 4; i++) {
            int u = i * 256 + w * 64 + lane;
            int r = u >> 3, c = u & 7;
            int cs = c ^ (r & 7);
            int c8 = coff + cs * 8;
            if (c8 >= 192) c8 -= 192;       // wrap: lands on zero-A K-rows
            const ushort* gb = Vsrc + ((size_t)(b * HWP + n0 + r)) * 192 + c8;
            __builtin_amdgcn_global_load_lds(AS1(gb), AS3(&Bs[(size_t)(i * 4 + w) * 512]), 16, 0, 0);
        }
        __syncthreads();
        #pragma unroll
        for (int kq = 0; kq < 8; kq += 4) {
            bf16x8 af[3], bfr[4];
            #pragma unroll
            for (int m = 0; m < 3; m++) {
                int R = wm * DH + m * 16 + fr;
                int unit = R * 8 + ((kq + kg) ^ (R & 7));
                af[m] = *(const bf16x8*)&As[unit * 8];
            }
            #pragma unroll
            for (int n = 0; n < 4; n++) {
                int R = wn * 64 + n * 16 + fr;
                int unit = R * 8 + ((kq + kg) ^ (R & 7));
                bfr[n] = *(const bf16x8*)&Bs[unit * 8];
            }
            #pragma unroll
            for (int m = 0; m < 3; m++)
                #pragma unroll
                for (int n = 0; n < 4; n++)
                    acc[m][n] = __builtin_amdgcn_mfma_f32_16x16x32_bf16(af[m], bfr[n], acc[m][n], 0, 0, 0);
        }
        __syncthreads();
    }

    #pragma unroll
    for (int m = 0; m < 3; m++) {
        int row = wm * DH + m * 16 + kg * 4;
        #pragma unroll
        for (int n = 0; n < 4; n++) {
            int col = n0 + wn * 64 + n * 16 + fr;
            #pragma unroll
            for (int r = 0; r < 4; r++) {
                int rr = row + r;
                float* dst = (rr < DH)
                    ? (out + (size_t)b * X_B + (h * DH + rr) * HWP + col)
                    : (out + OUT_HALF + (size_t)b * X_B + (h * DH + rr - DH) * HWP + col);
                *dst = acc[m][n][r];
            }
        }
    }
}

// ============================================================
extern "C" void kernel_launch(void* const* d_in, const int* in_sizes, int n_in,
                              void* d_out, int out_size, void* d_ws, size_t ws_size,
                              hipStream_t stream)
{
    const float* x  = (const float*)d_in[0];
    const float* y  = (const float*)d_in[1];
    const float* wq = (const float*)d_in[2];
    const float* wd = (const float*)d_in[3];
    const float* tp = (const float*)d_in[4];
    float* out = (float*)d_out;
    float* ws = (float*)d_ws;

    // ---- workspace layout (float units), total ~176 MB of 256 MB ----
    ushort* qh0 = (ushort*)ws;
    float*  v0f = ws + 12582912;
    ushort* v0  = (ushort*)v0f;
    float*  t10 = ws + 12582912 + 6291456;
    ushort* t1s = (ushort*)t10;
    ushort* XT  = (ushort*)(ws + 12582912 + 6291456 + 18874368);
    ushort* Wc  = (ushort*)(ws + 12582912 + 6291456 + 18874368 + 6291456);
    float*  inv0 = ws + 12582912 + 6291456 + 18874368 + 6291456 + 61440;
    float*  invx = inv0;
    float*  invy = inv0 + 3072;
    // aliases over t1 region (dead after dw):
    ushort* VTx  = t1s;
    ushort* VTy  = (ushort*)(t10 + 3145728);
    float*  spart = t10 + 6291456;
    ushort* Mpp  = (ushort*)(t10 + 6291456 + 2359296);
    ushort* qhx = qh0;
    ushort* qhy = qh0 + 12582912;

    wconvert_kernel<<<120, 256, 0, stream>>>(wq, Wc);

    // both tensors: convert -> conv -> dw (one dispatch each)
    convert_single_kernel<<<dim3(64, 3, 16), 256, 0, stream>>>(x, y, XT);
    conv1x1_mfma<<<1280, 512, 0, stream>>>(XT, Wc, t1s);
    dw3x3_kernel<<<2 * BB * C3, 256, 0, stream>>>(t1s, wd, qh0, v0, inv0);

    // transpose v (both tensors) into dead t1 region
    vtrans_kernel<<<dim3(64, 3, 16), 256, 0, stream>>>(v0, VTx);

    gram_mfma<<<dim3(8, 32), 256, 0, stream>>>(qhx, qhy, spart);
    softmax_kernel<<<32, 256, 0, stream>>>(spart, invx, invy, tp, Mpp);
    outmm_mfma<<<dim3(HWP / 128, 32), 256, 0, stream>>>(VTx, VTy, Mpp, out);
}

// Round 16
// 138.501 us; speedup vs baseline: 2.2775x; 1.0279x over previous
//
#include <hip/hip_runtime.h>

// ---- problem constants ----
#define CC   192                 // C
#define C3   576                 // 3C
#define HH   64
#define WW   64
#define HWP  4096                // H*W
#define BB   8
#define DH   48                  // C/HEADS
#define QKV_B (C3*HWP)           // elements per batch of conv-out tensor
#define X_B   (CC*HWP)
#define OUT_HALF ((size_t)BB*X_B)

typedef short bf16x8 __attribute__((ext_vector_type(8)));
typedef float f32x4  __attribute__((ext_vector_type(4)));

#define AS1(p) ((__attribute__((address_space(1))) void*)(p))
#define AS3(p) ((__attribute__((address_space(3))) void*)(p))

__device__ __forceinline__ ushort f2bf(float v) {
    union { float f; unsigned u; } a; a.f = v;
    unsigned r = a.u + 0x7FFF + ((a.u >> 16) & 1);   // RNE
    return (ushort)(r >> 16);
}
__device__ __forceinline__ float bf2f(ushort h) {
    union { float f; unsigned u; } a; a.u = ((unsigned)h) << 16; return a.f;
}

// ============================================================
// {x,y} (b,192,4096) fp32 -> XT (tsr,b,4096,192) bf16 single. z in [0,16).
// ============================================================
__global__ __launch_bounds__(256) void convert_single_kernel(const float* __restrict__ x,
    const float* __restrict__ y, ushort* __restrict__ xt)
{
    __shared__ float L[64][65];
    const int n0 = blockIdx.x * 64, c0 = blockIdx.y * 64, z = blockIdx.z;
    const int t = threadIdx.x;
    const float* ip = ((z < 8) ? x : y) + (size_t)(z & 7) * X_B;
    #pragma unroll
    for (int i = 0; i < 16; i++) {
        int e = t + 256 * i;
        int r = e >> 6, col = e & 63;
        L[r][col] = ip[(size_t)(c0 + r) * HWP + n0 + col];
    }
    __syncthreads();
    #pragma unroll
    for (int i = 0; i < 4; i++) {
        int e = t + 256 * i;
        int n = e >> 4, c4 = e & 15;
        ushort hi[4];
        #pragma unroll
        for (int j = 0; j < 4; j++)
            hi[j] = f2bf(L[c4 * 4 + j][n]);
        size_t base = ((size_t)z * HWP + n0 + n) * 192 + c0 + c4 * 4;
        *(ushort4*)&xt[base] = make_ushort4(hi[0], hi[1], hi[2], hi[3]);
    }
}

// ============================================================
// v bf16 (16 batch-slices,192,4096) -> VT (...,4096,192) transpose. z in [0,16).
// ============================================================
__global__ __launch_bounds__(256) void vtrans_kernel(const ushort* __restrict__ in,
    ushort* __restrict__ vt)
{
    __shared__ __align__(16) ushort L[64][72];
    const int n0 = blockIdx.x * 64, c0 = blockIdx.y * 64, z = blockIdx.z;
    const int t = threadIdx.x;
    const ushort* ip = in + (size_t)z * X_B;
    #pragma unroll
    for (int i = 0; i < 2; i++) {
        int e = t + 256 * i;            // 512 units of 8 ushorts
        int r = e >> 3, u8 = e & 7;
        *(bf16x8*)&L[r][u8 * 8] = *(const bf16x8*)&ip[(size_t)(c0 + r) * HWP + n0 + u8 * 8];
    }
    __syncthreads();
    #pragma unroll
    for (int i = 0; i < 4; i++) {
        int e = t + 256 * i;            // 1024: 64 n x 16 c4
        int n = e >> 4, c4 = e & 15;
        ushort o[4];
        #pragma unroll
        for (int j = 0; j < 4; j++) o[j] = L[c4 * 4 + j][n];
        *(ushort4*)&vt[((size_t)z * HWP + n0 + n) * 192 + c0 + c4 * 4] =
            make_ushort4(o[0], o[1], o[2], o[3]);
    }
}

// ============================================================
// w_qkv -> Wc(640,192) bf16 SINGLE, zero-padded rows 576..639
// ============================================================
__global__ __launch_bounds__(256) void wconvert_kernel(const float* __restrict__ wq,
    ushort* __restrict__ wc)
{
    int e = (blockIdx.x * 256 + threadIdx.x) * 4;    // 640*192 total
    int oc = e / 192, k = e % 192;
    ushort o[4] = {0, 0, 0, 0};
    if (oc < C3) {
        #pragma unroll
        for (int j = 0; j < 4; j++)
            o[j] = f2bf(wq[oc * CC + k + j]);
    }
    *(ushort4*)&wc[e] = make_ushort4(o[0], o[1], o[2], o[3]);
}

// ============================================================
// conv1x1 via MFMA, X-RESIDENT schedule: block = (tsr,b,nt of 256 cols),
// stages all 6 X chunks (96 KB) ONCE, then loops mi=0..4 streaming W
// (8 KB dbuf, prefetch chained across mi). Eliminates the 5x X re-staging:
// VMEM bytes 266 -> 166 MB. Grid 256 blocks x 512 thr (1 block/CU, one
// round). Proven round-13 staging swizzles + fragment reads + E epilogue.
// ============================================================
__global__ __launch_bounds__(512) void conv1x1_mfma(const ushort* __restrict__ XT,
    const ushort* __restrict__ Wc, ushort* __restrict__ t1s)
{
    __shared__ __align__(16) ushort Xres[6][1024 * 8];  // 6 x 16 KB resident
    __shared__ __align__(16) ushort Wsb[2][512 * 8];    // 2 x 8 KB dbuf
    __shared__ __align__(16) ushort E[128][128];        // 32 KB epilogue
    const int t = threadIdx.x;
    const int lane = t & 63, w = t >> 6;
    const int wm = w >> 2, wn = w & 3;
    const int fr = lane & 15, kg = lane >> 4;
    const int g = blockIdx.x;
    const int bg = g & 7, s = g >> 3;           // s in [0,32)
    const int tsr = s >> 4;
    const int nt = s & 15;
    const int n0 = nt * 256;
    const ushort* XTp = XT + (size_t)(tsr * 8 + bg) * (HWP * 192);
    ushort* ob = t1s + (size_t)(tsr * 8 + bg) * QKV_B;

    // ---- stage all X chunks (linear dest per chunk, paired-row swizzle) ----
    #pragma unroll
    for (int ck = 0; ck < 6; ck++) {
        const int k0 = ck * 32;
        #pragma unroll
        for (int i = 0; i < 2; i++) {
            int u = i * 512 + t;                // 1024 units: 256 rows x 4 units
            int rp = u >> 3;
            int p = (u & 7) ^ (rp & 7);
            int r = (rp << 1) | (p >> 2);
            int c = p & 3;
            const ushort* gx = XTp + (size_t)(n0 + r) * 192 + k0 + c * 8;
            __builtin_amdgcn_global_load_lds(AS1(gx), AS3(&Xres[ck][(size_t)(i * 512 + t) * 8]), 16, 0, 0);
        }
    }

    auto STAGE_W = [&](int buf, int mi, int ck) {
        const int k0 = ck * 32;
        int u = t;                              // 512 units: 128 rows x 4 units
        int rp = u >> 3;
        int p = (u & 7) ^ (rp & 7);
        int r = (rp << 1) | (p >> 2);
        int c = p & 3;
        const ushort* gw = Wc + (size_t)(mi * 128 + r) * 192 + k0 + c * 8;
        __builtin_amdgcn_global_load_lds(AS1(gw), AS3(&Wsb[buf][(size_t)t * 8]), 16, 0, 0);
    };

    STAGE_W(0, 0, 0);
    __syncthreads();                 // X + W(0,0) resident
    int cur = 0;

    for (int mi = 0; mi < 5; mi++) {
        f32x4 acc[4][4] = {};
        for (int ck = 0; ck < 6; ck++) {
            if (mi * 6 + ck < 29) {
                int nmi = (ck == 5) ? mi + 1 : mi;
                int nck = (ck == 5) ? 0 : ck + 1;
                STAGE_W(cur ^ 1, nmi, nck);     // prefetch next W chunk
            }
            bf16x8 afh[4], bfr[4];
            #pragma unroll
            for (int m = 0; m < 4; m++) {
                int R = wm * 64 + m * 16 + fr;  // [0,128)
                int unit = (R >> 1) * 8 + ((((R & 1) << 2) | kg) ^ ((R >> 1) & 7));
                afh[m] = *(const bf16x8*)&Wsb[cur][unit * 8];
            }
            #pragma unroll
            for (int n = 0; n < 4; n++) {
                int R = wn * 64 + n * 16 + fr;  // [0,256)
                int unit = (R >> 1) * 8 + ((((R & 1) << 2) | kg) ^ ((R >> 1) & 7));
                bfr[n] = *(const bf16x8*)&Xres[ck][unit * 8];
            }
            #pragma unroll
            for (int m = 0; m < 4; m++)
                #pragma unroll
                for (int n = 0; n < 4; n++)
                    acc[m][n] = __builtin_amdgcn_mfma_f32_16x16x32_bf16(afh[m], bfr[n], acc[m][n], 0, 0, 0);
            __syncthreads();         // W prefetch done + WAR safe
            cur ^= 1;
        }

        // epilogue for this mi: two 128x128 half-tiles via E
        const int m0 = mi * 128;
        #pragma unroll
        for (int hf = 0; hf < 2; hf++) {
            if (hf) __syncthreads();
            if ((wn >> 1) == hf) {
                int wn2 = wn & 1;
                #pragma unroll
                for (int m = 0; m < 4; m++) {
                    int rl = wm * 64 + m * 16 + kg * 4;
                    #pragma unroll
                    for (int n = 0; n < 4; n++) {
                        int cl = wn2 * 64 + n * 16 + fr;
                        #pragma unroll
                        for (int r = 0; r < 4; r++)
                            E[rl + r][cl] = f2bf(acc[m][n][r]);
                    }
                }
            }
            __syncthreads();
            #pragma unroll
            for (int i = 0; i < 4; i++) {
                int u = t + 512 * i;            // 2048: 128 rows x 16 col-units
                int row = u >> 4, c8 = u & 15;
                int oc = m0 + row;
                if (oc < C3)
                    *(bf16x8*)&ob[(size_t)oc * HWP + n0 + hf * 128 + c8 * 8] =
                        *(bf16x8*)&E[row][c8 * 8];
            }
        }
        __syncthreads();             // E reads done before next mi overwrites
    }
}

// ============================================================
// depthwise 3x3, both tensors (grid 9216). 4x4 register-blocked rolling
// window (proven round-15). q/k bf16 + fused L2 norm; v bf16.
// ============================================================
__global__ __launch_bounds__(256) void dw3x3_kernel(const ushort* __restrict__ inp,
    const float* __restrict__ wd,
    ushort* __restrict__ qh0, ushort* __restrict__ vv0, float* __restrict__ inv0)
{
    __shared__ float P[66][76];
    const int bcg = blockIdx.x;
    const int tsr = bcg / (BB * C3);
    const int bc = bcg - tsr * (BB * C3);       // b*576 + ch
    const int b = bc / C3, ch = bc % C3;
    const int t = threadIdx.x;
    const ushort* ip = inp + (size_t)tsr * ((size_t)BB * QKV_B) + (size_t)bc * HWP;
    ushort* qh = qh0 + (size_t)tsr * 12582912;
    ushort* vv = vv0 + (size_t)tsr * 6291456;
    float* inv = inv0 + (size_t)tsr * 3072;
    float wr[9];
    #pragma unroll
    for (int k = 0; k < 9; k++) wr[k] = wd[ch * 9 + k];
    for (int i = t; i < 66 * 76; i += 256) ((float*)P)[i] = 0.f;
    __syncthreads();
    #pragma unroll
    for (int i = 0; i < 2; i++) {
        int u = t + 256 * i;            // 512 units of 8 px
        int y = u >> 3, x0 = (u & 7) * 8;
        bf16x8 v8 = *(const bf16x8*)&ip[u * 8];
        float f0 = bf2f((ushort)v8[0]), f1 = bf2f((ushort)v8[1]);
        float f2 = bf2f((ushort)v8[2]), f3 = bf2f((ushort)v8[3]);
        float f4 = bf2f((ushort)v8[4]), f5 = bf2f((ushort)v8[5]);
        float f6 = bf2f((ushort)v8[6]), f7 = bf2f((ushort)v8[7]);
        *(float4*)&P[1 + y][4 + x0]     = make_float4(f0, f1, f2, f3);
        *(float4*)&P[1 + y][4 + x0 + 4] = make_float4(f4, f5, f6, f7);
    }
    __syncthreads();

    const int tx = t & 15, ty = t >> 4;
    const int x0 = tx * 4, y0 = ty * 4;

    float ssum = 0.f;
    float4 a0 = *(float4*)&P[y0][x0], b0 = *(float4*)&P[y0][x0 + 4], c0 = *(float4*)&P[y0][x0 + 8];
    float4 a1 = *(float4*)&P[y0 + 1][x0], b1 = *(float4*)&P[y0 + 1][x0 + 4], c1 = *(float4*)&P[y0 + 1][x0 + 8];
    #pragma unroll
    for (int r = 0; r < 4; r++) {
        float4 a2 = *(float4*)&P[y0 + r + 2][x0];
        float4 b2 = *(float4*)&P[y0 + r + 2][x0 + 4];
        float4 c2 = *(float4*)&P[y0 + r + 2][x0 + 8];
        float res[4] = {0.f, 0.f, 0.f, 0.f};
        {
            float e0 = a0.w, e1 = b0.x, e2 = b0.y, e3 = b0.z, e4 = b0.w, e5 = c0.x;
            res[0] += wr[0]*e0 + wr[1]*e1 + wr[2]*e2;
            res[1] += wr[0]*e1 + wr[1]*e2 + wr[2]*e3;
            res[2] += wr[0]*e2 + wr[1]*e3 + wr[2]*e4;
            res[3] += wr[0]*e3 + wr[1]*e4 + wr[2]*e5;
        }
        {
            float e0 = a1.w, e1 = b1.x, e2 = b1.y, e3 = b1.z, e4 = b1.w, e5 = c1.x;
            res[0] += wr[3]*e0 + wr[4]*e1 + wr[5]*e2;
            res[1] += wr[3]*e1 + wr[4]*e2 + wr[5]*e3;
            res[2] += wr[3]*e2 + wr[4]*e3 + wr[5]*e4;
            res[3] += wr[3]*e3 + wr[4]*e4 + wr[5]*e5;
        }
        {
            float e0 = a2.w, e1 = b2.x, e2 = b2.y, e3 = b2.z, e4 = b2.w, e5 = c2.x;
            res[0] += wr[6]*e0 + wr[7]*e1 + wr[8]*e2;
            res[1] += wr[6]*e1 + wr[7]*e2 + wr[8]*e3;
            res[2] += wr[6]*e2 + wr[7]*e3 + wr[8]*e4;
            res[3] += wr[6]*e3 + wr[7]*e4 + wr[8]*e5;
        }
        #pragma unroll
        for (int k = 0; k < 4; k++) ssum += res[k] * res[k];
        int px = (y0 + r) * WW + x0;
        if (ch < 384) {
            size_t base = ((size_t)b * 384 + ch) * HWP + px;
            *(ushort4*)&qh[base] = make_ushort4(f2bf(res[0]), f2bf(res[1]),
                                                f2bf(res[2]), f2bf(res[3]));
        } else {
            size_t base = ((size_t)b * CC + (ch - 384)) * HWP + px;
            *(ushort4*)&vv[base] = make_ushort4(f2bf(res[0]), f2bf(res[1]),
                                                f2bf(res[2]), f2bf(res[3]));
        }
        a0 = a1; b0 = b1; c0 = c1;
        a1 = a2; b1 = b2; c1 = c2;
    }
    if (ch < 384) {
        #pragma unroll
        for (int off = 32; off > 0; off >>= 1) ssum += __shfl_down(ssum, off);
        __shared__ float red[4];
        if ((t & 63) == 0) red[t >> 6] = ssum;
        __syncthreads();
        if (t == 0) {
            float tot = red[0] + red[1] + red[2] + red[3];
            inv[b * 384 + ch] = 1.f / fmaxf(sqrtf(tot), 1e-12f);
        }
    }
}

// ============================================================
// stacked Gram via MFMA, single bf16 (proven, unchanged)
// ============================================================
__global__ __launch_bounds__(256) void gram_mfma(const ushort* __restrict__ qhx,
    const ushort* __restrict__ qhy, float* __restrict__ spart)
{
    __shared__ __align__(16) ushort As[96 * 64];
    __shared__ __align__(16) ushort Bs[96 * 64];
    const int chunk = blockIdx.x, bh = blockIdx.y;
    const int b = bh >> 2, h = bh & 3;
    const int t = threadIdx.x;
    const int lane = t & 63, w = t >> 6;
    const int wm = w >> 1, wn = w & 1;
    const int fr = lane & 15, kg = lane >> 4;

    const size_t qbase = ((size_t)b * 384 + h * DH) * HWP;
    const size_t kbase = ((size_t)b * 384 + 192 + h * DH) * HWP;

    f32x4 acc[3][3] = {};

    for (int ks = 0; ks < 8; ks++) {
        const int n0 = chunk * 512 + ks * 64;
        #pragma unroll
        for (int i = 0; i < 3; i++) {
            int u = i * 256 + w * 64 + lane;
            int r = u >> 3, c = u & 7;
            int cs = c ^ (r & 7);
            const ushort* ga = ((r < DH) ? (qhx + qbase + (size_t)r * HWP)
                                         : (qhy + qbase + (size_t)(r - DH) * HWP))
                               + n0 + cs * 8;
            __builtin_amdgcn_global_load_lds(AS1(ga), AS3(&As[(size_t)(i * 4 + w) * 512]), 16, 0, 0);
            const ushort* gb = ((r < DH) ? (qhx + kbase + (size_t)r * HWP)
                                         : (qhy + kbase + (size_t)(r - DH) * HWP))
                               + n0 + cs * 8;
            __builtin_amdgcn_global_load_lds(AS1(gb), AS3(&Bs[(size_t)(i * 4 + w) * 512]), 16, 0, 0);
        }
        __syncthreads();
        #pragma unroll
        for (int kq = 0; kq < 8; kq += 4) {
            bf16x8 af[3], bfr[3];
            #pragma unroll
            for (int m = 0; m < 3; m++) {
                int R = wm * DH + m * 16 + fr;
                int unit = R * 8 + ((kq + kg) ^ (R & 7));
                af[m] = *(const bf16x8*)&As[unit * 8];
            }
            #pragma unroll
            for (int n = 0; n < 3; n++) {
                int R = wn * DH + n * 16 + fr;
                int unit = R * 8 + ((kq + kg) ^ (R & 7));
                bfr[n] = *(const bf16x8*)&Bs[unit * 8];
            }
            #pragma unroll
            for (int m = 0; m < 3; m++)
                #pragma unroll
                for (int n = 0; n < 3; n++)
                    acc[m][n] = __builtin_amdgcn_mfma_f32_16x16x32_bf16(af[m], bfr[n], acc[m][n], 0, 0, 0);
        }
        __syncthreads();
    }

    float* sp = spart + ((size_t)chunk * 32 + bh) * 9216;
    #pragma unroll
    for (int m = 0; m < 3; m++) {
        int row = wm * DH + m * 16 + kg * 4;
        #pragma unroll
        for (int n = 0; n < 3; n++) {
            int col = wn * DH + n * 16 + fr;
            #pragma unroll
            for (int r = 0; r < 4; r++)
                sp[(row + r) * 96 + col] = acc[m][n][r];
        }
    }
}

// ============================================================
// combine split-K partials, scale, softmax; emit single-bf16 coefficient
// matrix M'(96 x 128): two BK=64 chunks [Mx|My], cols 48..63 of each zeroed
// ============================================================
__global__ __launch_bounds__(256) void softmax_kernel(const float* __restrict__ spart,
    const float* __restrict__ invx, const float* __restrict__ invy,
    const float* __restrict__ temp, ushort* __restrict__ mpp)
{
    __shared__ float G[96][97];
    const int bh = blockIdx.x, b = bh >> 2, h = bh & 3;
    const int t = threadIdx.x;
    const float ts = temp[h];
    for (int i = 0; i < 36; i++) {
        int f = t + 256 * i;
        float s = 0.f;
        #pragma unroll
        for (int cch = 0; cch < 8; cch++)
            s += spart[((size_t)cch * 32 + bh) * 9216 + f];
        int r = f / 96, c = f % 96;
        float iq = (r < DH) ? invx[b*384 + h*DH + r] : invy[b*384 + h*DH + (r-DH)];
        float ik = (c < DH) ? invx[b*384 + CC + h*DH + c] : invy[b*384 + CC + h*DH + (c-DH)];
        G[r][c] = s * iq * ik * ts;
    }
    __syncthreads();
    if (t < 192) {
        int r = t >> 1, hf = t & 1;
        float* rowp = &G[r][hf * DH];
        float m = rowp[0];
        for (int i = 1; i < DH; i++) m = fmaxf(m, rowp[i]);
        float s = 0.f;
        for (int i = 0; i < DH; i++) { float e = __expf(rowp[i] - m); rowp[i] = e; s += e; }
        float inv = 1.f / s;
        for (int i = 0; i < DH; i++) rowp[i] *= inv;
    }
    __syncthreads();
    ushort* mo = mpp + (size_t)bh * 96 * 128;
    for (int i = 0; i < 12; i++) {
        int f = t + 256 * i;                 // 96 rows x 32 pad cols
        int r = f / 32, p = f % 32;
        int ch = p >> 4, j = p & 15;
        mo[(size_t)r * 128 + ch * 64 + 48 + j] = 0;
    }
    for (int i = 0; i < 36; i++) {
        int f = t + 256 * i;
        int r = f / 96, c = f % 96;
        float v;
        if (c < DH) v = (r < DH) ? G[DH + r][c] : G[r - DH][c];
        else        v = G[r][c];
        ushort hi = f2bf(v);
        if (c < DH) mo[(size_t)r * 128 + c] = hi;
        else        mo[(size_t)r * 128 + 64 + (c - DH)] = hi;
    }
}

// ============================================================
// output GEMM via MFMA (proven, unchanged)
// ============================================================
__global__ __launch_bounds__(256) void outmm_mfma(const ushort* __restrict__ VTx,
    const ushort* __restrict__ VTy, const ushort* __restrict__ mpp,
    float* __restrict__ out)
{
    __shared__ __align__(16) ushort As[96 * 64];
    __shared__ __align__(16) ushort Bs[128 * 64];
    const int t = threadIdx.x;
    const int lane = t & 63, w = t >> 6;
    const int wm = w >> 1, wn = w & 1;
    const int fr = lane & 15, kg = lane >> 4;
    const int nc = blockIdx.x, bh = blockIdx.y;
    const int b = bh >> 2, h = bh & 3;
    const int n0 = nc * 128;
    const ushort* mp = mpp + (size_t)bh * 96 * 128;

    f32x4 acc[3][4] = {};

    for (int kc = 0; kc < 2; kc++) {
        const ushort* Vsrc = kc ? VTy : VTx;
        const int coff = h * DH;
        const int aoff = kc * 64;
        #pragma unroll
        for (int i = 0; i < 3; i++) {
            int u = i * 256 + w * 64 + lane;
            int r = u >> 3, c = u & 7;
            int cs = c ^ (r & 7);
            const ushort* ga = mp + (size_t)r * 128 + aoff + cs * 8;
            __builtin_amdgcn_global_load_lds(AS1(ga), AS3(&As[(size_t)(i * 4 + w) * 512]), 16, 0, 0);
        }
        #pragma unroll
        for (int i = 0; i < 4; i++) {
            int u = i * 256 + w * 64 + lane;
            int r = u >> 3, c = u & 7;
            int cs = c ^ (r & 7);
            int c8 = coff + cs * 8;
            if (c8 >= 192) c8 -= 192;       // wrap: lands on zero-A K-rows
            const ushort* gb = Vsrc + ((size_t)(b * HWP + n0 + r)) * 192 + c8;
            __builtin_amdgcn_global_load_lds(AS1(gb), AS3(&Bs[(size_t)(i * 4 + w) * 512]), 16, 0, 0);
        }
        __syncthreads();
        #pragma unroll
        for (int kq = 0; kq < 8; kq += 4) {
            bf16x8 af[3], bfr[4];
            #pragma unroll
            for (int m = 0; m < 3; m++) {
                int R = wm * DH + m * 16 + fr;
                int unit = R * 8 + ((kq + kg) ^ (R & 7));
                af[m] = *(const bf16x8*)&As[unit * 8];
            }
            #pragma unroll
            for (int n = 0; n < 4; n++) {
                int R = wn * 64 + n * 16 + fr;
                int unit = R * 8 + ((kq + kg) ^ (R & 7));
                bfr[n] = *(const bf16x8*)&Bs[unit * 8];
            }
            #pragma unroll
            for (int m = 0; m < 3; m++)
                #pragma unroll
                for (int n = 0; n < 4; n++)
                    acc[m][n] = __builtin_amdgcn_mfma_f32_16x16x32_bf16(af[m], bfr[n], acc[m][n], 0, 0, 0);
        }
        __syncthreads();
    }

    #pragma unroll
    for (int m = 0; m < 3; m++) {
        int row = wm * DH + m * 16 + kg * 4;
        #pragma unroll
        for (int n = 0; n < 4; n++) {
            int col = n0 + wn * 64 + n * 16 + fr;
            #pragma unroll
            for (int r = 0; r < 4; r++) {
                int rr = row + r;
                float* dst = (rr < DH)
                    ? (out + (size_t)b * X_B + (h * DH + rr) * HWP + col)
                    : (out + OUT_HALF + (size_t)b * X_B + (h * DH + rr - DH) * HWP + col);
                *dst = acc[m][n][r];
            }
        }
    }
}

// ============================================================
extern "C" void kernel_launch(void* const* d_in, const int* in_sizes, int n_in,
                              void* d_out, int out_size, void* d_ws, size_t ws_size,
                              hipStream_t stream)
{
    const float* x  = (const float*)d_in[0];
    const float* y  = (const float*)d_in[1];
    const float* wq = (const float*)d_in[2];
    const float* wd = (const float*)d_in[3];
    const float* tp = (const float*)d_in[4];
    float* out = (float*)d_out;
    float* ws = (float*)d_ws;

    // ---- workspace layout (float units), total ~176 MB of 256 MB ----
    ushort* qh0 = (ushort*)ws;
    float*  v0f = ws + 12582912;
    ushort* v0  = (ushort*)v0f;
    float*  t10 = ws + 12582912 + 6291456;
    ushort* t1s = (ushort*)t10;
    ushort* XT  = (ushort*)(ws + 12582912 + 6291456 + 18874368);
    ushort* Wc  = (ushort*)(ws + 12582912 + 6291456 + 18874368 + 6291456);
    float*  inv0 = ws + 12582912 + 6291456 + 18874368 + 6291456 + 61440;
    float*  invx = inv0;
    float*  invy = inv0 + 3072;
    // aliases over t1 region (dead after dw):
    ushort* VTx  = t1s;
    ushort* VTy  = (ushort*)(t10 + 3145728);
    float*  spart = t10 + 6291456;
    ushort* Mpp  = (ushort*)(t10 + 6291456 + 2359296);
    ushort* qhx = qh0;
    ushort* qhy = qh0 + 12582912;

    wconvert_kernel<<<120, 256, 0, stream>>>(wq, Wc);

    // both tensors: convert -> conv -> dw (one dispatch each)
    convert_single_kernel<<<dim3(64, 3, 16), 256, 0, stream>>>(x, y, XT);
    conv1x1_mfma<<<256, 512, 0, stream>>>(XT, Wc, t1s);
    dw3x3_kernel<<<2 * BB * C3, 256, 0, stream>>>(t1s, wd, qh0, v0, inv0);

    // transpose v (both tensors) into dead t1 region
    vtrans_kernel<<<dim3(64, 3, 16), 256, 0, stream>>>(v0, VTx);

    gram_mfma<<<dim3(8, 32), 256, 0, stream>>>(qhx, qhy, spart);
    softmax_kernel<<<32, 256, 0, stream>>>(spart, invx, invy, tp, Mpp);
    outmm_mfma<<<dim3(HWP / 128, 32), 256, 0, stream>>>(VTx, VTy, Mpp, out);
}